// Round 2
// baseline (613.947 us; speedup 1.0000x reference)
//
#include <hip/hip_runtime.h>
#include <hip/hip_bf16.h>
#include <math.h>

using bf16 = __hip_bfloat16;
typedef __attribute__((ext_vector_type(8))) short short8;
typedef __attribute__((ext_vector_type(4))) float floatx4;

// ---------------------------------------------------------------- helpers
__device__ inline void gl_lds16(const void* g, void* l) {
  __builtin_amdgcn_global_load_lds(
      (const __attribute__((address_space(1))) unsigned int*)g,
      (__attribute__((address_space(3))) unsigned int*)l,
      16, 0, 0);
}

__device__ inline void store_cast(float* d, float x) { *d = x; }
__device__ inline void store_cast(bf16* d, float x) { *d = __float2bfloat16(x); }
__device__ inline float load_f(const float* p) { return *p; }
__device__ inline float load_f(const bf16* p) { return __bfloat162float(*p); }

// ---------------------------------------------------------------- dtype probe
// Inputs may be f32 (per reference) or bf16 (per dataset conversion). Probe
// node_feature: view as bf16; EVEN-index elements are the low mantissa halves
// if data is really f32 -> uniform random bits -> ~10% decode to |x|>5e30.
// Genuine bf16 N(0,1) data never does. flag=1 -> inputs are f32.
__global__ void probe_dtype(const unsigned short* __restrict__ x, int* __restrict__ flag) {
  __shared__ int s;
  int t = threadIdx.x;
  if (t == 0) s = 0;
  __syncthreads();
  int bad = 0;
  for (int i = t; i < 1024; i += 256) {
    unsigned short h = x[2 * i];
    unsigned e = (h >> 7) & 0xFF;
    if (e >= 0xE5) bad = 1;
  }
  if (bad) atomicOr(&s, 1);
  __syncthreads();
  if (t == 0) flag[0] = s;
}

__global__ void to_bf16_kernel(const void* __restrict__ in, bf16* __restrict__ out,
                               int nelem, const int* __restrict__ flag) {
  int i = blockIdx.x * 256 + threadIdx.x;
  if (i >= nelem) return;
  if (*flag) out[i] = __float2bfloat16(((const float*)in)[i]);
  else       out[i] = ((const bf16*)in)[i];
}

__global__ void to_f32_kernel(const void* __restrict__ in, float* __restrict__ out,
                              int nelem, const int* __restrict__ flag) {
  int i = blockIdx.x * 256 + threadIdx.x;
  if (i >= nelem) return;
  if (*flag) out[i] = ((const float*)in)[i];
  else       out[i] = __bfloat162float(((const bf16*)in)[i]);
}

// ---------------------------------------------------------------- graph prep
__global__ void deg_kernel(const int* __restrict__ dst, int E, int* __restrict__ deg) {
  int e = blockIdx.x * 256 + threadIdx.x;
  if (e < E) atomicAdd(&deg[dst[e]], 1);
}

// single-block exclusive scan over n elements + dinv = rsqrt(deg+1)
__global__ void scan_kernel(const int* __restrict__ deg, int* __restrict__ off,
                            float* __restrict__ dinv, int n) {
  __shared__ int s[1024];
  __shared__ int carry_s;
  int t = threadIdx.x;
  if (t == 0) carry_s = 0;
  __syncthreads();
  for (int base = 0; base < n; base += 1024) {
    int i = base + t;
    int orig = (i < n) ? deg[i] : 0;
    s[t] = orig;
    __syncthreads();
    for (int d = 1; d < 1024; d <<= 1) {
      int add = (t >= d) ? s[t - d] : 0;
      __syncthreads();
      s[t] += add;
      __syncthreads();
    }
    int incl = s[t];
    int carry = carry_s;
    if (i < n) {
      off[i]  = carry + incl - orig;          // exclusive prefix
      dinv[i] = rsqrtf((float)(orig + 1));    // self-loop included, always >=1
    }
    __syncthreads();
    if (t == 1023) carry_s = carry + incl;
    __syncthreads();
  }
  if (t == 0) off[n] = carry_s;
}

__global__ void csr_fill(const int* __restrict__ src, const int* __restrict__ dst, int E,
                         const int* __restrict__ off, int* __restrict__ cur,
                         const float* __restrict__ dinv,
                         int* __restrict__ cs, float* __restrict__ cw) {
  int e = blockIdx.x * 256 + threadIdx.x;
  if (e < E) {
    int d = dst[e], s = src[e];
    int slot = off[d] + atomicAdd(&cur[d], 1);
    cs[slot] = s;
    cw[slot] = dinv[s];
  }
}

// W[K][N] -> Wt[N][K] (bf16 out), input dtype per flag. K,N multiples of 32.
__global__ void transpose_to_bf16(const void* __restrict__ in, bf16* __restrict__ out,
                                  int K, int N, const int* __restrict__ flag) {
  __shared__ bf16 tile[32][33];
  const bool f32 = *flag != 0;
  int bx = blockIdx.x * 32;  // N offset
  int by = blockIdx.y * 32;  // K offset
  int tx = threadIdx.x, ty = threadIdx.y;
#pragma unroll
  for (int i = 0; i < 32; i += 8) {
    size_t idx = (size_t)(by + ty + i) * N + (bx + tx);
    tile[ty + i][tx] = f32 ? __float2bfloat16(((const float*)in)[idx])
                           : ((const bf16*)in)[idx];
  }
  __syncthreads();
#pragma unroll
  for (int i = 0; i < 32; i += 8)
    out[(size_t)(bx + ty + i) * K + (by + tx)] = tile[tx][ty + i];
}

// ---------------------------------------------------------------- GEMM (m97-style)
// C[M][N] = A[M][K] @ Bt[N][K]^T, 128x128 tile, BK=32, 4 waves, 16x16x32 bf16 MFMA
template <typename CT>
__global__ __launch_bounds__(256) void gemm128(const bf16* __restrict__ A,
                                               const bf16* __restrict__ Bt,
                                               CT* __restrict__ C,
                                               int M, int K, int N) {
  __shared__ bf16 As[128 * 32];
  __shared__ bf16 Bs[128 * 32];
  const int tid = threadIdx.x;
  const int wave = tid >> 6;
  const int lane = tid & 63;
  const int quad = lane >> 4;
  const int l16 = lane & 15;
  const int m0 = blockIdx.y * 128;
  const int n0 = blockIdx.x * 128;
  const int wr = (wave >> 1) * 64;
  const int wc = (wave & 1) * 64;
  const int r_sub = lane >> 2;       // 0..15 row within 16-row portion
  const int cb = (lane & 3) * 16;    // byte offset within 64B row chunk

  floatx4 acc[4][4];
#pragma unroll
  for (int i = 0; i < 4; i++)
#pragma unroll
    for (int j = 0; j < 4; j++) acc[i][j] = (floatx4){0.f, 0.f, 0.f, 0.f};

  for (int k0 = 0; k0 < K; k0 += 32) {
    __syncthreads();
#pragma unroll
    for (int j = 0; j < 2; ++j) {
      int p = wave * 2 + j;                    // portion 0..7 (16 rows each)
      int ra = p * 16 + r_sub;
      int grow = m0 + ra; if (grow >= M) grow = M - 1;
      gl_lds16((const char*)(A + (size_t)grow * K + k0) + cb, (char*)As + p * 1024);
      int rb = n0 + p * 16 + r_sub;            // N % 128 == 0, no guard
      gl_lds16((const char*)(Bt + (size_t)rb * K + k0) + cb, (char*)Bs + p * 1024);
    }
    __syncthreads();  // drains vmcnt(0) then barrier

    short8 af[4], bfr[4];
#pragma unroll
    for (int i = 0; i < 4; i++)
      af[i] = *(const short8*)(As + (wr + i * 16 + l16) * 32 + quad * 8);
#pragma unroll
    for (int j = 0; j < 4; j++)
      bfr[j] = *(const short8*)(Bs + (wc + j * 16 + l16) * 32 + quad * 8);
#pragma unroll
    for (int i = 0; i < 4; i++)
#pragma unroll
      for (int j = 0; j < 4; j++)
        acc[i][j] = __builtin_amdgcn_mfma_f32_16x16x32_bf16(af[i], bfr[j], acc[i][j], 0, 0, 0);
  }

#pragma unroll
  for (int i = 0; i < 4; i++) {
#pragma unroll
    for (int r = 0; r < 4; r++) {
      int row = m0 + wr + i * 16 + quad * 4 + r;
      if (row < M) {
#pragma unroll
        for (int j = 0; j < 4; j++) {
          int col = n0 + wc + j * 16 + l16;
          store_cast(&C[(size_t)row * N + col], acc[i][j][r]);
        }
      }
    }
  }
}

// ---------------------------------------------------------------- fused aggregation
// out[v,c] = softmax-combine( elu(dv1*sum1 + dv1^2*Ha[v,c] + ba[c]),
//                             elu(dv2*sum2 + dv2^2*Hb[v,c] + bb[c]) )
// outflag==nullptr -> bf16 store; else *outflag selects f32/bf16.
template <int CPT, typename HT>
__global__ __launch_bounds__(256) void agg_kernel(
    const HT* __restrict__ Ha, const HT* __restrict__ Hb,
    const int* __restrict__ off1, const int* __restrict__ cs1, const float* __restrict__ cw1,
    const int* __restrict__ off2, const int* __restrict__ cs2, const float* __restrict__ cw2,
    const float* __restrict__ dinv1, const float* __restrict__ dinv2,
    const float* __restrict__ ba, const float* __restrict__ bb,
    const float* __restrict__ aw, void* __restrict__ out, int C,
    const int* __restrict__ outflag) {
  const int v = blockIdx.x;
  const int t = threadIdx.x;
  const int B = blockDim.x;
  const float dv1 = dinv1[v], dv2 = dinv2[v];
  float a1[CPT], a2[CPT];
#pragma unroll
  for (int j = 0; j < CPT; j++) { a1[j] = 0.f; a2[j] = 0.f; }

  const int s1 = off1[v], e1 = off1[v + 1];
  for (int i = s1; i < e1; ++i) {
    const int u = cs1[i];
    const float w = cw1[i];
    const HT* row = Ha + (size_t)u * C;
#pragma unroll
    for (int j = 0; j < CPT; j++) a1[j] += w * load_f(row + t + j * B);
  }
  const int s2 = off2[v], e2 = off2[v + 1];
  for (int i = s2; i < e2; ++i) {
    const int u = cs2[i];
    const float w = cw2[i];
    const HT* row = Hb + (size_t)u * C;
#pragma unroll
    for (int j = 0; j < CPT; j++) a2[j] += w * load_f(row + t + j * B);
  }

  const bool out_f32 = (outflag != nullptr) && (*outflag != 0);
  const HT* rva = Ha + (size_t)v * C;
  const HT* rvb = Hb + (size_t)v * C;
#pragma unroll
  for (int j = 0; j < CPT; j++) {
    int c = t + j * B;
    float x1 = dv1 * a1[j] + dv1 * dv1 * load_f(rva + c) + ba[c];
    float x2 = dv2 * a2[j] + dv2 * dv2 * load_f(rvb + c) + bb[c];
    x1 = x1 > 0.f ? x1 : expm1f(x1);
    x2 = x2 > 0.f ? x2 : expm1f(x2);
    float e0 = aw[2 * c];
    float e1v = aw[2 * c + 1];
    float mx = fmaxf(e0, e1v);
    float w0 = expf(e0 - mx), w1 = expf(e1v - mx);
    float r = (x1 * w0 + x2 * w1) / (w0 + w1);
    size_t oi = (size_t)v * C + c;
    if (out_f32) ((float*)out)[oi] = r;
    else         ((bf16*)out)[oi] = __float2bfloat16(r);
  }
}

// ---------------------------------------------------------------- host pipeline
template <typename HT>
static void run_pipeline(const void* X, const int* src1, const int* dst1, int E1,
                         const int* src2, const int* dst2, int E2, int n,
                         void* const* d_in, void* d_out, char* ws, hipStream_t stream) {
  auto rnd = [](size_t b) { return (b + 255) & ~(size_t)255; };
  char* p = ws;
  auto alloc = [&](size_t bytes) { char* r = p; p += rnd(bytes); return r; };

  int* flag = (int*)alloc(256);
  int* deg1 = (int*)alloc((size_t)n * 4);
  int* deg2 = (int*)alloc((size_t)n * 4);
  int* cur1 = (int*)alloc((size_t)n * 4);
  int* cur2 = (int*)alloc((size_t)n * 4);
  int* off1 = (int*)alloc((size_t)(n + 1) * 4);
  int* off2 = (int*)alloc((size_t)(n + 1) * 4);
  float* dinv1 = (float*)alloc((size_t)n * 4);
  float* dinv2 = (float*)alloc((size_t)n * 4);
  int* cs1 = (int*)alloc((size_t)E1 * 4);
  float* cw1 = (float*)alloc((size_t)E1 * 4);
  int* cs2 = (int*)alloc((size_t)E2 * 4);
  float* cw2 = (float*)alloc((size_t)E2 * 4);
  bf16* Wt11 = (bf16*)alloc((size_t)512 * 1024 * 2);
  bf16* Wt12 = (bf16*)alloc((size_t)512 * 1024 * 2);
  bf16* Wt21 = (bf16*)alloc((size_t)1024 * 512 * 2);
  bf16* Wt22 = (bf16*)alloc((size_t)1024 * 512 * 2);
  bf16* Wt31 = (bf16*)alloc((size_t)512 * 128 * 2);
  bf16* Wt32 = (bf16*)alloc((size_t)512 * 128 * 2);
  float* bf_[6]; int bsz[6] = {1024, 1024, 512, 512, 128, 128};
  for (int i = 0; i < 6; i++) bf_[i] = (float*)alloc((size_t)bsz[i] * 4);
  float* awf[3]; int asz[3] = {2048, 1024, 256};
  for (int i = 0; i < 3; i++) awf[i] = (float*)alloc((size_t)asz[i] * 4);
  bf16* Xb = (bf16*)alloc((size_t)n * 512 * 2);
  HT* Ha = (HT*)alloc((size_t)n * 1024 * sizeof(HT));
  HT* Hb = (HT*)alloc((size_t)n * 1024 * sizeof(HT));
  bf16* act = (bf16*)alloc((size_t)n * 1024 * 2);

  // dtype probe first — everything downstream branches on *flag
  probe_dtype<<<1, 256, 0, stream>>>((const unsigned short*)X, flag);

  // zero counters (deg1,deg2,cur1,cur2 contiguous 256B-rounded blocks)
  hipMemsetAsync(deg1, 0, rnd((size_t)n * 4) * 4, stream);

  // input conversions
  to_bf16_kernel<<<(n * 512 + 255) / 256, 256, 0, stream>>>(X, Xb, n * 512, flag);
  const int bidx[6] = {4, 6, 8, 10, 12, 14};
  for (int i = 0; i < 6; i++)
    to_f32_kernel<<<(bsz[i] + 255) / 256, 256, 0, stream>>>(d_in[bidx[i]], bf_[i], bsz[i], flag);
  const int aidx[3] = {15, 16, 17};
  for (int i = 0; i < 3; i++)
    to_f32_kernel<<<(asz[i] + 255) / 256, 256, 0, stream>>>(d_in[aidx[i]], awf[i], asz[i], flag);

  // degrees
  deg_kernel<<<(E1 + 255) / 256, 256, 0, stream>>>(dst1, E1, deg1);
  deg_kernel<<<(E2 + 255) / 256, 256, 0, stream>>>(dst2, E2, deg2);
  // scans + dinv
  scan_kernel<<<1, 1024, 0, stream>>>(deg1, off1, dinv1, n);
  scan_kernel<<<1, 1024, 0, stream>>>(deg2, off2, dinv2, n);
  // CSR fill (with per-edge src dinv weight)
  csr_fill<<<(E1 + 255) / 256, 256, 0, stream>>>(src1, dst1, E1, off1, cur1, dinv1, cs1, cw1);
  csr_fill<<<(E2 + 255) / 256, 256, 0, stream>>>(src2, dst2, E2, off2, cur2, dinv2, cs2, cw2);
  // weight transposes: W[K][N] -> Wt[N][K]
  dim3 tb(32, 8);
  transpose_to_bf16<<<dim3(1024 / 32, 512 / 32), tb, 0, stream>>>(d_in[3], Wt11, 512, 1024, flag);
  transpose_to_bf16<<<dim3(1024 / 32, 512 / 32), tb, 0, stream>>>(d_in[5], Wt12, 512, 1024, flag);
  transpose_to_bf16<<<dim3(512 / 32, 1024 / 32), tb, 0, stream>>>(d_in[7], Wt21, 1024, 512, flag);
  transpose_to_bf16<<<dim3(512 / 32, 1024 / 32), tb, 0, stream>>>(d_in[9], Wt22, 1024, 512, flag);
  transpose_to_bf16<<<dim3(128 / 32, 512 / 32), tb, 0, stream>>>(d_in[11], Wt31, 512, 128, flag);
  transpose_to_bf16<<<dim3(128 / 32, 512 / 32), tb, 0, stream>>>(d_in[13], Wt32, 512, 128, flag);

  int mtiles = (n + 127) / 128;
  // ---- layer 1: 512 -> 1024
  gemm128<HT><<<dim3(1024 / 128, mtiles), 256, 0, stream>>>(Xb, Wt11, Ha, n, 512, 1024);
  gemm128<HT><<<dim3(1024 / 128, mtiles), 256, 0, stream>>>(Xb, Wt12, Hb, n, 512, 1024);
  agg_kernel<4, HT><<<n, 256, 0, stream>>>(Ha, Hb, off1, cs1, cw1, off2, cs2, cw2,
                                           dinv1, dinv2, bf_[0], bf_[1], awf[0], act, 1024,
                                           (const int*)nullptr);
  // ---- layer 2: 1024 -> 512
  gemm128<HT><<<dim3(512 / 128, mtiles), 256, 0, stream>>>(act, Wt21, Ha, n, 1024, 512);
  gemm128<HT><<<dim3(512 / 128, mtiles), 256, 0, stream>>>(act, Wt22, Hb, n, 1024, 512);
  agg_kernel<2, HT><<<n, 256, 0, stream>>>(Ha, Hb, off1, cs1, cw1, off2, cs2, cw2,
                                           dinv1, dinv2, bf_[2], bf_[3], awf[1], act, 512,
                                           (const int*)nullptr);
  // ---- layer 3: 512 -> 128
  gemm128<HT><<<dim3(128 / 128, mtiles), 256, 0, stream>>>(act, Wt31, Ha, n, 512, 128);
  gemm128<HT><<<dim3(128 / 128, mtiles), 256, 0, stream>>>(act, Wt32, Hb, n, 512, 128);
  agg_kernel<1, HT><<<n, 128, 0, stream>>>(Ha, Hb, off1, cs1, cw1, off2, cs2, cw2,
                                           dinv1, dinv2, bf_[4], bf_[5], awf[2], d_out, 128,
                                           flag);
}

extern "C" void kernel_launch(void* const* d_in, const int* in_sizes, int n_in,
                              void* d_out, int out_size, void* d_ws, size_t ws_size,
                              hipStream_t stream) {
  const void* X = d_in[0];
  const int* ei1 = (const int*)d_in[1];
  const int* ei2 = (const int*)d_in[2];
  const int n = in_sizes[0] / 512;
  const int E1 = in_sizes[1] / 2;
  const int E2 = in_sizes[2] / 2;
  const int* src1 = ei1;           const int* dst1 = ei1 + E1;
  const int* src2 = ei2;           const int* dst2 = ei2 + E2;

  auto rnd = [](size_t b) { return (b + 255) & ~(size_t)255; };
  size_t fixed = 256 + rnd((size_t)n * 4) * 4 + rnd((size_t)(n + 1) * 4) * 2 +
                 rnd((size_t)n * 4) * 2 +
                 rnd((size_t)E1 * 4) * 2 + rnd((size_t)E2 * 4) * 2 +
                 rnd((size_t)512 * 1024 * 2) * 2 + rnd((size_t)1024 * 512 * 2) * 2 +
                 rnd((size_t)512 * 128 * 2) * 2 +
                 rnd(1024 * 4) * 2 + rnd(512 * 4) * 2 + rnd(128 * 4) * 2 +
                 rnd(2048 * 4) + rnd(1024 * 4) + rnd(256 * 4) +
                 rnd((size_t)n * 512 * 2) + rnd((size_t)n * 1024 * 2);
  bool h_fp32 = ws_size >= fixed + 2 * rnd((size_t)n * 1024 * 4) + 65536;

  if (h_fp32)
    run_pipeline<float>(X, src1, dst1, E1, src2, dst2, E2, n, d_in, d_out, (char*)d_ws, stream);
  else
    run_pipeline<bf16>(X, src1, dst1, E1, src2, dst2, E2, n, d_in, d_out, (char*)d_ws, stream);
}

// Round 3
// 486.594 us; speedup vs baseline: 1.2617x; 1.2617x over previous
//
#include <hip/hip_runtime.h>
#include <hip/hip_bf16.h>
#include <math.h>

using bf16 = __hip_bfloat16;
typedef __attribute__((ext_vector_type(8))) short short8;
typedef __attribute__((ext_vector_type(4))) float floatx4;

// ---------------------------------------------------------------- helpers
__device__ inline void gl_lds16(const void* g, void* l) {
  __builtin_amdgcn_global_load_lds(
      (const __attribute__((address_space(1))) unsigned int*)g,
      (__attribute__((address_space(3))) unsigned int*)l,
      16, 0, 0);
}

__device__ inline void store_cast(float* d, float x) { *d = x; }
__device__ inline void store_cast(bf16* d, float x) { *d = __float2bfloat16(x); }
__device__ inline float load_f(const float* p) { return *p; }
__device__ inline float load_f(const bf16* p) { return __bfloat162float(*p); }
__device__ inline float eluf(float x) { return x > 0.f ? x : expm1f(x); }

// ---------------------------------------------------------------- dtype probe
// Inputs may be f32 or bf16. View node_feature as bf16: even-index elements
// are low mantissa halves if really f32 -> ~10% decode |x|>5e30. flag=1 -> f32.
__global__ void probe_dtype(const unsigned short* __restrict__ x, int* __restrict__ flag) {
  __shared__ int s;
  int t = threadIdx.x;
  if (t == 0) s = 0;
  __syncthreads();
  int bad = 0;
  for (int i = t; i < 1024; i += 256) {
    unsigned short h = x[2 * i];
    unsigned e = (h >> 7) & 0xFF;
    if (e >= 0xE5) bad = 1;
  }
  if (bad) atomicOr(&s, 1);
  __syncthreads();
  if (t == 0) flag[0] = s;
}

__global__ void to_bf16_kernel(const void* __restrict__ in, bf16* __restrict__ out,
                               int nelem, const int* __restrict__ flag) {
  int i = blockIdx.x * 256 + threadIdx.x;
  if (i >= nelem) return;
  if (*flag) out[i] = __float2bfloat16(((const float*)in)[i]);
  else       out[i] = ((const bf16*)in)[i];
}

// biases -> f32; aw -> softmaxed (w0,w1) pairs, one kernel.
__global__ void small_prep(
    const void* b11, const void* b12, const void* b21, const void* b22,
    const void* b31, const void* b32, const void* aw1, const void* aw2, const void* aw3,
    float* ob11, float* ob12, float* ob21, float* ob22, float* ob31, float* ob32,
    float* ow1, float* ow2, float* ow3, const int* __restrict__ flag) {
  const bool f32 = *flag != 0;
  auto cv = [&](const void* p, int i) -> float {
    return f32 ? ((const float*)p)[i] : __bfloat162float(((const bf16*)p)[i]);
  };
  int t = blockIdx.x * 256 + threadIdx.x;
  if (t < 1024) ob11[t] = cv(b11, t);
  else if (t < 2048) ob12[t - 1024] = cv(b12, t - 1024);
  else if (t < 2560) ob21[t - 2048] = cv(b21, t - 2048);
  else if (t < 3072) ob22[t - 2560] = cv(b22, t - 2560);
  else if (t < 3200) ob31[t - 3072] = cv(b31, t - 3072);
  else if (t < 3328) ob32[t - 3200] = cv(b32, t - 3200);
  else if (t < 4992) {
    int j = t - 3328;
    const void* src; float* dst; int jj;
    if (j < 1024)      { src = aw1; dst = ow1; jj = j; }
    else if (j < 1536) { src = aw2; dst = ow2; jj = j - 1024; }
    else               { src = aw3; dst = ow3; jj = j - 1536; }
    float e0 = cv(src, 2 * jj), e1 = cv(src, 2 * jj + 1);
    float mx = fmaxf(e0, e1);
    float w0 = expf(e0 - mx), w1 = expf(e1 - mx);
    float inv = 1.f / (w0 + w1);
    dst[2 * jj] = w0 * inv;
    dst[2 * jj + 1] = w1 * inv;
  }
}

// ---------------------------------------------------------------- graph prep
__global__ void deg_fused(const int* __restrict__ dst1, int E1,
                          const int* __restrict__ dst2, int E2,
                          int* __restrict__ deg1, int* __restrict__ deg2) {
  int e = blockIdx.x * 256 + threadIdx.x;
  if (e < E1) atomicAdd(&deg1[dst1[e]], 1);
  else if (e < E1 + E2) atomicAdd(&deg2[dst2[e - E1]], 1);
}

// blockIdx.x selects graph; serial chunked scan + dinv = rsqrt(deg+1)
__global__ void scan2_kernel(const int* __restrict__ deg1, int* __restrict__ off1,
                             float* __restrict__ dinv1,
                             const int* __restrict__ deg2, int* __restrict__ off2,
                             float* __restrict__ dinv2, int n) {
  const int* deg = blockIdx.x ? deg2 : deg1;
  int* off = blockIdx.x ? off2 : off1;
  float* dinv = blockIdx.x ? dinv2 : dinv1;
  __shared__ int s[1024];
  __shared__ int carry_s;
  int t = threadIdx.x;
  if (t == 0) carry_s = 0;
  __syncthreads();
  for (int base = 0; base < n; base += 1024) {
    int i = base + t;
    int orig = (i < n) ? deg[i] : 0;
    s[t] = orig;
    __syncthreads();
    for (int d = 1; d < 1024; d <<= 1) {
      int add = (t >= d) ? s[t - d] : 0;
      __syncthreads();
      s[t] += add;
      __syncthreads();
    }
    int incl = s[t];
    int carry = carry_s;
    if (i < n) {
      off[i]  = carry + incl - orig;
      dinv[i] = rsqrtf((float)(orig + 1));
    }
    __syncthreads();
    if (t == 1023) carry_s = carry + incl;
    __syncthreads();
  }
  if (t == 0) off[n] = carry_s;
}

__global__ void csr_fused(const int* __restrict__ src1, const int* __restrict__ dst1, int E1,
                          const int* __restrict__ src2, const int* __restrict__ dst2, int E2,
                          const int* __restrict__ off1, int* __restrict__ cur1,
                          const float* __restrict__ dinv1,
                          int* __restrict__ cs1, float* __restrict__ cw1,
                          const int* __restrict__ off2, int* __restrict__ cur2,
                          const float* __restrict__ dinv2,
                          int* __restrict__ cs2, float* __restrict__ cw2) {
  int e = blockIdx.x * 256 + threadIdx.x;
  if (e < E1) {
    int d = dst1[e], s = src1[e];
    int slot = off1[d] + atomicAdd(&cur1[d], 1);
    cs1[slot] = s;
    cw1[slot] = dinv1[s];
  } else if (e < E1 + E2) {
    int ee = e - E1;
    int d = dst2[ee], s = src2[ee];
    int slot = off2[d] + atomicAdd(&cur2[d], 1);
    cs2[slot] = s;
    cw2[slot] = dinv2[s];
  }
}

// W[K][N] -> Wt[N][K] (bf16 out). K,N multiples of 32.
__global__ void transpose_to_bf16(const void* __restrict__ in, bf16* __restrict__ out,
                                  int K, int N, const int* __restrict__ flag) {
  __shared__ bf16 tile[32][33];
  const bool f32 = *flag != 0;
  int bx = blockIdx.x * 32;  // N offset
  int by = blockIdx.y * 32;  // K offset
  int tx = threadIdx.x, ty = threadIdx.y;
#pragma unroll
  for (int i = 0; i < 32; i += 8) {
    size_t idx = (size_t)(by + ty + i) * N + (bx + tx);
    tile[ty + i][tx] = f32 ? __float2bfloat16(((const float*)in)[idx])
                           : ((const bf16*)in)[idx];
  }
  __syncthreads();
#pragma unroll
  for (int i = 0; i < 32; i += 8)
    out[(size_t)(bx + ty + i) * K + (by + tx)] = tile[tx][ty + i];
}

// ---------------------------------------------------------------- input-side agg (layer 1)
// outA[v] = dv1 * sum_{u in N1(v)} cw1*X[u] + dv1^2 * X[v]; same for set 2.
// X is [n,512] bf16 (10 MB -> L2-resident gather arena).
__global__ __launch_bounds__(256) void aggx_kernel(
    const bf16* __restrict__ X,
    const int* __restrict__ off1, const int* __restrict__ cs1, const float* __restrict__ cw1,
    const int* __restrict__ off2, const int* __restrict__ cs2, const float* __restrict__ cw2,
    const float* __restrict__ dinv1, const float* __restrict__ dinv2,
    bf16* __restrict__ outA, bf16* __restrict__ outB) {
  const int v = blockIdx.x;
  const int c2 = threadIdx.x * 2;  // channel pair
  float a0 = 0.f, a1 = 0.f, b0 = 0.f, b1 = 0.f;

  const int s1 = off1[v], e1 = off1[v + 1];
  for (int i = s1; i < e1; ++i) {
    const int u = cs1[i];
    const float w = cw1[i];
    __hip_bfloat162 h2 = *(const __hip_bfloat162*)(X + (size_t)u * 512 + c2);
    a0 += w * __bfloat162float(h2.x);
    a1 += w * __bfloat162float(h2.y);
  }
  const int s2 = off2[v], e2 = off2[v + 1];
  for (int i = s2; i < e2; ++i) {
    const int u = cs2[i];
    const float w = cw2[i];
    __hip_bfloat162 h2 = *(const __hip_bfloat162*)(X + (size_t)u * 512 + c2);
    b0 += w * __bfloat162float(h2.x);
    b1 += w * __bfloat162float(h2.y);
  }
  __hip_bfloat162 hs = *(const __hip_bfloat162*)(X + (size_t)v * 512 + c2);
  float xs0 = __bfloat162float(hs.x), xs1 = __bfloat162float(hs.y);
  const float dv1 = dinv1[v], dv2 = dinv2[v];

  __hip_bfloat162 ra, rb;
  ra.x = __float2bfloat16(dv1 * a0 + dv1 * dv1 * xs0);
  ra.y = __float2bfloat16(dv1 * a1 + dv1 * dv1 * xs1);
  rb.x = __float2bfloat16(dv2 * b0 + dv2 * dv2 * xs0);
  rb.y = __float2bfloat16(dv2 * b1 + dv2 * dv2 * xs1);
  *(__hip_bfloat162*)(outA + (size_t)v * 512 + c2) = ra;
  *(__hip_bfloat162*)(outB + (size_t)v * 512 + c2) = rb;
}

// ---------------------------------------------------------------- GEMM (m97-style)
// C[M][N] = A[M][K] @ Bt[N][K]^T, 128x128 tile, BK=32, 4 waves, 16x16x32 bf16 MFMA
template <typename CT>
__global__ __launch_bounds__(256) void gemm128(const bf16* __restrict__ A,
                                               const bf16* __restrict__ Bt,
                                               CT* __restrict__ C,
                                               int M, int K, int N) {
  __shared__ bf16 As[128 * 32];
  __shared__ bf16 Bs[128 * 32];
  const int tid = threadIdx.x;
  const int wave = tid >> 6;
  const int lane = tid & 63;
  const int quad = lane >> 4;
  const int l16 = lane & 15;
  const int m0 = blockIdx.y * 128;
  const int n0 = blockIdx.x * 128;
  const int wr = (wave >> 1) * 64;
  const int wc = (wave & 1) * 64;
  const int r_sub = lane >> 2;
  const int cb = (lane & 3) * 16;

  floatx4 acc[4][4];
#pragma unroll
  for (int i = 0; i < 4; i++)
#pragma unroll
    for (int j = 0; j < 4; j++) acc[i][j] = (floatx4){0.f, 0.f, 0.f, 0.f};

  for (int k0 = 0; k0 < K; k0 += 32) {
    __syncthreads();
#pragma unroll
    for (int j = 0; j < 2; ++j) {
      int p = wave * 2 + j;
      int ra = p * 16 + r_sub;
      int grow = m0 + ra; if (grow >= M) grow = M - 1;
      gl_lds16((const char*)(A + (size_t)grow * K + k0) + cb, (char*)As + p * 1024);
      int rb = n0 + p * 16 + r_sub;
      gl_lds16((const char*)(Bt + (size_t)rb * K + k0) + cb, (char*)Bs + p * 1024);
    }
    __syncthreads();

    short8 af[4], bfr[4];
#pragma unroll
    for (int i = 0; i < 4; i++)
      af[i] = *(const short8*)(As + (wr + i * 16 + l16) * 32 + quad * 8);
#pragma unroll
    for (int j = 0; j < 4; j++)
      bfr[j] = *(const short8*)(Bs + (wc + j * 16 + l16) * 32 + quad * 8);
#pragma unroll
    for (int i = 0; i < 4; i++)
#pragma unroll
      for (int j = 0; j < 4; j++)
        acc[i][j] = __builtin_amdgcn_mfma_f32_16x16x32_bf16(af[i], bfr[j], acc[i][j], 0, 0, 0);
  }

#pragma unroll
  for (int i = 0; i < 4; i++) {
#pragma unroll
    for (int r = 0; r < 4; r++) {
      int row = m0 + wr + i * 16 + quad * 4 + r;
      if (row < M) {
#pragma unroll
        for (int j = 0; j < 4; j++) {
          int col = n0 + wc + j * 16 + l16;
          store_cast(&C[(size_t)row * N + col], acc[i][j][r]);
        }
      }
    }
  }
}

// ---------------------------------------------------------------- layer-1 epilogue
// act = w0*elu(H1a + ba) + w1*elu(H1b + bb), elementwise, 2 channels/thread.
template <typename HT>
__global__ __launch_bounds__(256) void combine1_kernel(
    const HT* __restrict__ Ha, const HT* __restrict__ Hb,
    const float* __restrict__ ba, const float* __restrict__ bb,
    const float* __restrict__ w01, bf16* __restrict__ out, int total) {
  int i = blockIdx.x * 256 + threadIdx.x;
  int e = i * 2;
  if (e >= total) return;
  int c = e & 1023;
  float x0 = eluf(load_f(Ha + e) + ba[c]);
  float y0 = eluf(load_f(Hb + e) + bb[c]);
  float x1 = eluf(load_f(Ha + e + 1) + ba[c + 1]);
  float y1 = eluf(load_f(Hb + e + 1) + bb[c + 1]);
  __hip_bfloat162 r;
  r.x = __float2bfloat16(x0 * w01[2 * c] + y0 * w01[2 * c + 1]);
  r.y = __float2bfloat16(x1 * w01[2 * c + 2] + y1 * w01[2 * c + 3]);
  *(__hip_bfloat162*)(out + e) = r;
}

// ---------------------------------------------------------------- output-side agg (layers 2,3)
// out[v,c] = w0*elu(dv1*sum1 + dv1^2*Ha[v,c] + ba[c]) + w1*elu(dv2*sum2 + ...)
// Ha/Hb rows have leading dim ldH (concat GEMM output).
template <int CPT, typename HT>
__global__ __launch_bounds__(256) void agg_kernel(
    const HT* __restrict__ Ha, const HT* __restrict__ Hb, int ldH,
    const int* __restrict__ off1, const int* __restrict__ cs1, const float* __restrict__ cw1,
    const int* __restrict__ off2, const int* __restrict__ cs2, const float* __restrict__ cw2,
    const float* __restrict__ dinv1, const float* __restrict__ dinv2,
    const float* __restrict__ ba, const float* __restrict__ bb,
    const float* __restrict__ w01, void* __restrict__ out, int C,
    const int* __restrict__ outflag) {
  const int v = blockIdx.x;
  const int t = threadIdx.x;
  const int B = blockDim.x;
  const float dv1 = dinv1[v], dv2 = dinv2[v];
  float a1[CPT], a2[CPT];
#pragma unroll
  for (int j = 0; j < CPT; j++) { a1[j] = 0.f; a2[j] = 0.f; }

  const int s1 = off1[v], e1 = off1[v + 1];
  for (int i = s1; i < e1; ++i) {
    const int u = cs1[i];
    const float w = cw1[i];
    const HT* row = Ha + (size_t)u * ldH;
#pragma unroll
    for (int j = 0; j < CPT; j++) a1[j] += w * load_f(row + t + j * B);
  }
  const int s2 = off2[v], e2 = off2[v + 1];
  for (int i = s2; i < e2; ++i) {
    const int u = cs2[i];
    const float w = cw2[i];
    const HT* row = Hb + (size_t)u * ldH;
#pragma unroll
    for (int j = 0; j < CPT; j++) a2[j] += w * load_f(row + t + j * B);
  }

  const bool out_f32 = (outflag != nullptr) && (*outflag != 0);
  const HT* rva = Ha + (size_t)v * ldH;
  const HT* rvb = Hb + (size_t)v * ldH;
#pragma unroll
  for (int j = 0; j < CPT; j++) {
    int c = t + j * B;
    float x1 = eluf(dv1 * a1[j] + dv1 * dv1 * load_f(rva + c) + ba[c]);
    float x2 = eluf(dv2 * a2[j] + dv2 * dv2 * load_f(rvb + c) + bb[c]);
    float r = x1 * w01[2 * c] + x2 * w01[2 * c + 1];
    size_t oi = (size_t)v * C + c;
    if (out_f32) ((float*)out)[oi] = r;
    else         ((bf16*)out)[oi] = __float2bfloat16(r);
  }
}

// ---------------------------------------------------------------- host pipeline
template <typename HT>
static void run_pipeline(const void* X, const int* src1, const int* dst1, int E1,
                         const int* src2, const int* dst2, int E2, int n,
                         void* const* d_in, void* d_out, char* ws, hipStream_t stream) {
  auto rnd = [](size_t b) { return (b + 255) & ~(size_t)255; };
  char* p = ws;
  auto alloc = [&](size_t bytes) { char* r = p; p += rnd(bytes); return r; };

  int* flag = (int*)alloc(256);
  int* deg1 = (int*)alloc((size_t)n * 4);
  int* deg2 = (int*)alloc((size_t)n * 4);
  int* cur1 = (int*)alloc((size_t)n * 4);
  int* cur2 = (int*)alloc((size_t)n * 4);
  int* off1 = (int*)alloc((size_t)(n + 1) * 4);
  int* off2 = (int*)alloc((size_t)(n + 1) * 4);
  float* dinv1 = (float*)alloc((size_t)n * 4);
  float* dinv2 = (float*)alloc((size_t)n * 4);
  int* cs1 = (int*)alloc((size_t)E1 * 4);
  float* cw1 = (float*)alloc((size_t)E1 * 4);
  int* cs2 = (int*)alloc((size_t)E2 * 4);
  float* cw2 = (float*)alloc((size_t)E2 * 4);
  bf16* Wt11 = (bf16*)alloc((size_t)512 * 1024 * 2);
  bf16* Wt12 = (bf16*)alloc((size_t)512 * 1024 * 2);
  bf16* Wt2cat = (bf16*)alloc((size_t)1024 * 1024 * 2);  // [512 W21^T | 512 W22^T] x K=1024
  bf16* Wt3cat = (bf16*)alloc((size_t)256 * 512 * 2);    // [128 W31^T | 128 W32^T] x K=512
  float* bf_[6]; int bsz[6] = {1024, 1024, 512, 512, 128, 128};
  for (int i = 0; i < 6; i++) bf_[i] = (float*)alloc((size_t)bsz[i] * 4);
  float* w01_[3]; int asz[3] = {2048, 1024, 256};
  for (int i = 0; i < 3; i++) w01_[i] = (float*)alloc((size_t)asz[i] * 4);
  bf16* Xb = (bf16*)alloc((size_t)n * 512 * 2);
  bf16* aggXa = (bf16*)alloc((size_t)n * 512 * 2);
  bf16* aggXb = (bf16*)alloc((size_t)n * 512 * 2);
  HT* H1a = (HT*)alloc((size_t)n * 1024 * sizeof(HT));
  HT* H1b = (HT*)alloc((size_t)n * 1024 * sizeof(HT));
  bf16* act1 = (bf16*)alloc((size_t)n * 1024 * 2);
  bf16* act2 = (bf16*)alloc((size_t)n * 512 * 2);
  HT* H2cat = H1a;                 // reuse: H1a dead after combine1
  HT* H3cat = H1b;                 // reuse: H1b dead after gemm2 reads act1

  probe_dtype<<<1, 256, 0, stream>>>((const unsigned short*)X, flag);
  hipMemsetAsync(deg1, 0, rnd((size_t)n * 4) * 4, stream);  // deg1,deg2,cur1,cur2

  // conversions
  to_bf16_kernel<<<(n * 512 + 255) / 256, 256, 0, stream>>>(X, Xb, n * 512, flag);
  small_prep<<<20, 256, 0, stream>>>(d_in[4], d_in[6], d_in[8], d_in[10], d_in[12], d_in[14],
                                     d_in[15], d_in[16], d_in[17],
                                     bf_[0], bf_[1], bf_[2], bf_[3], bf_[4], bf_[5],
                                     w01_[0], w01_[1], w01_[2], flag);

  // graph prep
  int Etot = E1 + E2;
  deg_fused<<<(Etot + 255) / 256, 256, 0, stream>>>(dst1, E1, dst2, E2, deg1, deg2);
  scan2_kernel<<<2, 1024, 0, stream>>>(deg1, off1, dinv1, deg2, off2, dinv2, n);
  csr_fused<<<(Etot + 255) / 256, 256, 0, stream>>>(src1, dst1, E1, src2, dst2, E2,
                                                    off1, cur1, dinv1, cs1, cw1,
                                                    off2, cur2, dinv2, cs2, cw2);

  // weight transposes (into concat buffers for layers 2,3)
  dim3 tb(32, 8);
  transpose_to_bf16<<<dim3(32, 16), tb, 0, stream>>>(d_in[3], Wt11, 512, 1024, flag);
  transpose_to_bf16<<<dim3(32, 16), tb, 0, stream>>>(d_in[5], Wt12, 512, 1024, flag);
  transpose_to_bf16<<<dim3(16, 32), tb, 0, stream>>>(d_in[7], Wt2cat, 1024, 512, flag);
  transpose_to_bf16<<<dim3(16, 32), tb, 0, stream>>>(d_in[9], Wt2cat + (size_t)512 * 1024, 1024, 512, flag);
  transpose_to_bf16<<<dim3(4, 16), tb, 0, stream>>>(d_in[11], Wt3cat, 512, 128, flag);
  transpose_to_bf16<<<dim3(4, 16), tb, 0, stream>>>(d_in[13], Wt3cat + (size_t)128 * 512, 512, 128, flag);

  const int mtiles = (n + 127) / 128;
  // ---- layer 1: input-side aggregation (X gather arena = 10 MB, L2-resident)
  aggx_kernel<<<n, 256, 0, stream>>>(Xb, off1, cs1, cw1, off2, cs2, cw2,
                                     dinv1, dinv2, aggXa, aggXb);
  gemm128<HT><<<dim3(8, mtiles), 256, 0, stream>>>(aggXa, Wt11, H1a, n, 512, 1024);
  gemm128<HT><<<dim3(8, mtiles), 256, 0, stream>>>(aggXb, Wt12, H1b, n, 512, 1024);
  combine1_kernel<HT><<<(n * 1024 / 2 + 255) / 256, 256, 0, stream>>>(
      H1a, H1b, bf_[0], bf_[1], w01_[0], act1, n * 1024);
  // ---- layer 2: concat GEMM + output-side agg
  gemm128<HT><<<dim3(8, mtiles), 256, 0, stream>>>(act1, Wt2cat, H2cat, n, 1024, 1024);
  agg_kernel<2, HT><<<n, 256, 0, stream>>>(H2cat, H2cat + 512, 1024,
                                           off1, cs1, cw1, off2, cs2, cw2, dinv1, dinv2,
                                           bf_[2], bf_[3], w01_[1], act2, 512,
                                           (const int*)nullptr);
  // ---- layer 3: concat GEMM + output-side agg -> d_out
  gemm128<HT><<<dim3(2, mtiles), 256, 0, stream>>>(act2, Wt3cat, H3cat, n, 512, 256);
  agg_kernel<1, HT><<<n, 128, 0, stream>>>(H3cat, H3cat + 128, 256,
                                           off1, cs1, cw1, off2, cs2, cw2, dinv1, dinv2,
                                           bf_[4], bf_[5], w01_[2], d_out, 128, flag);
}

extern "C" void kernel_launch(void* const* d_in, const int* in_sizes, int n_in,
                              void* d_out, int out_size, void* d_ws, size_t ws_size,
                              hipStream_t stream) {
  const void* X = d_in[0];
  const int* ei1 = (const int*)d_in[1];
  const int* ei2 = (const int*)d_in[2];
  const int n = in_sizes[0] / 512;
  const int E1 = in_sizes[1] / 2;
  const int E2 = in_sizes[2] / 2;
  const int* src1 = ei1;           const int* dst1 = ei1 + E1;
  const int* src2 = ei2;           const int* dst2 = ei2 + E2;

  auto rnd = [](size_t b) { return (b + 255) & ~(size_t)255; };
  size_t fixed = 256 + rnd((size_t)n * 4) * 4 + rnd((size_t)(n + 1) * 4) * 2 +
                 rnd((size_t)n * 4) * 2 +
                 rnd((size_t)E1 * 4) * 2 + rnd((size_t)E2 * 4) * 2 +
                 rnd((size_t)512 * 1024 * 2) * 2 + rnd((size_t)1024 * 1024 * 2) +
                 rnd((size_t)256 * 512 * 2) +
                 rnd(1024 * 4) * 2 + rnd(512 * 4) * 2 + rnd(128 * 4) * 2 +
                 rnd(2048 * 4) + rnd(1024 * 4) + rnd(256 * 4) +
                 rnd((size_t)n * 512 * 2) * 3 +            // Xb, aggXa, aggXb
                 rnd((size_t)n * 1024 * 2) + rnd((size_t)n * 512 * 2);  // act1, act2
  bool h_fp32 = ws_size >= fixed + 2 * rnd((size_t)n * 1024 * 4) + 65536;

  if (h_fp32)
    run_pipeline<float>(X, src1, dst1, E1, src2, dst2, E2, n, d_in, d_out, (char*)d_ws, stream);
  else
    run_pipeline<bf16>(X, src1, dst1, E1, src2, dst2, E2, n, d_in, d_out, (char*)d_ws, stream);
}

// Round 4
// 466.038 us; speedup vs baseline: 1.3174x; 1.0441x over previous
//
#include <hip/hip_runtime.h>
#include <hip/hip_bf16.h>
#include <math.h>

using bf16 = __hip_bfloat16;
typedef __attribute__((ext_vector_type(8))) short short8;
typedef __attribute__((ext_vector_type(4))) float floatx4;

// ---------------------------------------------------------------- helpers
__device__ inline void gl_lds16(const void* g, void* l) {
  __builtin_amdgcn_global_load_lds(
      (const __attribute__((address_space(1))) unsigned int*)g,
      (__attribute__((address_space(3))) unsigned int*)l,
      16, 0, 0);
}
__device__ inline float eluf(float x) { return x > 0.f ? x : expm1f(x); }
__device__ inline float bl(const __hip_bfloat162& h, int i) {
  return i ? __bfloat162float(h.y) : __bfloat162float(h.x);
}

// ---------------------------------------------------------------- dtype probe
// Inputs may be f32 or bf16. View node_feature as bf16: even-index elements
// are low mantissa halves if really f32 -> ~10% decode |x|>5e30. flag=1 -> f32.
__global__ void probe_dtype(const unsigned short* __restrict__ x, int* __restrict__ flag) {
  __shared__ int s;
  int t = threadIdx.x;
  if (t == 0) s = 0;
  __syncthreads();
  int bad = 0;
  for (int i = t; i < 1024; i += 256) {
    unsigned short h = x[2 * i];
    unsigned e = (h >> 7) & 0xFF;
    if (e >= 0xE5) bad = 1;
  }
  if (bad) atomicOr(&s, 1);
  __syncthreads();
  if (t == 0) flag[0] = s;
}

__global__ void to_bf16_kernel(const void* __restrict__ in, bf16* __restrict__ out,
                               int nelem, const int* __restrict__ flag) {
  int i = blockIdx.x * 256 + threadIdx.x;
  if (i >= nelem) return;
  if (*flag) out[i] = __float2bfloat16(((const float*)in)[i]);
  else       out[i] = ((const bf16*)in)[i];
}

// biases -> f32; aw -> softmaxed (w0,w1) pairs, one kernel.
__global__ void small_prep(
    const void* b11, const void* b12, const void* b21, const void* b22,
    const void* b31, const void* b32, const void* aw1, const void* aw2, const void* aw3,
    float* ob11, float* ob12, float* ob21, float* ob22, float* ob31, float* ob32,
    float* ow1, float* ow2, float* ow3, const int* __restrict__ flag) {
  const bool f32 = *flag != 0;
  auto cv = [&](const void* p, int i) -> float {
    return f32 ? ((const float*)p)[i] : __bfloat162float(((const bf16*)p)[i]);
  };
  int t = blockIdx.x * 256 + threadIdx.x;
  if (t < 1024) ob11[t] = cv(b11, t);
  else if (t < 2048) ob12[t - 1024] = cv(b12, t - 1024);
  else if (t < 2560) ob21[t - 2048] = cv(b21, t - 2048);
  else if (t < 3072) ob22[t - 2560] = cv(b22, t - 2560);
  else if (t < 3200) ob31[t - 3072] = cv(b31, t - 3072);
  else if (t < 3328) ob32[t - 3200] = cv(b32, t - 3200);
  else if (t < 4992) {
    int j = t - 3328;
    const void* src; float* dst; int jj;
    if (j < 1024)      { src = aw1; dst = ow1; jj = j; }
    else if (j < 1536) { src = aw2; dst = ow2; jj = j - 1024; }
    else               { src = aw3; dst = ow3; jj = j - 1536; }
    float e0 = cv(src, 2 * jj), e1 = cv(src, 2 * jj + 1);
    float mx = fmaxf(e0, e1);
    float w0 = expf(e0 - mx), w1 = expf(e1 - mx);
    float inv = 1.f / (w0 + w1);
    dst[2 * jj] = w0 * inv;
    dst[2 * jj + 1] = w1 * inv;
  }
}

// ---------------------------------------------------------------- graph prep
__global__ void deg_fused(const int* __restrict__ dst1, int E1,
                          const int* __restrict__ dst2, int E2,
                          int* __restrict__ deg1, int* __restrict__ deg2) {
  int e = blockIdx.x * 256 + threadIdx.x;
  if (e < E1) atomicAdd(&deg1[dst1[e]], 1);
  else if (e < E1 + E2) atomicAdd(&deg2[dst2[e - E1]], 1);
}

__global__ void scan2_kernel(const int* __restrict__ deg1, int* __restrict__ off1,
                             float* __restrict__ dinv1,
                             const int* __restrict__ deg2, int* __restrict__ off2,
                             float* __restrict__ dinv2, int n) {
  const int* deg = blockIdx.x ? deg2 : deg1;
  int* off = blockIdx.x ? off2 : off1;
  float* dinv = blockIdx.x ? dinv2 : dinv1;
  __shared__ int s[1024];
  __shared__ int carry_s;
  int t = threadIdx.x;
  if (t == 0) carry_s = 0;
  __syncthreads();
  for (int base = 0; base < n; base += 1024) {
    int i = base + t;
    int orig = (i < n) ? deg[i] : 0;
    s[t] = orig;
    __syncthreads();
    for (int d = 1; d < 1024; d <<= 1) {
      int add = (t >= d) ? s[t - d] : 0;
      __syncthreads();
      s[t] += add;
      __syncthreads();
    }
    int incl = s[t];
    int carry = carry_s;
    if (i < n) {
      off[i]  = carry + incl - orig;
      dinv[i] = rsqrtf((float)(orig + 1));
    }
    __syncthreads();
    if (t == 1023) carry_s = carry + incl;
    __syncthreads();
  }
  if (t == 0) off[n] = carry_s;
}

__global__ void csr_fused(const int* __restrict__ src1, const int* __restrict__ dst1, int E1,
                          const int* __restrict__ src2, const int* __restrict__ dst2, int E2,
                          const int* __restrict__ off1, int* __restrict__ cur1,
                          const float* __restrict__ dinv1,
                          int* __restrict__ cs1, float* __restrict__ cw1,
                          const int* __restrict__ off2, int* __restrict__ cur2,
                          const float* __restrict__ dinv2,
                          int* __restrict__ cs2, float* __restrict__ cw2) {
  int e = blockIdx.x * 256 + threadIdx.x;
  if (e < E1) {
    int d = dst1[e], s = src1[e];
    int slot = off1[d] + atomicAdd(&cur1[d], 1);
    cs1[slot] = s;
    cw1[slot] = dinv1[s];
  } else if (e < E1 + E2) {
    int ee = e - E1;
    int d = dst2[ee], s = src2[ee];
    int slot = off2[d] + atomicAdd(&cur2[d], 1);
    cs2[slot] = s;
    cw2[slot] = dinv2[s];
  }
}

// All six W[K][N] -> Wt[N][K] transposes in one dispatch.
__global__ void transpose_all(const void* W11, const void* W12, const void* W21,
                              const void* W22, const void* W31, const void* W32,
                              bf16* Wt11, bf16* Wt12, bf16* Wt2cat, bf16* Wt3cat,
                              const int* __restrict__ flag) {
  __shared__ bf16 tile[32][33];
  const bool f32 = *flag != 0;
  int b = blockIdx.x;
  const void* in; bf16* out; int K, N, tt;
  if (b < 512)       { in = W11; out = Wt11; K = 512;  N = 1024; tt = b; }
  else if (b < 1024) { in = W12; out = Wt12; K = 512;  N = 1024; tt = b - 512; }
  else if (b < 1536) { in = W21; out = Wt2cat; K = 1024; N = 512; tt = b - 1024; }
  else if (b < 2048) { in = W22; out = Wt2cat + (size_t)512 * 1024; K = 1024; N = 512; tt = b - 1536; }
  else if (b < 2112) { in = W31; out = Wt3cat; K = 512; N = 128; tt = b - 2048; }
  else               { in = W32; out = Wt3cat + (size_t)128 * 512; K = 512; N = 128; tt = b - 2112; }
  int tilesx = N / 32;
  int bx = (tt % tilesx) * 32;
  int by = (tt / tilesx) * 32;
  int tx = threadIdx.x, ty = threadIdx.y;
#pragma unroll
  for (int i = 0; i < 32; i += 8) {
    size_t idx = (size_t)(by + ty + i) * N + (bx + tx);
    tile[ty + i][tx] = f32 ? __float2bfloat16(((const float*)in)[idx])
                           : ((const bf16*)in)[idx];
  }
  __syncthreads();
#pragma unroll
  for (int i = 0; i < 32; i += 8)
    out[(size_t)(bx + ty + i) * K + (by + tx)] = tile[tx][ty + i];
}

// ---------------------------------------------------------------- input-side agg (layer 1)
__global__ __launch_bounds__(256) void aggx_kernel(
    const bf16* __restrict__ X,
    const int* __restrict__ off1, const int* __restrict__ cs1, const float* __restrict__ cw1,
    const int* __restrict__ off2, const int* __restrict__ cs2, const float* __restrict__ cw2,
    const float* __restrict__ dinv1, const float* __restrict__ dinv2,
    bf16* __restrict__ outA, bf16* __restrict__ outB) {
  const int v = blockIdx.x;
  const int c2 = threadIdx.x * 2;
  float a0 = 0.f, a1 = 0.f, b0 = 0.f, b1 = 0.f;

  const int s1 = off1[v], e1 = off1[v + 1];
  for (int i = s1; i < e1; ++i) {
    const int u = cs1[i];
    const float w = cw1[i];
    __hip_bfloat162 h2 = *(const __hip_bfloat162*)(X + (size_t)u * 512 + c2);
    a0 += w * __bfloat162float(h2.x);
    a1 += w * __bfloat162float(h2.y);
  }
  const int s2 = off2[v], e2 = off2[v + 1];
  for (int i = s2; i < e2; ++i) {
    const int u = cs2[i];
    const float w = cw2[i];
    __hip_bfloat162 h2 = *(const __hip_bfloat162*)(X + (size_t)u * 512 + c2);
    b0 += w * __bfloat162float(h2.x);
    b1 += w * __bfloat162float(h2.y);
  }
  __hip_bfloat162 hs = *(const __hip_bfloat162*)(X + (size_t)v * 512 + c2);
  float xs0 = __bfloat162float(hs.x), xs1 = __bfloat162float(hs.y);
  const float dv1 = dinv1[v], dv2 = dinv2[v];

  __hip_bfloat162 ra, rb;
  ra.x = __float2bfloat16(dv1 * a0 + dv1 * dv1 * xs0);
  ra.y = __float2bfloat16(dv1 * a1 + dv1 * dv1 * xs1);
  rb.x = __float2bfloat16(dv2 * b0 + dv2 * dv2 * xs0);
  rb.y = __float2bfloat16(dv2 * b1 + dv2 * dv2 * xs1);
  *(__hip_bfloat162*)(outA + (size_t)v * 512 + c2) = ra;
  *(__hip_bfloat162*)(outB + (size_t)v * 512 + c2) = rb;
}

// ---------------------------------------------------------------- GEMM body (m97-style)
// C[M][N] = A[M][K] @ Bt[N][K]^T, 128x128 tile, bf16 out.
__device__ inline void gemm_body(const bf16* __restrict__ A, const bf16* __restrict__ Bt,
                                 bf16* __restrict__ C, int M, int K, int N,
                                 int m0, int n0) {
  __shared__ bf16 As[128 * 32];
  __shared__ bf16 Bs[128 * 32];
  const int tid = threadIdx.x;
  const int wave = tid >> 6;
  const int lane = tid & 63;
  const int quad = lane >> 4;
  const int l16 = lane & 15;
  const int wr = (wave >> 1) * 64;
  const int wc = (wave & 1) * 64;
  const int r_sub = lane >> 2;
  const int cb = (lane & 3) * 16;

  floatx4 acc[4][4];
#pragma unroll
  for (int i = 0; i < 4; i++)
#pragma unroll
    for (int j = 0; j < 4; j++) acc[i][j] = (floatx4){0.f, 0.f, 0.f, 0.f};

  for (int k0 = 0; k0 < K; k0 += 32) {
    __syncthreads();
#pragma unroll
    for (int j = 0; j < 2; ++j) {
      int p = wave * 2 + j;
      int ra = p * 16 + r_sub;
      int grow = m0 + ra; if (grow >= M) grow = M - 1;
      gl_lds16((const char*)(A + (size_t)grow * K + k0) + cb, (char*)As + p * 1024);
      int rb = n0 + p * 16 + r_sub;
      gl_lds16((const char*)(Bt + (size_t)rb * K + k0) + cb, (char*)Bs + p * 1024);
    }
    __syncthreads();

    short8 af[4], bfr[4];
#pragma unroll
    for (int i = 0; i < 4; i++)
      af[i] = *(const short8*)(As + (wr + i * 16 + l16) * 32 + quad * 8);
#pragma unroll
    for (int j = 0; j < 4; j++)
      bfr[j] = *(const short8*)(Bs + (wc + j * 16 + l16) * 32 + quad * 8);
#pragma unroll
    for (int i = 0; i < 4; i++)
#pragma unroll
      for (int j = 0; j < 4; j++)
        acc[i][j] = __builtin_amdgcn_mfma_f32_16x16x32_bf16(af[i], bfr[j], acc[i][j], 0, 0, 0);
  }

#pragma unroll
  for (int i = 0; i < 4; i++) {
#pragma unroll
    for (int r = 0; r < 4; r++) {
      int row = m0 + wr + i * 16 + quad * 4 + r;
      if (row < M) {
#pragma unroll
        for (int j = 0; j < 4; j++) {
          int col = n0 + wc + j * 16 + l16;
          C[(size_t)row * N + col] = __float2bfloat16(acc[i][j][r]);
        }
      }
    }
  }
}

__global__ __launch_bounds__(256) void gemm128(const bf16* __restrict__ A,
                                               const bf16* __restrict__ Bt,
                                               bf16* __restrict__ C, int M, int K, int N) {
  gemm_body(A, Bt, C, M, K, N, blockIdx.y * 128, blockIdx.x * 128);
}

// two independent GEMMs (same M,K,N) in one dispatch: blockIdx.y selects half
__global__ __launch_bounds__(256) void gemm128_dual(
    const bf16* __restrict__ A0, const bf16* __restrict__ Bt0, bf16* __restrict__ C0,
    const bf16* __restrict__ A1, const bf16* __restrict__ Bt1, bf16* __restrict__ C1,
    int M, int K, int N, int mtiles) {
  int half = blockIdx.y / mtiles;
  int by = blockIdx.y % mtiles;
  const bf16* A = half ? A1 : A0;
  const bf16* Bt = half ? Bt1 : Bt0;
  bf16* C = half ? C1 : C0;
  gemm_body(A, Bt, C, M, K, N, by * 128, blockIdx.x * 128);
}

// ---------------------------------------------------------------- layer-1 epilogue
__global__ __launch_bounds__(256) void combine1_kernel(
    const bf16* __restrict__ Ha, const bf16* __restrict__ Hb,
    const float* __restrict__ ba, const float* __restrict__ bb,
    const float* __restrict__ w01, bf16* __restrict__ out, int total) {
  int e = (blockIdx.x * 256 + threadIdx.x) * 2;
  if (e >= total) return;
  int c = e & 1023;
  __hip_bfloat162 ha = *(const __hip_bfloat162*)(Ha + e);
  __hip_bfloat162 hb = *(const __hip_bfloat162*)(Hb + e);
  float x0 = eluf(__bfloat162float(ha.x) + ba[c]);
  float y0 = eluf(__bfloat162float(hb.x) + bb[c]);
  float x1 = eluf(__bfloat162float(ha.y) + ba[c + 1]);
  float y1 = eluf(__bfloat162float(hb.y) + bb[c + 1]);
  __hip_bfloat162 r;
  r.x = __float2bfloat16(x0 * w01[2 * c] + y0 * w01[2 * c + 1]);
  r.y = __float2bfloat16(x1 * w01[2 * c + 2] + y1 * w01[2 * c + 3]);
  *(__hip_bfloat162*)(out + e) = r;
}

// ---------------------------------------------------------------- output-side agg (layers 2,3)
// C channels per edge-set; G vertices per block; block = G*C/2 threads.
// Ha/Hb rows have leading dim ldH (bf16). outflag: null->bf16, else f32/bf16.
template <int C, int G>
__global__ __launch_bounds__(256) void agg_out_kernel(
    const bf16* __restrict__ Ha, const bf16* __restrict__ Hb, int ldH,
    const int* __restrict__ off1, const int* __restrict__ cs1, const float* __restrict__ cw1,
    const int* __restrict__ off2, const int* __restrict__ cs2, const float* __restrict__ cw2,
    const float* __restrict__ dinv1, const float* __restrict__ dinv2,
    const float* __restrict__ ba, const float* __restrict__ bb,
    const float* __restrict__ w01, void* __restrict__ out, int n,
    const int* __restrict__ outflag) {
  const int TPV = C / 2;
  const int t = threadIdx.x;
  const int g = t / TPV;
  const int l = t % TPV;
  const int v = blockIdx.x * G + g;
  if (v >= n) return;
  const int c = 2 * l;
  const float dv1 = dinv1[v], dv2 = dinv2[v];
  float a0 = 0.f, a1 = 0.f, b0 = 0.f, b1 = 0.f;

  const int s1 = off1[v], e1 = off1[v + 1];
  for (int i = s1; i < e1; ++i) {
    const int u = cs1[i];
    const float w = cw1[i];
    __hip_bfloat162 h = *(const __hip_bfloat162*)(Ha + (size_t)u * ldH + c);
    a0 += w * __bfloat162float(h.x);
    a1 += w * __bfloat162float(h.y);
  }
  const int s2 = off2[v], e2 = off2[v + 1];
  for (int i = s2; i < e2; ++i) {
    const int u = cs2[i];
    const float w = cw2[i];
    __hip_bfloat162 h = *(const __hip_bfloat162*)(Hb + (size_t)u * ldH + c);
    b0 += w * __bfloat162float(h.x);
    b1 += w * __bfloat162float(h.y);
  }
  __hip_bfloat162 sa = *(const __hip_bfloat162*)(Ha + (size_t)v * ldH + c);
  __hip_bfloat162 sb = *(const __hip_bfloat162*)(Hb + (size_t)v * ldH + c);

  float x0 = eluf(dv1 * a0 + dv1 * dv1 * __bfloat162float(sa.x) + ba[c]);
  float x1 = eluf(dv1 * a1 + dv1 * dv1 * __bfloat162float(sa.y) + ba[c + 1]);
  float y0 = eluf(dv2 * b0 + dv2 * dv2 * __bfloat162float(sb.x) + bb[c]);
  float y1 = eluf(dv2 * b1 + dv2 * dv2 * __bfloat162float(sb.y) + bb[c + 1]);
  float r0 = x0 * w01[2 * c] + y0 * w01[2 * c + 1];
  float r1 = x1 * w01[2 * c + 2] + y1 * w01[2 * c + 3];

  const bool out_f32 = (outflag != nullptr) && (*outflag != 0);
  size_t oi = (size_t)v * C + c;
  if (out_f32) {
    ((float*)out)[oi] = r0;
    ((float*)out)[oi + 1] = r1;
  } else {
    __hip_bfloat162 r;
    r.x = __float2bfloat16(r0);
    r.y = __float2bfloat16(r1);
    *(__hip_bfloat162*)((bf16*)out + oi) = r;
  }
}

// ---------------------------------------------------------------- host pipeline
extern "C" void kernel_launch(void* const* d_in, const int* in_sizes, int n_in,
                              void* d_out, int out_size, void* d_ws, size_t ws_size,
                              hipStream_t stream) {
  const void* X = d_in[0];
  const int* ei1 = (const int*)d_in[1];
  const int* ei2 = (const int*)d_in[2];
  const int n = in_sizes[0] / 512;
  const int E1 = in_sizes[1] / 2;
  const int E2 = in_sizes[2] / 2;
  const int* src1 = ei1;           const int* dst1 = ei1 + E1;
  const int* src2 = ei2;           const int* dst2 = ei2 + E2;

  auto rnd = [](size_t b) { return (b + 255) & ~(size_t)255; };
  char* p = (char*)d_ws;
  auto alloc = [&](size_t bytes) { char* r = p; p += rnd(bytes); return r; };

  int* flag = (int*)alloc(256);
  int* deg1 = (int*)alloc((size_t)n * 4);
  int* deg2 = (int*)alloc((size_t)n * 4);
  int* cur1 = (int*)alloc((size_t)n * 4);
  int* cur2 = (int*)alloc((size_t)n * 4);
  int* off1 = (int*)alloc((size_t)(n + 1) * 4);
  int* off2 = (int*)alloc((size_t)(n + 1) * 4);
  float* dinv1 = (float*)alloc((size_t)n * 4);
  float* dinv2 = (float*)alloc((size_t)n * 4);
  int* cs1 = (int*)alloc((size_t)E1 * 4);
  float* cw1 = (float*)alloc((size_t)E1 * 4);
  int* cs2 = (int*)alloc((size_t)E2 * 4);
  float* cw2 = (float*)alloc((size_t)E2 * 4);
  bf16* Wt11 = (bf16*)alloc((size_t)512 * 1024 * 2);
  bf16* Wt12 = (bf16*)alloc((size_t)512 * 1024 * 2);
  bf16* Wt2cat = (bf16*)alloc((size_t)1024 * 1024 * 2);
  bf16* Wt3cat = (bf16*)alloc((size_t)256 * 512 * 2);
  float* bf_[6]; int bsz[6] = {1024, 1024, 512, 512, 128, 128};
  for (int i = 0; i < 6; i++) bf_[i] = (float*)alloc((size_t)bsz[i] * 4);
  float* w01_[3]; int asz[3] = {2048, 1024, 256};
  for (int i = 0; i < 3; i++) w01_[i] = (float*)alloc((size_t)asz[i] * 4);
  bf16* Xb = (bf16*)alloc((size_t)n * 512 * 2);
  bf16* aggXa = (bf16*)alloc((size_t)n * 512 * 2);
  bf16* aggXb = (bf16*)alloc((size_t)n * 512 * 2);
  bf16* H1a = (bf16*)alloc((size_t)n * 1024 * 2);
  bf16* H1b = (bf16*)alloc((size_t)n * 1024 * 2);
  bf16* act1 = (bf16*)alloc((size_t)n * 1024 * 2);
  bf16* H2cat = H1a;   // dead after combine1
  bf16* act2 = aggXa;  // dead after layer-1 GEMM
  bf16* H3cat = H1b;   // dead after layer-2 GEMM reads act1... (H1b dead after combine1)

  probe_dtype<<<1, 256, 0, stream>>>((const unsigned short*)X, flag);
  hipMemsetAsync(deg1, 0, rnd((size_t)n * 4) * 4, stream);  // deg1,deg2,cur1,cur2

  to_bf16_kernel<<<(n * 512 + 255) / 256, 256, 0, stream>>>(X, Xb, n * 512, flag);
  small_prep<<<20, 256, 0, stream>>>(d_in[4], d_in[6], d_in[8], d_in[10], d_in[12], d_in[14],
                                     d_in[15], d_in[16], d_in[17],
                                     bf_[0], bf_[1], bf_[2], bf_[3], bf_[4], bf_[5],
                                     w01_[0], w01_[1], w01_[2], flag);

  int Etot = E1 + E2;
  deg_fused<<<(Etot + 255) / 256, 256, 0, stream>>>(dst1, E1, dst2, E2, deg1, deg2);
  scan2_kernel<<<2, 1024, 0, stream>>>(deg1, off1, dinv1, deg2, off2, dinv2, n);
  csr_fused<<<(Etot + 255) / 256, 256, 0, stream>>>(src1, dst1, E1, src2, dst2, E2,
                                                    off1, cur1, dinv1, cs1, cw1,
                                                    off2, cur2, dinv2, cs2, cw2);

  transpose_all<<<2176, dim3(32, 8), 0, stream>>>(d_in[3], d_in[5], d_in[7], d_in[9],
                                                  d_in[11], d_in[13],
                                                  Wt11, Wt12, Wt2cat, Wt3cat, flag);

  const int mtiles = (n + 127) / 128;
  // ---- layer 1: input-side aggregation, dual GEMM, elementwise combine
  aggx_kernel<<<n, 256, 0, stream>>>(Xb, off1, cs1, cw1, off2, cs2, cw2,
                                     dinv1, dinv2, aggXa, aggXb);
  gemm128_dual<<<dim3(8, 2 * mtiles), 256, 0, stream>>>(aggXa, Wt11, H1a,
                                                        aggXb, Wt12, H1b,
                                                        n, 512, 1024, mtiles);
  combine1_kernel<<<(n * 1024 / 2 + 255) / 256, 256, 0, stream>>>(
      H1a, H1b, bf_[0], bf_[1], w01_[0], act1, n * 1024);
  // ---- layer 2: concat GEMM (bf16 out) + output-side agg
  gemm128<<<dim3(8, mtiles), 256, 0, stream>>>(act1, Wt2cat, H2cat, n, 1024, 1024);
  agg_out_kernel<512, 1><<<n, 256, 0, stream>>>(H2cat, H2cat + 512, 1024,
                                                off1, cs1, cw1, off2, cs2, cw2,
                                                dinv1, dinv2, bf_[2], bf_[3], w01_[1],
                                                act2, n, (const int*)nullptr);
  // ---- layer 3: concat GEMM (bf16 out) + output-side agg -> d_out
  gemm128<<<dim3(2, mtiles), 256, 0, stream>>>(act2, Wt3cat, H3cat, n, 512, 256);
  agg_out_kernel<128, 4><<<(n + 3) / 4, 256, 0, stream>>>(H3cat, H3cat + 128, 256,
                                                          off1, cs1, cw1, off2, cs2, cw2,
                                                          dinv1, dinv2, bf_[4], bf_[5], w01_[2],
                                                          d_out, n, flag);
}

// Round 5
// 423.925 us; speedup vs baseline: 1.4482x; 1.0993x over previous
//
#include <hip/hip_runtime.h>
#include <hip/hip_bf16.h>
#include <math.h>

using bf16 = __hip_bfloat16;
typedef __attribute__((ext_vector_type(8))) short short8;
typedef __attribute__((ext_vector_type(4))) float floatx4;

// ---------------------------------------------------------------- helpers
__device__ inline void gl_lds16(const void* g, void* l) {
  __builtin_amdgcn_global_load_lds(
      (const __attribute__((address_space(1))) unsigned int*)g,
      (__attribute__((address_space(3))) unsigned int*)l,
      16, 0, 0);
}
__device__ inline float eluf(float x) { return x > 0.f ? x : expm1f(x); }
__device__ inline float bf2f(unsigned short h) {
  return __uint_as_float(((unsigned)h) << 16);
}
__device__ inline void bf16x8_fma(short8 r, float w, float* acc) {
#pragma unroll
  for (int k = 0; k < 8; k++) acc[k] += w * bf2f((unsigned short)r[k]);
}

// ---------------------------------------------------------------- dtype probe
__global__ void probe_dtype(const unsigned short* __restrict__ x, int* __restrict__ flag) {
  __shared__ int s;
  int t = threadIdx.x;
  if (t == 0) s = 0;
  __syncthreads();
  int bad = 0;
  for (int i = t; i < 1024; i += 256) {
    unsigned short h = x[2 * i];
    unsigned e = (h >> 7) & 0xFF;
    if (e >= 0xE5) bad = 1;
  }
  if (bad) atomicOr(&s, 1);
  __syncthreads();
  if (t == 0) flag[0] = s;
}

__global__ void to_bf16_kernel(const void* __restrict__ in, bf16* __restrict__ out,
                               int nelem, const int* __restrict__ flag) {
  int i = blockIdx.x * 256 + threadIdx.x;
  if (i >= nelem) return;
  if (*flag) out[i] = __float2bfloat16(((const float*)in)[i]);
  else       out[i] = ((const bf16*)in)[i];
}

// biases -> f32; aw -> softmaxed (w0,w1) pairs.
__global__ void small_prep(
    const void* b11, const void* b12, const void* b21, const void* b22,
    const void* b31, const void* b32, const void* aw1, const void* aw2, const void* aw3,
    float* ob11, float* ob12, float* ob21, float* ob22, float* ob31, float* ob32,
    float* ow1, float* ow2, float* ow3, const int* __restrict__ flag) {
  const bool f32 = *flag != 0;
  auto cv = [&](const void* p, int i) -> float {
    return f32 ? ((const float*)p)[i] : __bfloat162float(((const bf16*)p)[i]);
  };
  int t = blockIdx.x * 256 + threadIdx.x;
  if (t < 1024) ob11[t] = cv(b11, t);
  else if (t < 2048) ob12[t - 1024] = cv(b12, t - 1024);
  else if (t < 2560) ob21[t - 2048] = cv(b21, t - 2048);
  else if (t < 3072) ob22[t - 2560] = cv(b22, t - 2560);
  else if (t < 3200) ob31[t - 3072] = cv(b31, t - 3072);
  else if (t < 3328) ob32[t - 3200] = cv(b32, t - 3200);
  else if (t < 4992) {
    int j = t - 3328;
    const void* src; float* dst; int jj;
    if (j < 1024)      { src = aw1; dst = ow1; jj = j; }
    else if (j < 1536) { src = aw2; dst = ow2; jj = j - 1024; }
    else               { src = aw3; dst = ow3; jj = j - 1536; }
    float e0 = cv(src, 2 * jj), e1 = cv(src, 2 * jj + 1);
    float mx = fmaxf(e0, e1);
    float w0 = expf(e0 - mx), w1 = expf(e1 - mx);
    float inv = 1.f / (w0 + w1);
    dst[2 * jj] = w0 * inv;
    dst[2 * jj + 1] = w1 * inv;
  }
}

// ---------------------------------------------------------------- graph prep
__global__ void deg_fused(const int* __restrict__ dst1, int E1,
                          const int* __restrict__ dst2, int E2,
                          int* __restrict__ deg1, int* __restrict__ deg2) {
  int e = blockIdx.x * 256 + threadIdx.x;
  if (e < E1) atomicAdd(&deg1[dst1[e]], 1);
  else if (e < E1 + E2) atomicAdd(&deg2[dst2[e - E1]], 1);
}

__global__ void scan2_kernel(const int* __restrict__ deg1, int* __restrict__ off1,
                             float* __restrict__ dinv1,
                             const int* __restrict__ deg2, int* __restrict__ off2,
                             float* __restrict__ dinv2, int n) {
  const int* deg = blockIdx.x ? deg2 : deg1;
  int* off = blockIdx.x ? off2 : off1;
  float* dinv = blockIdx.x ? dinv2 : dinv1;
  __shared__ int s[1024];
  __shared__ int carry_s;
  int t = threadIdx.x;
  if (t == 0) carry_s = 0;
  __syncthreads();
  for (int base = 0; base < n; base += 1024) {
    int i = base + t;
    int orig = (i < n) ? deg[i] : 0;
    s[t] = orig;
    __syncthreads();
    for (int d = 1; d < 1024; d <<= 1) {
      int add = (t >= d) ? s[t - d] : 0;
      __syncthreads();
      s[t] += add;
      __syncthreads();
    }
    int incl = s[t];
    int carry = carry_s;
    if (i < n) {
      off[i]  = carry + incl - orig;
      dinv[i] = rsqrtf((float)(orig + 1));
    }
    __syncthreads();
    if (t == 1023) carry_s = carry + incl;
    __syncthreads();
  }
  if (t == 0) off[n] = carry_s;
}

__global__ void csr_fused(const int* __restrict__ src1, const int* __restrict__ dst1, int E1,
                          const int* __restrict__ src2, const int* __restrict__ dst2, int E2,
                          const int* __restrict__ off1, int* __restrict__ cur1,
                          const float* __restrict__ dinv1,
                          int* __restrict__ cs1, float* __restrict__ cw1,
                          const int* __restrict__ off2, int* __restrict__ cur2,
                          const float* __restrict__ dinv2,
                          int* __restrict__ cs2, float* __restrict__ cw2) {
  int e = blockIdx.x * 256 + threadIdx.x;
  if (e < E1) {
    int d = dst1[e], s = src1[e];
    int slot = off1[d] + atomicAdd(&cur1[d], 1);
    cs1[slot] = s;
    cw1[slot] = dinv1[s];
  } else if (e < E1 + E2) {
    int ee = e - E1;
    int d = dst2[ee], s = src2[ee];
    int slot = off2[d] + atomicAdd(&cur2[d], 1);
    cs2[slot] = s;
    cw2[slot] = dinv2[s];
  }
}

// All six W[K][N] -> Wt[N][K] transposes in one dispatch.
__global__ void transpose_all(const void* W11, const void* W12, const void* W21,
                              const void* W22, const void* W31, const void* W32,
                              bf16* Wt11, bf16* Wt12, bf16* Wt2cat, bf16* Wt3cat,
                              const int* __restrict__ flag) {
  __shared__ bf16 tile[32][33];
  const bool f32 = *flag != 0;
  int b = blockIdx.x;
  const void* in; bf16* out; int K, N, tt;
  if (b < 512)       { in = W11; out = Wt11; K = 512;  N = 1024; tt = b; }
  else if (b < 1024) { in = W12; out = Wt12; K = 512;  N = 1024; tt = b - 512; }
  else if (b < 1536) { in = W21; out = Wt2cat; K = 1024; N = 512; tt = b - 1024; }
  else if (b < 2048) { in = W22; out = Wt2cat + (size_t)512 * 1024; K = 1024; N = 512; tt = b - 1536; }
  else if (b < 2112) { in = W31; out = Wt3cat; K = 512; N = 128; tt = b - 2048; }
  else               { in = W32; out = Wt3cat + (size_t)128 * 512; K = 512; N = 128; tt = b - 2112; }
  int tilesx = N / 32;
  int bx = (tt % tilesx) * 32;
  int by = (tt / tilesx) * 32;
  int tx = threadIdx.x, ty = threadIdx.y;
#pragma unroll
  for (int i = 0; i < 32; i += 8) {
    size_t idx = (size_t)(by + ty + i) * N + (bx + tx);
    tile[ty + i][tx] = f32 ? __float2bfloat16(((const float*)in)[idx])
                           : ((const bf16*)in)[idx];
  }
  __syncthreads();
#pragma unroll
  for (int i = 0; i < 32; i += 8)
    out[(size_t)(bx + ty + i) * K + (by + tx)] = tile[tx][ty + i];
}

// ---------------------------------------------------------------- input-side agg (layer 1)
// One wave per vertex; each lane gathers bf16x8 (16B) per edge; 2-edge unroll.
__global__ __launch_bounds__(256) void aggx_kernel(
    const bf16* __restrict__ X,
    const int* __restrict__ off1, const int* __restrict__ cs1, const float* __restrict__ cw1,
    const int* __restrict__ off2, const int* __restrict__ cs2, const float* __restrict__ cw2,
    const float* __restrict__ dinv1, const float* __restrict__ dinv2,
    bf16* __restrict__ outA, bf16* __restrict__ outB, int n) {
  int v = blockIdx.x * 4 + (threadIdx.x >> 6);
  if (v >= n) return;
  v = __builtin_amdgcn_readfirstlane(v);
  const int c = (threadIdx.x & 63) * 8;
  const bf16* __restrict__ base = X + c;

  float a[8], b[8];
#pragma unroll
  for (int k = 0; k < 8; k++) { a[k] = 0.f; b[k] = 0.f; }

  int s1 = __builtin_amdgcn_readfirstlane(off1[v]);
  int e1 = __builtin_amdgcn_readfirstlane(off1[v + 1]);
  int i = s1;
  for (; i + 2 <= e1; i += 2) {
    int u0 = cs1[i], u1 = cs1[i + 1];
    float w0 = cw1[i], w1 = cw1[i + 1];
    short8 r0 = *(const short8*)(base + (size_t)u0 * 512);
    short8 r1 = *(const short8*)(base + (size_t)u1 * 512);
    bf16x8_fma(r0, w0, a);
    bf16x8_fma(r1, w1, a);
  }
  if (i < e1) {
    short8 r0 = *(const short8*)(base + (size_t)cs1[i] * 512);
    bf16x8_fma(r0, cw1[i], a);
  }
  int s2 = __builtin_amdgcn_readfirstlane(off2[v]);
  int e2 = __builtin_amdgcn_readfirstlane(off2[v + 1]);
  i = s2;
  for (; i + 2 <= e2; i += 2) {
    int u0 = cs2[i], u1 = cs2[i + 1];
    float w0 = cw2[i], w1 = cw2[i + 1];
    short8 r0 = *(const short8*)(base + (size_t)u0 * 512);
    short8 r1 = *(const short8*)(base + (size_t)u1 * 512);
    bf16x8_fma(r0, w0, b);
    bf16x8_fma(r1, w1, b);
  }
  if (i < e2) {
    short8 r0 = *(const short8*)(base + (size_t)cs2[i] * 512);
    bf16x8_fma(r0, cw2[i], b);
  }

  short8 self = *(const short8*)(base + (size_t)v * 512);
  const float dv1 = dinv1[v], dv2 = dinv2[v];
  short8 ra, rb;
#pragma unroll
  for (int k = 0; k < 8; k++) {
    float xs = bf2f((unsigned short)self[k]);
    ra[k] = (short)__bfloat16_as_ushort(__float2bfloat16(dv1 * a[k] + dv1 * dv1 * xs));
    rb[k] = (short)__bfloat16_as_ushort(__float2bfloat16(dv2 * b[k] + dv2 * dv2 * xs));
  }
  *(short8*)(outA + (size_t)v * 512 + c) = ra;
  *(short8*)(outB + (size_t)v * 512 + c) = rb;
}

// ---------------------------------------------------------------- GEMM body (m97-style)
__device__ inline void gemm_body(const bf16* __restrict__ A, const bf16* __restrict__ Bt,
                                 bf16* __restrict__ C, int M, int K, int N,
                                 int m0, int n0) {
  __shared__ bf16 As[128 * 32];
  __shared__ bf16 Bs[128 * 32];
  const int tid = threadIdx.x;
  const int wave = tid >> 6;
  const int lane = tid & 63;
  const int quad = lane >> 4;
  const int l16 = lane & 15;
  const int wr = (wave >> 1) * 64;
  const int wc = (wave & 1) * 64;
  const int r_sub = lane >> 2;
  const int cb = (lane & 3) * 16;

  floatx4 acc[4][4];
#pragma unroll
  for (int i = 0; i < 4; i++)
#pragma unroll
    for (int j = 0; j < 4; j++) acc[i][j] = (floatx4){0.f, 0.f, 0.f, 0.f};

  for (int k0 = 0; k0 < K; k0 += 32) {
    __syncthreads();
#pragma unroll
    for (int j = 0; j < 2; ++j) {
      int p = wave * 2 + j;
      int ra = p * 16 + r_sub;
      int grow = m0 + ra; if (grow >= M) grow = M - 1;
      gl_lds16((const char*)(A + (size_t)grow * K + k0) + cb, (char*)As + p * 1024);
      int rb = n0 + p * 16 + r_sub;
      gl_lds16((const char*)(Bt + (size_t)rb * K + k0) + cb, (char*)Bs + p * 1024);
    }
    __syncthreads();

    short8 af[4], bfr[4];
#pragma unroll
    for (int i = 0; i < 4; i++)
      af[i] = *(const short8*)(As + (wr + i * 16 + l16) * 32 + quad * 8);
#pragma unroll
    for (int j = 0; j < 4; j++)
      bfr[j] = *(const short8*)(Bs + (wc + j * 16 + l16) * 32 + quad * 8);
#pragma unroll
    for (int i = 0; i < 4; i++)
#pragma unroll
      for (int j = 0; j < 4; j++)
        acc[i][j] = __builtin_amdgcn_mfma_f32_16x16x32_bf16(af[i], bfr[j], acc[i][j], 0, 0, 0);
  }

#pragma unroll
  for (int i = 0; i < 4; i++) {
#pragma unroll
    for (int r = 0; r < 4; r++) {
      int row = m0 + wr + i * 16 + quad * 4 + r;
      if (row < M) {
#pragma unroll
        for (int j = 0; j < 4; j++) {
          int col = n0 + wc + j * 16 + l16;
          C[(size_t)row * N + col] = __float2bfloat16(acc[i][j][r]);
        }
      }
    }
  }
}

__global__ __launch_bounds__(256) void gemm128(const bf16* __restrict__ A,
                                               const bf16* __restrict__ Bt,
                                               bf16* __restrict__ C, int M, int K, int N) {
  gemm_body(A, Bt, C, M, K, N, blockIdx.y * 128, blockIdx.x * 128);
}

__global__ __launch_bounds__(256) void gemm128_dual(
    const bf16* __restrict__ A0, const bf16* __restrict__ Bt0, bf16* __restrict__ C0,
    const bf16* __restrict__ A1, const bf16* __restrict__ Bt1, bf16* __restrict__ C1,
    int M, int K, int N, int mtiles) {
  int half = blockIdx.y / mtiles;
  int by = blockIdx.y % mtiles;
  const bf16* A = half ? A1 : A0;
  const bf16* Bt = half ? Bt1 : Bt0;
  bf16* C = half ? C1 : C0;
  gemm_body(A, Bt, C, M, K, N, by * 128, blockIdx.x * 128);
}

// ---------------------------------------------------------------- layer-1 epilogue
__global__ __launch_bounds__(256) void combine1_kernel(
    const bf16* __restrict__ Ha, const bf16* __restrict__ Hb,
    const float* __restrict__ ba, const float* __restrict__ bb,
    const float* __restrict__ w01, bf16* __restrict__ out, int total) {
  int e = (blockIdx.x * 256 + threadIdx.x) * 8;
  if (e >= total) return;
  int c = e & 1023;
  short8 ha = *(const short8*)(Ha + e);
  short8 hb = *(const short8*)(Hb + e);
  short8 r;
#pragma unroll
  for (int k = 0; k < 8; k++) {
    float x = eluf(bf2f((unsigned short)ha[k]) + ba[c + k]);
    float y = eluf(bf2f((unsigned short)hb[k]) + bb[c + k]);
    r[k] = (short)__bfloat16_as_ushort(
        __float2bfloat16(x * w01[2 * (c + k)] + y * w01[2 * (c + k) + 1]));
  }
  *(short8*)(out + e) = r;
}

// ---------------------------------------------------------------- output-side agg (layers 2,3)
// TPV = C/8 lanes per vertex, 16B gathers, 2-edge unroll. WU: wave-uniform vertex.
template <int C, bool WU>
__global__ __launch_bounds__(256) void agg_out_kernel(
    const bf16* __restrict__ Ha, const bf16* __restrict__ Hb, int ldH,
    const int* __restrict__ off1, const int* __restrict__ cs1, const float* __restrict__ cw1,
    const int* __restrict__ off2, const int* __restrict__ cs2, const float* __restrict__ cw2,
    const float* __restrict__ dinv1, const float* __restrict__ dinv2,
    const float* __restrict__ ba, const float* __restrict__ bb,
    const float* __restrict__ w01, void* __restrict__ out, int n,
    const int* __restrict__ outflag) {
  constexpr int TPV = C / 8;
  constexpr int G = 256 / TPV;
  const int t = threadIdx.x;
  int v = blockIdx.x * G + t / TPV;
  if (v >= n) return;
  if (WU) v = __builtin_amdgcn_readfirstlane(v);
  const int c = (t % TPV) * 8;
  const bf16* __restrict__ baseA = Ha + c;
  const bf16* __restrict__ baseB = Hb + c;

  float a[8], b[8];
#pragma unroll
  for (int k = 0; k < 8; k++) { a[k] = 0.f; b[k] = 0.f; }

  int s1 = off1[v], e1 = off1[v + 1];
  if (WU) { s1 = __builtin_amdgcn_readfirstlane(s1); e1 = __builtin_amdgcn_readfirstlane(e1); }
  int i = s1;
  for (; i + 2 <= e1; i += 2) {
    int u0 = cs1[i], u1 = cs1[i + 1];
    float w0 = cw1[i], w1 = cw1[i + 1];
    short8 r0 = *(const short8*)(baseA + (size_t)u0 * ldH);
    short8 r1 = *(const short8*)(baseA + (size_t)u1 * ldH);
    bf16x8_fma(r0, w0, a);
    bf16x8_fma(r1, w1, a);
  }
  if (i < e1) {
    short8 r0 = *(const short8*)(baseA + (size_t)cs1[i] * ldH);
    bf16x8_fma(r0, cw1[i], a);
  }
  int s2 = off2[v], e2 = off2[v + 1];
  if (WU) { s2 = __builtin_amdgcn_readfirstlane(s2); e2 = __builtin_amdgcn_readfirstlane(e2); }
  i = s2;
  for (; i + 2 <= e2; i += 2) {
    int u0 = cs2[i], u1 = cs2[i + 1];
    float w0 = cw2[i], w1 = cw2[i + 1];
    short8 r0 = *(const short8*)(baseB + (size_t)u0 * ldH);
    short8 r1 = *(const short8*)(baseB + (size_t)u1 * ldH);
    bf16x8_fma(r0, w0, b);
    bf16x8_fma(r1, w1, b);
  }
  if (i < e2) {
    short8 r0 = *(const short8*)(baseB + (size_t)cs2[i] * ldH);
    bf16x8_fma(r0, cw2[i], b);
  }

  short8 sa = *(const short8*)(baseA + (size_t)v * ldH);
  short8 sb = *(const short8*)(baseB + (size_t)v * ldH);
  const float dv1 = dinv1[v], dv2 = dinv2[v];

  float r[8];
#pragma unroll
  for (int k = 0; k < 8; k++) {
    float x = eluf(dv1 * a[k] + dv1 * dv1 * bf2f((unsigned short)sa[k]) + ba[c + k]);
    float y = eluf(dv2 * b[k] + dv2 * dv2 * bf2f((unsigned short)sb[k]) + bb[c + k]);
    r[k] = x * w01[2 * (c + k)] + y * w01[2 * (c + k) + 1];
  }

  const bool out_f32 = (outflag != nullptr) && (*outflag != 0);
  size_t oi = (size_t)v * C + c;
  if (out_f32) {
    floatx4 lo = {r[0], r[1], r[2], r[3]};
    floatx4 hi = {r[4], r[5], r[6], r[7]};
    *(floatx4*)((float*)out + oi) = lo;
    *(floatx4*)((float*)out + oi + 4) = hi;
  } else {
    short8 rb;
#pragma unroll
    for (int k = 0; k < 8; k++)
      rb[k] = (short)__bfloat16_as_ushort(__float2bfloat16(r[k]));
    *(short8*)((bf16*)out + oi) = rb;
  }
}

// ---------------------------------------------------------------- host pipeline
extern "C" void kernel_launch(void* const* d_in, const int* in_sizes, int n_in,
                              void* d_out, int out_size, void* d_ws, size_t ws_size,
                              hipStream_t stream) {
  const void* X = d_in[0];
  const int* ei1 = (const int*)d_in[1];
  const int* ei2 = (const int*)d_in[2];
  const int n = in_sizes[0] / 512;
  const int E1 = in_sizes[1] / 2;
  const int E2 = in_sizes[2] / 2;
  const int* src1 = ei1;           const int* dst1 = ei1 + E1;
  const int* src2 = ei2;           const int* dst2 = ei2 + E2;

  auto rnd = [](size_t b) { return (b + 255) & ~(size_t)255; };
  char* p = (char*)d_ws;
  auto alloc = [&](size_t bytes) { char* r = p; p += rnd(bytes); return r; };

  int* flag = (int*)alloc(256);
  int* deg1 = (int*)alloc((size_t)n * 4);
  int* deg2 = (int*)alloc((size_t)n * 4);
  int* cur1 = (int*)alloc((size_t)n * 4);
  int* cur2 = (int*)alloc((size_t)n * 4);
  int* off1 = (int*)alloc((size_t)(n + 1) * 4);
  int* off2 = (int*)alloc((size_t)(n + 1) * 4);
  float* dinv1 = (float*)alloc((size_t)n * 4);
  float* dinv2 = (float*)alloc((size_t)n * 4);
  int* cs1 = (int*)alloc((size_t)E1 * 4);
  float* cw1 = (float*)alloc((size_t)E1 * 4);
  int* cs2 = (int*)alloc((size_t)E2 * 4);
  float* cw2 = (float*)alloc((size_t)E2 * 4);
  bf16* Wt11 = (bf16*)alloc((size_t)512 * 1024 * 2);
  bf16* Wt12 = (bf16*)alloc((size_t)512 * 1024 * 2);
  bf16* Wt2cat = (bf16*)alloc((size_t)1024 * 1024 * 2);
  bf16* Wt3cat = (bf16*)alloc((size_t)256 * 512 * 2);
  float* bf_[6]; int bsz[6] = {1024, 1024, 512, 512, 128, 128};
  for (int i = 0; i < 6; i++) bf_[i] = (float*)alloc((size_t)bsz[i] * 4);
  float* w01_[3]; int asz[3] = {2048, 1024, 256};
  for (int i = 0; i < 3; i++) w01_[i] = (float*)alloc((size_t)asz[i] * 4);
  bf16* Xb = (bf16*)alloc((size_t)n * 512 * 2);
  bf16* aggXa = (bf16*)alloc((size_t)n * 512 * 2);
  bf16* aggXb = (bf16*)alloc((size_t)n * 512 * 2);
  bf16* H1a = (bf16*)alloc((size_t)n * 1024 * 2);
  bf16* H1b = (bf16*)alloc((size_t)n * 1024 * 2);
  bf16* act1 = (bf16*)alloc((size_t)n * 1024 * 2);
  bf16* H2cat = H1a;   // dead after combine1
  bf16* act2 = aggXa;  // dead after layer-1 GEMM
  bf16* H3cat = H1b;   // dead after combine1

  probe_dtype<<<1, 256, 0, stream>>>((const unsigned short*)X, flag);
  hipMemsetAsync(deg1, 0, rnd((size_t)n * 4) * 4, stream);  // deg1,deg2,cur1,cur2

  to_bf16_kernel<<<(n * 512 + 255) / 256, 256, 0, stream>>>(X, Xb, n * 512, flag);
  small_prep<<<20, 256, 0, stream>>>(d_in[4], d_in[6], d_in[8], d_in[10], d_in[12], d_in[14],
                                     d_in[15], d_in[16], d_in[17],
                                     bf_[0], bf_[1], bf_[2], bf_[3], bf_[4], bf_[5],
                                     w01_[0], w01_[1], w01_[2], flag);

  int Etot = E1 + E2;
  deg_fused<<<(Etot + 255) / 256, 256, 0, stream>>>(dst1, E1, dst2, E2, deg1, deg2);
  scan2_kernel<<<2, 1024, 0, stream>>>(deg1, off1, dinv1, deg2, off2, dinv2, n);
  csr_fused<<<(Etot + 255) / 256, 256, 0, stream>>>(src1, dst1, E1, src2, dst2, E2,
                                                    off1, cur1, dinv1, cs1, cw1,
                                                    off2, cur2, dinv2, cs2, cw2);

  transpose_all<<<2176, dim3(32, 8), 0, stream>>>(d_in[3], d_in[5], d_in[7], d_in[9],
                                                  d_in[11], d_in[13],
                                                  Wt11, Wt12, Wt2cat, Wt3cat, flag);

  const int mtiles = (n + 127) / 128;
  // ---- layer 1: input-side aggregation, dual GEMM, elementwise combine
  aggx_kernel<<<(n + 3) / 4, 256, 0, stream>>>(Xb, off1, cs1, cw1, off2, cs2, cw2,
                                               dinv1, dinv2, aggXa, aggXb, n);
  gemm128_dual<<<dim3(8, 2 * mtiles), 256, 0, stream>>>(aggXa, Wt11, H1a,
                                                        aggXb, Wt12, H1b,
                                                        n, 512, 1024, mtiles);
  combine1_kernel<<<(n * 1024 / 8 + 255) / 256, 256, 0, stream>>>(
      H1a, H1b, bf_[0], bf_[1], w01_[0], act1, n * 1024);
  // ---- layer 2: concat GEMM (bf16 out) + output-side agg
  gemm128<<<dim3(8, mtiles), 256, 0, stream>>>(act1, Wt2cat, H2cat, n, 1024, 1024);
  agg_out_kernel<512, true><<<(n + 3) / 4, 256, 0, stream>>>(
      H2cat, H2cat + 512, 1024, off1, cs1, cw1, off2, cs2, cw2,
      dinv1, dinv2, bf_[2], bf_[3], w01_[1], act2, n, (const int*)nullptr);
  // ---- layer 3: concat GEMM (bf16 out) + output-side agg -> d_out
  gemm128<<<dim3(2, mtiles), 256, 0, stream>>>(act2, Wt3cat, H3cat, n, 512, 256);
  agg_out_kernel<128, false><<<(n + 15) / 16, 256, 0, stream>>>(
      H3cat, H3cat + 128, 256, off1, cs1, cw1, off2, cs2, cw2,
      dinv1, dinv2, bf_[4], bf_[5], w01_[2], d_out, n, flag);
}

// Round 6
// 396.912 us; speedup vs baseline: 1.5468x; 1.0681x over previous
//
#include <hip/hip_runtime.h>
#include <hip/hip_bf16.h>
#include <math.h>

using bf16 = __hip_bfloat16;
typedef __attribute__((ext_vector_type(8))) short short8;
typedef __attribute__((ext_vector_type(4))) float floatx4;

// ---------------------------------------------------------------- helpers
__device__ inline void gl_lds16(const void* g, void* l) {
  __builtin_amdgcn_global_load_lds(
      (const __attribute__((address_space(1))) unsigned int*)g,
      (__attribute__((address_space(3))) unsigned int*)l,
      16, 0, 0);
}
// fast ELU: branch-free select + v_exp_f32 (error ~1e-7, invisible at bf16)
__device__ inline float eluf(float x) { return x > 0.f ? x : __expf(x) - 1.f; }
__device__ inline float bf2f(unsigned short h) {
  return __uint_as_float(((unsigned)h) << 16);
}
__device__ inline void bf16x8_fma(short8 r, float w, float* acc) {
#pragma unroll
  for (int k = 0; k < 8; k++) acc[k] += w * bf2f((unsigned short)r[k]);
}

// ---------------------------------------------------------------- dtype probe
__global__ void probe_dtype(const unsigned short* __restrict__ x, int* __restrict__ flag) {
  __shared__ int s;
  int t = threadIdx.x;
  if (t == 0) s = 0;
  __syncthreads();
  int bad = 0;
  for (int i = t; i < 1024; i += 256) {
    unsigned short h = x[2 * i];
    unsigned e = (h >> 7) & 0xFF;
    if (e >= 0xE5) bad = 1;
  }
  if (bad) atomicOr(&s, 1);
  __syncthreads();
  if (t == 0) flag[0] = s;
}

__global__ void to_bf16_kernel(const void* __restrict__ in, bf16* __restrict__ out,
                               int nelem, const int* __restrict__ flag) {
  int i = blockIdx.x * 256 + threadIdx.x;
  if (i >= nelem) return;
  if (*flag) out[i] = __float2bfloat16(((const float*)in)[i]);
  else       out[i] = ((const bf16*)in)[i];
}

// biases -> f32; aw -> softmaxed (w0,w1) pairs.
__global__ void small_prep(
    const void* b11, const void* b12, const void* b21, const void* b22,
    const void* b31, const void* b32, const void* aw1, const void* aw2, const void* aw3,
    float* ob11, float* ob12, float* ob21, float* ob22, float* ob31, float* ob32,
    float* ow1, float* ow2, float* ow3, const int* __restrict__ flag) {
  const bool f32 = *flag != 0;
  auto cv = [&](const void* p, int i) -> float {
    return f32 ? ((const float*)p)[i] : __bfloat162float(((const bf16*)p)[i]);
  };
  int t = blockIdx.x * 256 + threadIdx.x;
  if (t < 1024) ob11[t] = cv(b11, t);
  else if (t < 2048) ob12[t - 1024] = cv(b12, t - 1024);
  else if (t < 2560) ob21[t - 2048] = cv(b21, t - 2048);
  else if (t < 3072) ob22[t - 2560] = cv(b22, t - 2560);
  else if (t < 3200) ob31[t - 3072] = cv(b31, t - 3072);
  else if (t < 3328) ob32[t - 3200] = cv(b32, t - 3200);
  else if (t < 4992) {
    int j = t - 3328;
    const void* src; float* dst; int jj;
    if (j < 1024)      { src = aw1; dst = ow1; jj = j; }
    else if (j < 1536) { src = aw2; dst = ow2; jj = j - 1024; }
    else               { src = aw3; dst = ow3; jj = j - 1536; }
    float e0 = cv(src, 2 * jj), e1 = cv(src, 2 * jj + 1);
    float mx = fmaxf(e0, e1);
    float w0 = expf(e0 - mx), w1 = expf(e1 - mx);
    float inv = 1.f / (w0 + w1);
    dst[2 * jj] = w0 * inv;
    dst[2 * jj + 1] = w1 * inv;
  }
}

// ---------------------------------------------------------------- graph prep
__global__ void deg_fused(const int* __restrict__ dst1, int E1,
                          const int* __restrict__ dst2, int E2,
                          int* __restrict__ deg1, int* __restrict__ deg2) {
  int e = blockIdx.x * 256 + threadIdx.x;
  if (e < E1) atomicAdd(&deg1[dst1[e]], 1);
  else if (e < E1 + E2) atomicAdd(&deg2[dst2[e - E1]], 1);
}

__global__ void scan2_kernel(const int* __restrict__ deg1, int* __restrict__ off1,
                             float* __restrict__ dinv1,
                             const int* __restrict__ deg2, int* __restrict__ off2,
                             float* __restrict__ dinv2, int n) {
  const int* deg = blockIdx.x ? deg2 : deg1;
  int* off = blockIdx.x ? off2 : off1;
  float* dinv = blockIdx.x ? dinv2 : dinv1;
  __shared__ int s[1024];
  __shared__ int carry_s;
  int t = threadIdx.x;
  if (t == 0) carry_s = 0;
  __syncthreads();
  for (int base = 0; base < n; base += 1024) {
    int i = base + t;
    int orig = (i < n) ? deg[i] : 0;
    s[t] = orig;
    __syncthreads();
    for (int d = 1; d < 1024; d <<= 1) {
      int add = (t >= d) ? s[t - d] : 0;
      __syncthreads();
      s[t] += add;
      __syncthreads();
    }
    int incl = s[t];
    int carry = carry_s;
    if (i < n) {
      off[i]  = carry + incl - orig;
      dinv[i] = rsqrtf((float)(orig + 1));
    }
    __syncthreads();
    if (t == 1023) carry_s = carry + incl;
    __syncthreads();
  }
  if (t == 0) off[n] = carry_s;
}

__global__ void csr_fused(const int* __restrict__ src1, const int* __restrict__ dst1, int E1,
                          const int* __restrict__ src2, const int* __restrict__ dst2, int E2,
                          const int* __restrict__ off1, int* __restrict__ cur1,
                          const float* __restrict__ dinv1,
                          int* __restrict__ cs1, float* __restrict__ cw1,
                          const int* __restrict__ off2, int* __restrict__ cur2,
                          const float* __restrict__ dinv2,
                          int* __restrict__ cs2, float* __restrict__ cw2) {
  int e = blockIdx.x * 256 + threadIdx.x;
  if (e < E1) {
    int d = dst1[e], s = src1[e];
    int slot = off1[d] + atomicAdd(&cur1[d], 1);
    cs1[slot] = s;
    cw1[slot] = dinv1[s];
  } else if (e < E1 + E2) {
    int ee = e - E1;
    int d = dst2[ee], s = src2[ee];
    int slot = off2[d] + atomicAdd(&cur2[d], 1);
    cs2[slot] = s;
    cw2[slot] = dinv2[s];
  }
}

// All six W[K][N] -> Wt[N][K] transposes in one dispatch.
__global__ void transpose_all(const void* W11, const void* W12, const void* W21,
                              const void* W22, const void* W31, const void* W32,
                              bf16* Wt11, bf16* Wt12, bf16* Wt2cat, bf16* Wt3cat,
                              const int* __restrict__ flag) {
  __shared__ bf16 tile[32][33];
  const bool f32 = *flag != 0;
  int b = blockIdx.x;
  const void* in; bf16* out; int K, N, tt;
  if (b < 512)       { in = W11; out = Wt11; K = 512;  N = 1024; tt = b; }
  else if (b < 1024) { in = W12; out = Wt12; K = 512;  N = 1024; tt = b - 512; }
  else if (b < 1536) { in = W21; out = Wt2cat; K = 1024; N = 512; tt = b - 1024; }
  else if (b < 2048) { in = W22; out = Wt2cat + (size_t)512 * 1024; K = 1024; N = 512; tt = b - 1536; }
  else if (b < 2112) { in = W31; out = Wt3cat; K = 512; N = 128; tt = b - 2048; }
  else               { in = W32; out = Wt3cat + (size_t)128 * 512; K = 512; N = 128; tt = b - 2112; }
  int tilesx = N / 32;
  int bx = (tt % tilesx) * 32;
  int by = (tt / tilesx) * 32;
  int tx = threadIdx.x, ty = threadIdx.y;
#pragma unroll
  for (int i = 0; i < 32; i += 8) {
    size_t idx = (size_t)(by + ty + i) * N + (bx + tx);
    tile[ty + i][tx] = f32 ? __float2bfloat16(((const float*)in)[idx])
                           : ((const bf16*)in)[idx];
  }
  __syncthreads();
#pragma unroll
  for (int i = 0; i < 32; i += 8)
    out[(size_t)(bx + ty + i) * K + (by + tx)] = tile[tx][ty + i];
}

// ---------------------------------------------------------------- input-side agg (layer 1)
__global__ __launch_bounds__(256) void aggx_kernel(
    const bf16* __restrict__ X,
    const int* __restrict__ off1, const int* __restrict__ cs1, const float* __restrict__ cw1,
    const int* __restrict__ off2, const int* __restrict__ cs2, const float* __restrict__ cw2,
    const float* __restrict__ dinv1, const float* __restrict__ dinv2,
    bf16* __restrict__ outA, bf16* __restrict__ outB, int n) {
  int v = blockIdx.x * 4 + (threadIdx.x >> 6);
  if (v >= n) return;
  v = __builtin_amdgcn_readfirstlane(v);
  const int c = (threadIdx.x & 63) * 8;
  const bf16* __restrict__ base = X + c;

  float a[8], b[8];
#pragma unroll
  for (int k = 0; k < 8; k++) { a[k] = 0.f; b[k] = 0.f; }

  int s1 = __builtin_amdgcn_readfirstlane(off1[v]);
  int e1 = __builtin_amdgcn_readfirstlane(off1[v + 1]);
  int i = s1;
  for (; i + 2 <= e1; i += 2) {
    int u0 = cs1[i], u1 = cs1[i + 1];
    float w0 = cw1[i], w1 = cw1[i + 1];
    short8 r0 = *(const short8*)(base + (size_t)u0 * 512);
    short8 r1 = *(const short8*)(base + (size_t)u1 * 512);
    bf16x8_fma(r0, w0, a);
    bf16x8_fma(r1, w1, a);
  }
  if (i < e1) {
    short8 r0 = *(const short8*)(base + (size_t)cs1[i] * 512);
    bf16x8_fma(r0, cw1[i], a);
  }
  int s2 = __builtin_amdgcn_readfirstlane(off2[v]);
  int e2 = __builtin_amdgcn_readfirstlane(off2[v + 1]);
  i = s2;
  for (; i + 2 <= e2; i += 2) {
    int u0 = cs2[i], u1 = cs2[i + 1];
    float w0 = cw2[i], w1 = cw2[i + 1];
    short8 r0 = *(const short8*)(base + (size_t)u0 * 512);
    short8 r1 = *(const short8*)(base + (size_t)u1 * 512);
    bf16x8_fma(r0, w0, b);
    bf16x8_fma(r1, w1, b);
  }
  if (i < e2) {
    short8 r0 = *(const short8*)(base + (size_t)cs2[i] * 512);
    bf16x8_fma(r0, cw2[i], b);
  }

  short8 self = *(const short8*)(base + (size_t)v * 512);
  const float dv1 = dinv1[v], dv2 = dinv2[v];
  short8 ra, rb;
#pragma unroll
  for (int k = 0; k < 8; k++) {
    float xs = bf2f((unsigned short)self[k]);
    ra[k] = (short)__bfloat16_as_ushort(__float2bfloat16(dv1 * a[k] + dv1 * dv1 * xs));
    rb[k] = (short)__bfloat16_as_ushort(__float2bfloat16(dv2 * b[k] + dv2 * dv2 * xs));
  }
  *(short8*)(outA + (size_t)v * 512 + c) = ra;
  *(short8*)(outB + (size_t)v * 512 + c) = rb;
}

// ---------------------------------------------------------------- GEMM pieces (m97-style)
// K-loop accumulate: acc += A[m0:m0+128][0:K] @ Bt[n0:n0+128][0:K]^T
__device__ inline void gemm_accum(const bf16* __restrict__ A, const bf16* __restrict__ Bt,
                                  bf16* As, bf16* Bs, int M, int K,
                                  int m0, int n0, floatx4 acc[4][4]) {
  const int tid = threadIdx.x;
  const int wave = tid >> 6;
  const int lane = tid & 63;
  const int quad = lane >> 4;
  const int l16 = lane & 15;
  const int wr = (wave >> 1) * 64;
  const int wc = (wave & 1) * 64;
  const int r_sub = lane >> 2;
  const int cb = (lane & 3) * 16;

  for (int k0 = 0; k0 < K; k0 += 32) {
    __syncthreads();
#pragma unroll
    for (int j = 0; j < 2; ++j) {
      int p = wave * 2 + j;
      int ra = p * 16 + r_sub;
      int grow = m0 + ra; if (grow >= M) grow = M - 1;
      gl_lds16((const char*)(A + (size_t)grow * K + k0) + cb, (char*)As + p * 1024);
      int rb = n0 + p * 16 + r_sub;
      gl_lds16((const char*)(Bt + (size_t)rb * K + k0) + cb, (char*)Bs + p * 1024);
    }
    __syncthreads();

    short8 af[4], bfr[4];
#pragma unroll
    for (int i = 0; i < 4; i++)
      af[i] = *(const short8*)(As + (wr + i * 16 + l16) * 32 + quad * 8);
#pragma unroll
    for (int j = 0; j < 4; j++)
      bfr[j] = *(const short8*)(Bs + (wc + j * 16 + l16) * 32 + quad * 8);
#pragma unroll
    for (int i = 0; i < 4; i++)
#pragma unroll
      for (int j = 0; j < 4; j++)
        acc[i][j] = __builtin_amdgcn_mfma_f32_16x16x32_bf16(af[i], bfr[j], acc[i][j], 0, 0, 0);
  }
}

__global__ __launch_bounds__(256) void gemm128(const bf16* __restrict__ A,
                                               const bf16* __restrict__ Bt,
                                               bf16* __restrict__ C, int M, int K, int N) {
  __shared__ bf16 As[128 * 32];
  __shared__ bf16 Bs[128 * 32];
  const int m0 = blockIdx.y * 128, n0 = blockIdx.x * 128;
  floatx4 acc[4][4];
#pragma unroll
  for (int i = 0; i < 4; i++)
#pragma unroll
    for (int j = 0; j < 4; j++) acc[i][j] = (floatx4){0.f, 0.f, 0.f, 0.f};
  gemm_accum(A, Bt, As, Bs, M, K, m0, n0, acc);

  const int tid = threadIdx.x;
  const int wave = tid >> 6;
  const int lane = tid & 63;
  const int quad = lane >> 4;
  const int l16 = lane & 15;
  const int wr = (wave >> 1) * 64;
  const int wc = (wave & 1) * 64;
#pragma unroll
  for (int i = 0; i < 4; i++) {
#pragma unroll
    for (int r = 0; r < 4; r++) {
      int row = m0 + wr + i * 16 + quad * 4 + r;
      if (row < M) {
#pragma unroll
        for (int j = 0; j < 4; j++) {
          int col = n0 + wc + j * 16 + l16;
          C[(size_t)row * N + col] = __float2bfloat16(acc[i][j][r]);
        }
      }
    }
  }
}

// layer-1 fused: act1 = w0*elu(aggXa@W11 + ba) + w1*elu(aggXb@W12 + bb)
__global__ __launch_bounds__(256) void gemm128_l1(
    const bf16* __restrict__ Aa, const bf16* __restrict__ Bta,
    const bf16* __restrict__ Ab, const bf16* __restrict__ Btb,
    const float* __restrict__ ba, const float* __restrict__ bb,
    const float* __restrict__ w01, bf16* __restrict__ out,
    int M, int K, int N) {
  __shared__ bf16 As[128 * 32];
  __shared__ bf16 Bs[128 * 32];
  const int m0 = blockIdx.y * 128, n0 = blockIdx.x * 128;
  floatx4 acca[4][4], accb[4][4];
#pragma unroll
  for (int i = 0; i < 4; i++)
#pragma unroll
    for (int j = 0; j < 4; j++) {
      acca[i][j] = (floatx4){0.f, 0.f, 0.f, 0.f};
      accb[i][j] = (floatx4){0.f, 0.f, 0.f, 0.f};
    }
  gemm_accum(Aa, Bta, As, Bs, M, K, m0, n0, acca);
  gemm_accum(Ab, Btb, As, Bs, M, K, m0, n0, accb);

  const int tid = threadIdx.x;
  const int wave = tid >> 6;
  const int lane = tid & 63;
  const int quad = lane >> 4;
  const int l16 = lane & 15;
  const int wr = (wave >> 1) * 64;
  const int wc = (wave & 1) * 64;
#pragma unroll
  for (int j = 0; j < 4; j++) {
    int col = n0 + wc + j * 16 + l16;
    float baj = ba[col], bbj = bb[col];
    float w0 = w01[2 * col], w1 = w01[2 * col + 1];
#pragma unroll
    for (int i = 0; i < 4; i++) {
#pragma unroll
      for (int r = 0; r < 4; r++) {
        int row = m0 + wr + i * 16 + quad * 4 + r;
        if (row < M) {
          float x = eluf(acca[i][j][r] + baj);
          float y = eluf(accb[i][j][r] + bbj);
          out[(size_t)row * N + col] = __float2bfloat16(x * w0 + y * w1);
        }
      }
    }
  }
}

// ---------------------------------------------------------------- output-side agg (layers 2,3)
template <int C, bool WU>
__global__ __launch_bounds__(256) void agg_out_kernel(
    const bf16* __restrict__ Ha, const bf16* __restrict__ Hb, int ldH,
    const int* __restrict__ off1, const int* __restrict__ cs1, const float* __restrict__ cw1,
    const int* __restrict__ off2, const int* __restrict__ cs2, const float* __restrict__ cw2,
    const float* __restrict__ dinv1, const float* __restrict__ dinv2,
    const float* __restrict__ ba, const float* __restrict__ bb,
    const float* __restrict__ w01, void* __restrict__ out, int n,
    const int* __restrict__ outflag) {
  constexpr int TPV = C / 8;
  constexpr int G = 256 / TPV;
  const int t = threadIdx.x;
  int v = blockIdx.x * G + t / TPV;
  if (v >= n) return;
  if (WU) v = __builtin_amdgcn_readfirstlane(v);
  const int c = (t % TPV) * 8;
  const bf16* __restrict__ baseA = Ha + c;
  const bf16* __restrict__ baseB = Hb + c;

  float a[8], b[8];
#pragma unroll
  for (int k = 0; k < 8; k++) { a[k] = 0.f; b[k] = 0.f; }

  int s1 = off1[v], e1 = off1[v + 1];
  if (WU) { s1 = __builtin_amdgcn_readfirstlane(s1); e1 = __builtin_amdgcn_readfirstlane(e1); }
  int i = s1;
  for (; i + 2 <= e1; i += 2) {
    int u0 = cs1[i], u1 = cs1[i + 1];
    float w0 = cw1[i], w1 = cw1[i + 1];
    short8 r0 = *(const short8*)(baseA + (size_t)u0 * ldH);
    short8 r1 = *(const short8*)(baseA + (size_t)u1 * ldH);
    bf16x8_fma(r0, w0, a);
    bf16x8_fma(r1, w1, a);
  }
  if (i < e1) {
    short8 r0 = *(const short8*)(baseA + (size_t)cs1[i] * ldH);
    bf16x8_fma(r0, cw1[i], a);
  }
  int s2 = off2[v], e2 = off2[v + 1];
  if (WU) { s2 = __builtin_amdgcn_readfirstlane(s2); e2 = __builtin_amdgcn_readfirstlane(e2); }
  i = s2;
  for (; i + 2 <= e2; i += 2) {
    int u0 = cs2[i], u1 = cs2[i + 1];
    float w0 = cw2[i], w1 = cw2[i + 1];
    short8 r0 = *(const short8*)(baseB + (size_t)u0 * ldH);
    short8 r1 = *(const short8*)(baseB + (size_t)u1 * ldH);
    bf16x8_fma(r0, w0, b);
    bf16x8_fma(r1, w1, b);
  }
  if (i < e2) {
    short8 r0 = *(const short8*)(baseB + (size_t)cs2[i] * ldH);
    bf16x8_fma(r0, cw2[i], b);
  }

  short8 sa = *(const short8*)(baseA + (size_t)v * ldH);
  short8 sb = *(const short8*)(baseB + (size_t)v * ldH);
  const float dv1 = dinv1[v], dv2 = dinv2[v];

  float r[8];
#pragma unroll
  for (int k = 0; k < 8; k++) {
    float x = eluf(dv1 * a[k] + dv1 * dv1 * bf2f((unsigned short)sa[k]) + ba[c + k]);
    float y = eluf(dv2 * b[k] + dv2 * dv2 * bf2f((unsigned short)sb[k]) + bb[c + k]);
    r[k] = x * w01[2 * (c + k)] + y * w01[2 * (c + k) + 1];
  }

  const bool out_f32 = (outflag != nullptr) && (*outflag != 0);
  size_t oi = (size_t)v * C + c;
  if (out_f32) {
    floatx4 lo = {r[0], r[1], r[2], r[3]};
    floatx4 hi = {r[4], r[5], r[6], r[7]};
    *(floatx4*)((float*)out + oi) = lo;
    *(floatx4*)((float*)out + oi + 4) = hi;
  } else {
    short8 rb;
#pragma unroll
    for (int k = 0; k < 8; k++)
      rb[k] = (short)__bfloat16_as_ushort(__float2bfloat16(r[k]));
    *(short8*)((bf16*)out + oi) = rb;
  }
}

// ---------------------------------------------------------------- host pipeline
extern "C" void kernel_launch(void* const* d_in, const int* in_sizes, int n_in,
                              void* d_out, int out_size, void* d_ws, size_t ws_size,
                              hipStream_t stream) {
  const void* X = d_in[0];
  const int* ei1 = (const int*)d_in[1];
  const int* ei2 = (const int*)d_in[2];
  const int n = in_sizes[0] / 512;
  const int E1 = in_sizes[1] / 2;
  const int E2 = in_sizes[2] / 2;
  const int* src1 = ei1;           const int* dst1 = ei1 + E1;
  const int* src2 = ei2;           const int* dst2 = ei2 + E2;

  auto rnd = [](size_t b) { return (b + 255) & ~(size_t)255; };
  char* p = (char*)d_ws;
  auto alloc = [&](size_t bytes) { char* r = p; p += rnd(bytes); return r; };

  int* flag = (int*)alloc(256);
  int* deg1 = (int*)alloc((size_t)n * 4);
  int* deg2 = (int*)alloc((size_t)n * 4);
  int* cur1 = (int*)alloc((size_t)n * 4);
  int* cur2 = (int*)alloc((size_t)n * 4);
  int* off1 = (int*)alloc((size_t)(n + 1) * 4);
  int* off2 = (int*)alloc((size_t)(n + 1) * 4);
  float* dinv1 = (float*)alloc((size_t)n * 4);
  float* dinv2 = (float*)alloc((size_t)n * 4);
  int* cs1 = (int*)alloc((size_t)E1 * 4);
  float* cw1 = (float*)alloc((size_t)E1 * 4);
  int* cs2 = (int*)alloc((size_t)E2 * 4);
  float* cw2 = (float*)alloc((size_t)E2 * 4);
  bf16* Wt11 = (bf16*)alloc((size_t)512 * 1024 * 2);
  bf16* Wt12 = (bf16*)alloc((size_t)512 * 1024 * 2);
  bf16* Wt2cat = (bf16*)alloc((size_t)1024 * 1024 * 2);
  bf16* Wt3cat = (bf16*)alloc((size_t)256 * 512 * 2);
  float* bf_[6]; int bsz[6] = {1024, 1024, 512, 512, 128, 128};
  for (int i = 0; i < 6; i++) bf_[i] = (float*)alloc((size_t)bsz[i] * 4);
  float* w01_[3]; int asz[3] = {2048, 1024, 256};
  for (int i = 0; i < 3; i++) w01_[i] = (float*)alloc((size_t)asz[i] * 4);
  bf16* Xb = (bf16*)alloc((size_t)n * 512 * 2);
  bf16* aggXa = (bf16*)alloc((size_t)n * 512 * 2);
  bf16* aggXb = (bf16*)alloc((size_t)n * 512 * 2);
  bf16* H1a = (bf16*)alloc((size_t)n * 1024 * 2);
  bf16* H1b = (bf16*)alloc((size_t)n * 1024 * 2);
  bf16* act1 = (bf16*)alloc((size_t)n * 1024 * 2);
  bf16* H2cat = H1a;   // layer-2 GEMM output
  bf16* act2 = aggXa;  // dead after layer-1 fused GEMM
  bf16* H3cat = H1b;   // layer-3 GEMM output

  probe_dtype<<<1, 256, 0, stream>>>((const unsigned short*)X, flag);
  hipMemsetAsync(deg1, 0, rnd((size_t)n * 4) * 4, stream);  // deg1,deg2,cur1,cur2

  to_bf16_kernel<<<(n * 512 + 255) / 256, 256, 0, stream>>>(X, Xb, n * 512, flag);
  small_prep<<<20, 256, 0, stream>>>(d_in[4], d_in[6], d_in[8], d_in[10], d_in[12], d_in[14],
                                     d_in[15], d_in[16], d_in[17],
                                     bf_[0], bf_[1], bf_[2], bf_[3], bf_[4], bf_[5],
                                     w01_[0], w01_[1], w01_[2], flag);

  int Etot = E1 + E2;
  deg_fused<<<(Etot + 255) / 256, 256, 0, stream>>>(dst1, E1, dst2, E2, deg1, deg2);
  scan2_kernel<<<2, 1024, 0, stream>>>(deg1, off1, dinv1, deg2, off2, dinv2, n);
  csr_fused<<<(Etot + 255) / 256, 256, 0, stream>>>(src1, dst1, E1, src2, dst2, E2,
                                                    off1, cur1, dinv1, cs1, cw1,
                                                    off2, cur2, dinv2, cs2, cw2);

  transpose_all<<<2176, dim3(32, 8), 0, stream>>>(d_in[3], d_in[5], d_in[7], d_in[9],
                                                  d_in[11], d_in[13],
                                                  Wt11, Wt12, Wt2cat, Wt3cat, flag);

  const int mtiles = (n + 127) / 128;
  // ---- layer 1: input-side aggregation, fused dual-GEMM + bias/ELU/combine
  aggx_kernel<<<(n + 3) / 4, 256, 0, stream>>>(Xb, off1, cs1, cw1, off2, cs2, cw2,
                                               dinv1, dinv2, aggXa, aggXb, n);
  gemm128_l1<<<dim3(8, mtiles), 256, 0, stream>>>(aggXa, Wt11, aggXb, Wt12,
                                                  bf_[0], bf_[1], w01_[0], act1,
                                                  n, 512, 1024);
  // ---- layer 2: concat GEMM (bf16 out) + output-side agg
  gemm128<<<dim3(8, mtiles), 256, 0, stream>>>(act1, Wt2cat, H2cat, n, 1024, 1024);
  agg_out_kernel<512, true><<<(n + 3) / 4, 256, 0, stream>>>(
      H2cat, H2cat + 512, 1024, off1, cs1, cw1, off2, cs2, cw2,
      dinv1, dinv2, bf_[2], bf_[3], w01_[1], act2, n, (const int*)nullptr);
  // ---- layer 3: concat GEMM (bf16 out) + output-side agg -> d_out
  gemm128<<<dim3(2, mtiles), 256, 0, stream>>>(act2, Wt3cat, H3cat, n, 512, 256);
  agg_out_kernel<128, false><<<(n + 15) / 16, 256, 0, stream>>>(
      H3cat, H3cat + 128, 256, off1, cs1, cw1, off2, cs2, cw2,
      dinv1, dinv2, bf_[4], bf_[5], w01_[2], d_out, n, flag);
}

// Round 7
// 352.456 us; speedup vs baseline: 1.7419x; 1.1261x over previous
//
#include <hip/hip_runtime.h>
#include <hip/hip_bf16.h>
#include <math.h>

using bf16 = __hip_bfloat16;
typedef __attribute__((ext_vector_type(8))) short short8;
typedef __attribute__((ext_vector_type(4))) float floatx4;

// ---------------------------------------------------------------- helpers
__device__ inline void gl_lds16(const void* g, void* l) {
  __builtin_amdgcn_global_load_lds(
      (const __attribute__((address_space(1))) unsigned int*)g,
      (__attribute__((address_space(3))) unsigned int*)l,
      16, 0, 0);
}
// fast ELU: branch-free select + v_exp_f32 (error ~1e-7, invisible at bf16)
__device__ inline float eluf(float x) { return x > 0.f ? x : __expf(x) - 1.f; }
__device__ inline float bf2f(unsigned short h) {
  return __uint_as_float(((unsigned)h) << 16);
}
__device__ inline void bf16x8_fma(short8 r, float w, float* acc) {
#pragma unroll
  for (int k = 0; k < 8; k++) acc[k] += w * bf2f((unsigned short)r[k]);
}

// ---------------------------------------------------------------- dtype probe
__global__ void probe_dtype(const unsigned short* __restrict__ x, int* __restrict__ flag) {
  __shared__ int s;
  int t = threadIdx.x;
  if (t == 0) s = 0;
  __syncthreads();
  int bad = 0;
  for (int i = t; i < 1024; i += 256) {
    unsigned short h = x[2 * i];
    unsigned e = (h >> 7) & 0xFF;
    if (e >= 0xE5) bad = 1;
  }
  if (bad) atomicOr(&s, 1);
  __syncthreads();
  if (t == 0) flag[0] = s;
}

__global__ void to_bf16_kernel(const void* __restrict__ in, bf16* __restrict__ out,
                               int nelem, const int* __restrict__ flag) {
  int i = blockIdx.x * 256 + threadIdx.x;
  if (i >= nelem) return;
  if (*flag) out[i] = __float2bfloat16(((const float*)in)[i]);
  else       out[i] = ((const bf16*)in)[i];
}

// biases -> f32; aw -> softmaxed (w0,w1) pairs.
__global__ void small_prep(
    const void* b11, const void* b12, const void* b21, const void* b22,
    const void* b31, const void* b32, const void* aw1, const void* aw2, const void* aw3,
    float* ob11, float* ob12, float* ob21, float* ob22, float* ob31, float* ob32,
    float* ow1, float* ow2, float* ow3, const int* __restrict__ flag) {
  const bool f32 = *flag != 0;
  auto cv = [&](const void* p, int i) -> float {
    return f32 ? ((const float*)p)[i] : __bfloat162float(((const bf16*)p)[i]);
  };
  int t = blockIdx.x * 256 + threadIdx.x;
  if (t < 1024) ob11[t] = cv(b11, t);
  else if (t < 2048) ob12[t - 1024] = cv(b12, t - 1024);
  else if (t < 2560) ob21[t - 2048] = cv(b21, t - 2048);
  else if (t < 3072) ob22[t - 2560] = cv(b22, t - 2560);
  else if (t < 3200) ob31[t - 3072] = cv(b31, t - 3072);
  else if (t < 3328) ob32[t - 3200] = cv(b32, t - 3200);
  else if (t < 4992) {
    int j = t - 3328;
    const void* src; float* dst; int jj;
    if (j < 1024)      { src = aw1; dst = ow1; jj = j; }
    else if (j < 1536) { src = aw2; dst = ow2; jj = j - 1024; }
    else               { src = aw3; dst = ow3; jj = j - 1536; }
    float e0 = cv(src, 2 * jj), e1 = cv(src, 2 * jj + 1);
    float mx = fmaxf(e0, e1);
    float w0 = expf(e0 - mx), w1 = expf(e1 - mx);
    float inv = 1.f / (w0 + w1);
    dst[2 * jj] = w0 * inv;
    dst[2 * jj + 1] = w1 * inv;
  }
}

// ---------------------------------------------------------------- graph prep
__global__ void deg_fused(const int* __restrict__ dst1, int E1,
                          const int* __restrict__ dst2, int E2,
                          int* __restrict__ deg1, int* __restrict__ deg2) {
  int e = blockIdx.x * 256 + threadIdx.x;
  if (e < E1) atomicAdd(&deg1[dst1[e]], 1);
  else if (e < E1 + E2) atomicAdd(&deg2[dst2[e - E1]], 1);
}

__global__ void scan2_kernel(const int* __restrict__ deg1, int* __restrict__ off1,
                             float* __restrict__ dinv1,
                             const int* __restrict__ deg2, int* __restrict__ off2,
                             float* __restrict__ dinv2, int n) {
  const int* deg = blockIdx.x ? deg2 : deg1;
  int* off = blockIdx.x ? off2 : off1;
  float* dinv = blockIdx.x ? dinv2 : dinv1;
  __shared__ int s[1024];
  __shared__ int carry_s;
  int t = threadIdx.x;
  if (t == 0) carry_s = 0;
  __syncthreads();
  for (int base = 0; base < n; base += 1024) {
    int i = base + t;
    int orig = (i < n) ? deg[i] : 0;
    s[t] = orig;
    __syncthreads();
    for (int d = 1; d < 1024; d <<= 1) {
      int add = (t >= d) ? s[t - d] : 0;
      __syncthreads();
      s[t] += add;
      __syncthreads();
    }
    int incl = s[t];
    int carry = carry_s;
    if (i < n) {
      off[i]  = carry + incl - orig;
      dinv[i] = rsqrtf((float)(orig + 1));
    }
    __syncthreads();
    if (t == 1023) carry_s = carry + incl;
    __syncthreads();
  }
  if (t == 0) off[n] = carry_s;
}

__global__ void csr_fused(const int* __restrict__ src1, const int* __restrict__ dst1, int E1,
                          const int* __restrict__ src2, const int* __restrict__ dst2, int E2,
                          const int* __restrict__ off1, int* __restrict__ cur1,
                          const float* __restrict__ dinv1,
                          int* __restrict__ cs1, float* __restrict__ cw1,
                          const int* __restrict__ off2, int* __restrict__ cur2,
                          const float* __restrict__ dinv2,
                          int* __restrict__ cs2, float* __restrict__ cw2) {
  int e = blockIdx.x * 256 + threadIdx.x;
  if (e < E1) {
    int d = dst1[e], s = src1[e];
    int slot = off1[d] + atomicAdd(&cur1[d], 1);
    cs1[slot] = s;
    cw1[slot] = dinv1[s];
  } else if (e < E1 + E2) {
    int ee = e - E1;
    int d = dst2[ee], s = src2[ee];
    int slot = off2[d] + atomicAdd(&cur2[d], 1);
    cs2[slot] = s;
    cw2[slot] = dinv2[s];
  }
}

// All six W[K][N] -> Wt[N][K] transposes in one dispatch.
__global__ void transpose_all(const void* W11, const void* W12, const void* W21,
                              const void* W22, const void* W31, const void* W32,
                              bf16* Wt11, bf16* Wt12, bf16* Wt2cat, bf16* Wt3cat,
                              const int* __restrict__ flag) {
  __shared__ bf16 tile[32][33];
  const bool f32 = *flag != 0;
  int b = blockIdx.x;
  const void* in; bf16* out; int K, N, tt;
  if (b < 512)       { in = W11; out = Wt11; K = 512;  N = 1024; tt = b; }
  else if (b < 1024) { in = W12; out = Wt12; K = 512;  N = 1024; tt = b - 512; }
  else if (b < 1536) { in = W21; out = Wt2cat; K = 1024; N = 512; tt = b - 1024; }
  else if (b < 2048) { in = W22; out = Wt2cat + (size_t)512 * 1024; K = 1024; N = 512; tt = b - 1536; }
  else if (b < 2112) { in = W31; out = Wt3cat; K = 512; N = 128; tt = b - 2048; }
  else               { in = W32; out = Wt3cat + (size_t)128 * 512; K = 512; N = 128; tt = b - 2112; }
  int tilesx = N / 32;
  int bx = (tt % tilesx) * 32;
  int by = (tt / tilesx) * 32;
  int tx = threadIdx.x, ty = threadIdx.y;
#pragma unroll
  for (int i = 0; i < 32; i += 8) {
    size_t idx = (size_t)(by + ty + i) * N + (bx + tx);
    tile[ty + i][tx] = f32 ? __float2bfloat16(((const float*)in)[idx])
                           : ((const bf16*)in)[idx];
  }
  __syncthreads();
#pragma unroll
  for (int i = 0; i < 32; i += 8)
    out[(size_t)(bx + ty + i) * K + (by + tx)] = tile[tx][ty + i];
}

// ---------------------------------------------------------------- input-side agg (layer 1)
__global__ __launch_bounds__(256) void aggx_kernel(
    const bf16* __restrict__ X,
    const int* __restrict__ off1, const int* __restrict__ cs1, const float* __restrict__ cw1,
    const int* __restrict__ off2, const int* __restrict__ cs2, const float* __restrict__ cw2,
    const float* __restrict__ dinv1, const float* __restrict__ dinv2,
    bf16* __restrict__ outA, bf16* __restrict__ outB, int n) {
  int v = blockIdx.x * 4 + (threadIdx.x >> 6);
  if (v >= n) return;
  v = __builtin_amdgcn_readfirstlane(v);
  const int c = (threadIdx.x & 63) * 8;
  const bf16* __restrict__ base = X + c;

  float a[8], b[8];
#pragma unroll
  for (int k = 0; k < 8; k++) { a[k] = 0.f; b[k] = 0.f; }

  int s1 = __builtin_amdgcn_readfirstlane(off1[v]);
  int e1 = __builtin_amdgcn_readfirstlane(off1[v + 1]);
  int i = s1;
  for (; i + 2 <= e1; i += 2) {
    int u0 = cs1[i], u1 = cs1[i + 1];
    float w0 = cw1[i], w1 = cw1[i + 1];
    short8 r0 = *(const short8*)(base + (size_t)u0 * 512);
    short8 r1 = *(const short8*)(base + (size_t)u1 * 512);
    bf16x8_fma(r0, w0, a);
    bf16x8_fma(r1, w1, a);
  }
  if (i < e1) {
    short8 r0 = *(const short8*)(base + (size_t)cs1[i] * 512);
    bf16x8_fma(r0, cw1[i], a);
  }
  int s2 = __builtin_amdgcn_readfirstlane(off2[v]);
  int e2 = __builtin_amdgcn_readfirstlane(off2[v + 1]);
  i = s2;
  for (; i + 2 <= e2; i += 2) {
    int u0 = cs2[i], u1 = cs2[i + 1];
    float w0 = cw2[i], w1 = cw2[i + 1];
    short8 r0 = *(const short8*)(base + (size_t)u0 * 512);
    short8 r1 = *(const short8*)(base + (size_t)u1 * 512);
    bf16x8_fma(r0, w0, b);
    bf16x8_fma(r1, w1, b);
  }
  if (i < e2) {
    short8 r0 = *(const short8*)(base + (size_t)cs2[i] * 512);
    bf16x8_fma(r0, cw2[i], b);
  }

  short8 self = *(const short8*)(base + (size_t)v * 512);
  const float dv1 = dinv1[v], dv2 = dinv2[v];
  short8 ra, rb;
#pragma unroll
  for (int k = 0; k < 8; k++) {
    float xs = bf2f((unsigned short)self[k]);
    ra[k] = (short)__bfloat16_as_ushort(__float2bfloat16(dv1 * a[k] + dv1 * dv1 * xs));
    rb[k] = (short)__bfloat16_as_ushort(__float2bfloat16(dv2 * b[k] + dv2 * dv2 * xs));
  }
  *(short8*)(outA + (size_t)v * 512 + c) = ra;
  *(short8*)(outB + (size_t)v * 512 + c) = rb;
}

// ---------------------------------------------------------------- GEMM (m97-style)
// C[M][N] = A[M][K] @ Bt[N][K]^T, 128x128 tile, single acc set (occupancy!)
__device__ inline void gemm_body(const bf16* __restrict__ A, const bf16* __restrict__ Bt,
                                 bf16* __restrict__ C, int M, int K, int N,
                                 int m0, int n0) {
  __shared__ bf16 As[128 * 32];
  __shared__ bf16 Bs[128 * 32];
  const int tid = threadIdx.x;
  const int wave = tid >> 6;
  const int lane = tid & 63;
  const int quad = lane >> 4;
  const int l16 = lane & 15;
  const int wr = (wave >> 1) * 64;
  const int wc = (wave & 1) * 64;
  const int r_sub = lane >> 2;
  const int cb = (lane & 3) * 16;

  floatx4 acc[4][4];
#pragma unroll
  for (int i = 0; i < 4; i++)
#pragma unroll
    for (int j = 0; j < 4; j++) acc[i][j] = (floatx4){0.f, 0.f, 0.f, 0.f};

  for (int k0 = 0; k0 < K; k0 += 32) {
    __syncthreads();
#pragma unroll
    for (int j = 0; j < 2; ++j) {
      int p = wave * 2 + j;
      int ra = p * 16 + r_sub;
      int grow = m0 + ra; if (grow >= M) grow = M - 1;
      gl_lds16((const char*)(A + (size_t)grow * K + k0) + cb, (char*)As + p * 1024);
      int rb = n0 + p * 16 + r_sub;
      gl_lds16((const char*)(Bt + (size_t)rb * K + k0) + cb, (char*)Bs + p * 1024);
    }
    __syncthreads();

    short8 af[4], bfr[4];
#pragma unroll
    for (int i = 0; i < 4; i++)
      af[i] = *(const short8*)(As + (wr + i * 16 + l16) * 32 + quad * 8);
#pragma unroll
    for (int j = 0; j < 4; j++)
      bfr[j] = *(const short8*)(Bs + (wc + j * 16 + l16) * 32 + quad * 8);
#pragma unroll
    for (int i = 0; i < 4; i++)
#pragma unroll
      for (int j = 0; j < 4; j++)
        acc[i][j] = __builtin_amdgcn_mfma_f32_16x16x32_bf16(af[i], bfr[j], acc[i][j], 0, 0, 0);
  }

#pragma unroll
  for (int i = 0; i < 4; i++) {
#pragma unroll
    for (int r = 0; r < 4; r++) {
      int row = m0 + wr + i * 16 + quad * 4 + r;
      if (row < M) {
#pragma unroll
        for (int j = 0; j < 4; j++) {
          int col = n0 + wc + j * 16 + l16;
          C[(size_t)row * N + col] = __float2bfloat16(acc[i][j][r]);
        }
      }
    }
  }
}

__global__ __launch_bounds__(256) void gemm128(const bf16* __restrict__ A,
                                               const bf16* __restrict__ Bt,
                                               bf16* __restrict__ C, int M, int K, int N) {
  gemm_body(A, Bt, C, M, K, N, blockIdx.y * 128, blockIdx.x * 128);
}

// two independent GEMMs (same M,K,N) in one dispatch: blockIdx.y selects half
__global__ __launch_bounds__(256) void gemm128_dual(
    const bf16* __restrict__ A0, const bf16* __restrict__ Bt0, bf16* __restrict__ C0,
    const bf16* __restrict__ A1, const bf16* __restrict__ Bt1, bf16* __restrict__ C1,
    int M, int K, int N, int mtiles) {
  int half = blockIdx.y / mtiles;
  int by = blockIdx.y % mtiles;
  const bf16* A = half ? A1 : A0;
  const bf16* Bt = half ? Bt1 : Bt0;
  bf16* C = half ? C1 : C0;
  gemm_body(A, Bt, C, M, K, N, by * 128, blockIdx.x * 128);
}

// ---------------------------------------------------------------- layer-1 epilogue
__global__ __launch_bounds__(256) void combine1_kernel(
    const bf16* __restrict__ Ha, const bf16* __restrict__ Hb,
    const float* __restrict__ ba, const float* __restrict__ bb,
    const float* __restrict__ w01, bf16* __restrict__ out, int total) {
  int e = (blockIdx.x * 256 + threadIdx.x) * 8;
  if (e >= total) return;
  int c = e & 1023;
  short8 ha = *(const short8*)(Ha + e);
  short8 hb = *(const short8*)(Hb + e);
  short8 r;
#pragma unroll
  for (int k = 0; k < 8; k++) {
    float x = eluf(bf2f((unsigned short)ha[k]) + ba[c + k]);
    float y = eluf(bf2f((unsigned short)hb[k]) + bb[c + k]);
    r[k] = (short)__bfloat16_as_ushort(
        __float2bfloat16(x * w01[2 * (c + k)] + y * w01[2 * (c + k) + 1]));
  }
  *(short8*)(out + e) = r;
}

// ---------------------------------------------------------------- output-side agg (layers 2,3)
template <int C, bool WU>
__global__ __launch_bounds__(256) void agg_out_kernel(
    const bf16* __restrict__ Ha, const bf16* __restrict__ Hb, int ldH,
    const int* __restrict__ off1, const int* __restrict__ cs1, const float* __restrict__ cw1,
    const int* __restrict__ off2, const int* __restrict__ cs2, const float* __restrict__ cw2,
    const float* __restrict__ dinv1, const float* __restrict__ dinv2,
    const float* __restrict__ ba, const float* __restrict__ bb,
    const float* __restrict__ w01, void* __restrict__ out, int n,
    const int* __restrict__ outflag) {
  constexpr int TPV = C / 8;
  constexpr int G = 256 / TPV;
  const int t = threadIdx.x;
  int v = blockIdx.x * G + t / TPV;
  if (v >= n) return;
  if (WU) v = __builtin_amdgcn_readfirstlane(v);
  const int c = (t % TPV) * 8;
  const bf16* __restrict__ baseA = Ha + c;
  const bf16* __restrict__ baseB = Hb + c;

  float a[8], b[8];
#pragma unroll
  for (int k = 0; k < 8; k++) { a[k] = 0.f; b[k] = 0.f; }

  int s1 = off1[v], e1 = off1[v + 1];
  if (WU) { s1 = __builtin_amdgcn_readfirstlane(s1); e1 = __builtin_amdgcn_readfirstlane(e1); }
  int i = s1;
  for (; i + 2 <= e1; i += 2) {
    int u0 = cs1[i], u1 = cs1[i + 1];
    float w0 = cw1[i], w1 = cw1[i + 1];
    short8 r0 = *(const short8*)(baseA + (size_t)u0 * ldH);
    short8 r1 = *(const short8*)(baseA + (size_t)u1 * ldH);
    bf16x8_fma(r0, w0, a);
    bf16x8_fma(r1, w1, a);
  }
  if (i < e1) {
    short8 r0 = *(const short8*)(baseA + (size_t)cs1[i] * ldH);
    bf16x8_fma(r0, cw1[i], a);
  }
  int s2 = off2[v], e2 = off2[v + 1];
  if (WU) { s2 = __builtin_amdgcn_readfirstlane(s2); e2 = __builtin_amdgcn_readfirstlane(e2); }
  i = s2;
  for (; i + 2 <= e2; i += 2) {
    int u0 = cs2[i], u1 = cs2[i + 1];
    float w0 = cw2[i], w1 = cw2[i + 1];
    short8 r0 = *(const short8*)(baseB + (size_t)u0 * ldH);
    short8 r1 = *(const short8*)(baseB + (size_t)u1 * ldH);
    bf16x8_fma(r0, w0, b);
    bf16x8_fma(r1, w1, b);
  }
  if (i < e2) {
    short8 r0 = *(const short8*)(baseB + (size_t)cs2[i] * ldH);
    bf16x8_fma(r0, cw2[i], b);
  }

  short8 sa = *(const short8*)(baseA + (size_t)v * ldH);
  short8 sb = *(const short8*)(baseB + (size_t)v * ldH);
  const float dv1 = dinv1[v], dv2 = dinv2[v];

  float r[8];
#pragma unroll
  for (int k = 0; k < 8; k++) {
    float x = eluf(dv1 * a[k] + dv1 * dv1 * bf2f((unsigned short)sa[k]) + ba[c + k]);
    float y = eluf(dv2 * b[k] + dv2 * dv2 * bf2f((unsigned short)sb[k]) + bb[c + k]);
    r[k] = x * w01[2 * (c + k)] + y * w01[2 * (c + k) + 1];
  }

  const bool out_f32 = (outflag != nullptr) && (*outflag != 0);
  size_t oi = (size_t)v * C + c;
  if (out_f32) {
    floatx4 lo = {r[0], r[1], r[2], r[3]};
    floatx4 hi = {r[4], r[5], r[6], r[7]};
    *(floatx4*)((float*)out + oi) = lo;
    *(floatx4*)((float*)out + oi + 4) = hi;
  } else {
    short8 rb;
#pragma unroll
    for (int k = 0; k < 8; k++)
      rb[k] = (short)__bfloat16_as_ushort(__float2bfloat16(r[k]));
    *(short8*)((bf16*)out + oi) = rb;
  }
}

// ---------------------------------------------------------------- host pipeline
extern "C" void kernel_launch(void* const* d_in, const int* in_sizes, int n_in,
                              void* d_out, int out_size, void* d_ws, size_t ws_size,
                              hipStream_t stream) {
  const void* X = d_in[0];
  const int* ei1 = (const int*)d_in[1];
  const int* ei2 = (const int*)d_in[2];
  const int n = in_sizes[0] / 512;
  const int E1 = in_sizes[1] / 2;
  const int E2 = in_sizes[2] / 2;
  const int* src1 = ei1;           const int* dst1 = ei1 + E1;
  const int* src2 = ei2;           const int* dst2 = ei2 + E2;

  auto rnd = [](size_t b) { return (b + 255) & ~(size_t)255; };
  char* p = (char*)d_ws;
  auto alloc = [&](size_t bytes) { char* r = p; p += rnd(bytes); return r; };

  int* flag = (int*)alloc(256);
  int* deg1 = (int*)alloc((size_t)n * 4);
  int* deg2 = (int*)alloc((size_t)n * 4);
  int* cur1 = (int*)alloc((size_t)n * 4);
  int* cur2 = (int*)alloc((size_t)n * 4);
  int* off1 = (int*)alloc((size_t)(n + 1) * 4);
  int* off2 = (int*)alloc((size_t)(n + 1) * 4);
  float* dinv1 = (float*)alloc((size_t)n * 4);
  float* dinv2 = (float*)alloc((size_t)n * 4);
  int* cs1 = (int*)alloc((size_t)E1 * 4);
  float* cw1 = (float*)alloc((size_t)E1 * 4);
  int* cs2 = (int*)alloc((size_t)E2 * 4);
  float* cw2 = (float*)alloc((size_t)E2 * 4);
  bf16* Wt11 = (bf16*)alloc((size_t)512 * 1024 * 2);
  bf16* Wt12 = (bf16*)alloc((size_t)512 * 1024 * 2);
  bf16* Wt2cat = (bf16*)alloc((size_t)1024 * 1024 * 2);
  bf16* Wt3cat = (bf16*)alloc((size_t)256 * 512 * 2);
  float* bf_[6]; int bsz[6] = {1024, 1024, 512, 512, 128, 128};
  for (int i = 0; i < 6; i++) bf_[i] = (float*)alloc((size_t)bsz[i] * 4);
  float* w01_[3]; int asz[3] = {2048, 1024, 256};
  for (int i = 0; i < 3; i++) w01_[i] = (float*)alloc((size_t)asz[i] * 4);
  bf16* Xb = (bf16*)alloc((size_t)n * 512 * 2);
  bf16* aggXa = (bf16*)alloc((size_t)n * 512 * 2);
  bf16* aggXb = (bf16*)alloc((size_t)n * 512 * 2);
  bf16* H1a = (bf16*)alloc((size_t)n * 1024 * 2);
  bf16* H1b = (bf16*)alloc((size_t)n * 1024 * 2);
  bf16* act1 = (bf16*)alloc((size_t)n * 1024 * 2);
  bf16* H2cat = H1a;   // dead after combine1
  bf16* act2 = aggXa;  // dead after gemm_dual
  bf16* H3cat = H1b;   // dead after combine1

  probe_dtype<<<1, 256, 0, stream>>>((const unsigned short*)X, flag);
  hipMemsetAsync(deg1, 0, rnd((size_t)n * 4) * 4, stream);  // deg1,deg2,cur1,cur2

  to_bf16_kernel<<<(n * 512 + 255) / 256, 256, 0, stream>>>(X, Xb, n * 512, flag);
  small_prep<<<20, 256, 0, stream>>>(d_in[4], d_in[6], d_in[8], d_in[10], d_in[12], d_in[14],
                                     d_in[15], d_in[16], d_in[17],
                                     bf_[0], bf_[1], bf_[2], bf_[3], bf_[4], bf_[5],
                                     w01_[0], w01_[1], w01_[2], flag);

  int Etot = E1 + E2;
  deg_fused<<<(Etot + 255) / 256, 256, 0, stream>>>(dst1, E1, dst2, E2, deg1, deg2);
  scan2_kernel<<<2, 1024, 0, stream>>>(deg1, off1, dinv1, deg2, off2, dinv2, n);
  csr_fused<<<(Etot + 255) / 256, 256, 0, stream>>>(src1, dst1, E1, src2, dst2, E2,
                                                    off1, cur1, dinv1, cs1, cw1,
                                                    off2, cur2, dinv2, cs2, cw2);

  transpose_all<<<2176, dim3(32, 8), 0, stream>>>(d_in[3], d_in[5], d_in[7], d_in[9],
                                                  d_in[11], d_in[13],
                                                  Wt11, Wt12, Wt2cat, Wt3cat, flag);

  const int mtiles = (n + 127) / 128;
  // ---- layer 1: input-side aggregation, dual GEMM, fast elementwise combine
  aggx_kernel<<<(n + 3) / 4, 256, 0, stream>>>(Xb, off1, cs1, cw1, off2, cs2, cw2,
                                               dinv1, dinv2, aggXa, aggXb, n);
  gemm128_dual<<<dim3(8, 2 * mtiles), 256, 0, stream>>>(aggXa, Wt11, H1a,
                                                        aggXb, Wt12, H1b,
                                                        n, 512, 1024, mtiles);
  combine1_kernel<<<(n * 1024 / 8 + 255) / 256, 256, 0, stream>>>(
      H1a, H1b, bf_[0], bf_[1], w01_[0], act1, n * 1024);
  // ---- layer 2: concat GEMM (bf16 out) + output-side agg
  gemm128<<<dim3(8, mtiles), 256, 0, stream>>>(act1, Wt2cat, H2cat, n, 1024, 1024);
  agg_out_kernel<512, true><<<(n + 3) / 4, 256, 0, stream>>>(
      H2cat, H2cat + 512, 1024, off1, cs1, cw1, off2, cs2, cw2,
      dinv1, dinv2, bf_[2], bf_[3], w01_[1], act2, n, (const int*)nullptr);
  // ---- layer 3: concat GEMM (bf16 out) + output-side agg -> d_out
  gemm128<<<dim3(2, mtiles), 256, 0, stream>>>(act2, Wt3cat, H3cat, n, 512, 256);
  agg_out_kernel<128, false><<<(n + 15) / 16, 256, 0, stream>>>(
      H3cat, H3cat + 128, 256, off1, cs1, cw1, off2, cs2, cw2,
      dinv1, dinv2, bf_[4], bf_[5], w01_[2], d_out, n, flag);
}

// Round 8
// 345.328 us; speedup vs baseline: 1.7779x; 1.0206x over previous
//
#include <hip/hip_runtime.h>
#include <hip/hip_bf16.h>
#include <math.h>

using bf16 = __hip_bfloat16;
typedef __attribute__((ext_vector_type(8))) short short8;
typedef __attribute__((ext_vector_type(4))) float floatx4;

// ---------------------------------------------------------------- helpers
__device__ inline void gl_lds16(const void* g, void* l) {
  __builtin_amdgcn_global_load_lds(
      (const __attribute__((address_space(1))) unsigned int*)g,
      (__attribute__((address_space(3))) unsigned int*)l,
      16, 0, 0);
}
// fast ELU: branch-free select + v_exp_f32 (error ~1e-7, invisible at bf16)
__device__ inline float eluf(float x) { return x > 0.f ? x : __expf(x) - 1.f; }
__device__ inline float bf2f(unsigned short h) {
  return __uint_as_float(((unsigned)h) << 16);
}
__device__ inline void bf16x8_fma(short8 r, float w, float* acc) {
#pragma unroll
  for (int k = 0; k < 8; k++) acc[k] += w * bf2f((unsigned short)r[k]);
}

// ---------------------------------------------------------------- dtype probe
__global__ void probe_dtype(const unsigned short* __restrict__ x, int* __restrict__ flag) {
  __shared__ int s;
  int t = threadIdx.x;
  if (t == 0) s = 0;
  __syncthreads();
  int bad = 0;
  for (int i = t; i < 1024; i += 256) {
    unsigned short h = x[2 * i];
    unsigned e = (h >> 7) & 0xFF;
    if (e >= 0xE5) bad = 1;
  }
  if (bad) atomicOr(&s, 1);
  __syncthreads();
  if (t == 0) flag[0] = s;
}

__global__ void to_bf16_kernel(const void* __restrict__ in, bf16* __restrict__ out,
                               int nelem, const int* __restrict__ flag) {
  int i = blockIdx.x * 256 + threadIdx.x;
  if (i >= nelem) return;
  if (*flag) out[i] = __float2bfloat16(((const float*)in)[i]);
  else       out[i] = ((const bf16*)in)[i];
}

// biases -> f32; aw -> softmaxed (w0,w1) pairs.
__global__ void small_prep(
    const void* b11, const void* b12, const void* b21, const void* b22,
    const void* b31, const void* b32, const void* aw1, const void* aw2, const void* aw3,
    float* ob11, float* ob12, float* ob21, float* ob22, float* ob31, float* ob32,
    float* ow1, float* ow2, float* ow3, const int* __restrict__ flag) {
  const bool f32 = *flag != 0;
  auto cv = [&](const void* p, int i) -> float {
    return f32 ? ((const float*)p)[i] : __bfloat162float(((const bf16*)p)[i]);
  };
  int t = blockIdx.x * 256 + threadIdx.x;
  if (t < 1024) ob11[t] = cv(b11, t);
  else if (t < 2048) ob12[t - 1024] = cv(b12, t - 1024);
  else if (t < 2560) ob21[t - 2048] = cv(b21, t - 2048);
  else if (t < 3072) ob22[t - 2560] = cv(b22, t - 2560);
  else if (t < 3200) ob31[t - 3072] = cv(b31, t - 3072);
  else if (t < 3328) ob32[t - 3200] = cv(b32, t - 3200);
  else if (t < 4992) {
    int j = t - 3328;
    const void* src; float* dst; int jj;
    if (j < 1024)      { src = aw1; dst = ow1; jj = j; }
    else if (j < 1536) { src = aw2; dst = ow2; jj = j - 1024; }
    else               { src = aw3; dst = ow3; jj = j - 1536; }
    float e0 = cv(src, 2 * jj), e1 = cv(src, 2 * jj + 1);
    float mx = fmaxf(e0, e1);
    float w0 = expf(e0 - mx), w1 = expf(e1 - mx);
    float inv = 1.f / (w0 + w1);
    dst[2 * jj] = w0 * inv;
    dst[2 * jj + 1] = w1 * inv;
  }
}

// ---------------------------------------------------------------- graph prep
__global__ void deg_fused(const int* __restrict__ dst1, int E1,
                          const int* __restrict__ dst2, int E2,
                          int* __restrict__ deg1, int* __restrict__ deg2) {
  int e = blockIdx.x * 256 + threadIdx.x;
  if (e < E1) atomicAdd(&deg1[dst1[e]], 1);
  else if (e < E1 + E2) atomicAdd(&deg2[dst2[e - E1]], 1);
}

__global__ void scan2_kernel(const int* __restrict__ deg1, int* __restrict__ off1,
                             float* __restrict__ dinv1,
                             const int* __restrict__ deg2, int* __restrict__ off2,
                             float* __restrict__ dinv2, int n) {
  const int* deg = blockIdx.x ? deg2 : deg1;
  int* off = blockIdx.x ? off2 : off1;
  float* dinv = blockIdx.x ? dinv2 : dinv1;
  __shared__ int s[1024];
  __shared__ int carry_s;
  int t = threadIdx.x;
  if (t == 0) carry_s = 0;
  __syncthreads();
  for (int base = 0; base < n; base += 1024) {
    int i = base + t;
    int orig = (i < n) ? deg[i] : 0;
    s[t] = orig;
    __syncthreads();
    for (int d = 1; d < 1024; d <<= 1) {
      int add = (t >= d) ? s[t - d] : 0;
      __syncthreads();
      s[t] += add;
      __syncthreads();
    }
    int incl = s[t];
    int carry = carry_s;
    if (i < n) {
      off[i]  = carry + incl - orig;
      dinv[i] = rsqrtf((float)(orig + 1));
    }
    __syncthreads();
    if (t == 1023) carry_s = carry + incl;
    __syncthreads();
  }
  if (t == 0) off[n] = carry_s;
}

__global__ void csr_fused(const int* __restrict__ src1, const int* __restrict__ dst1, int E1,
                          const int* __restrict__ src2, const int* __restrict__ dst2, int E2,
                          const int* __restrict__ off1, int* __restrict__ cur1,
                          const float* __restrict__ dinv1,
                          int* __restrict__ cs1, float* __restrict__ cw1,
                          const int* __restrict__ off2, int* __restrict__ cur2,
                          const float* __restrict__ dinv2,
                          int* __restrict__ cs2, float* __restrict__ cw2) {
  int e = blockIdx.x * 256 + threadIdx.x;
  if (e < E1) {
    int d = dst1[e], s = src1[e];
    int slot = off1[d] + atomicAdd(&cur1[d], 1);
    cs1[slot] = s;
    cw1[slot] = dinv1[s];
  } else if (e < E1 + E2) {
    int ee = e - E1;
    int d = dst2[ee], s = src2[ee];
    int slot = off2[d] + atomicAdd(&cur2[d], 1);
    cs2[slot] = s;
    cw2[slot] = dinv2[s];
  }
}

// All six W[K][N] -> Wt[N][K] transposes in one dispatch.
__global__ void transpose_all(const void* W11, const void* W12, const void* W21,
                              const void* W22, const void* W31, const void* W32,
                              bf16* Wt11, bf16* Wt12, bf16* Wt2cat, bf16* Wt3cat,
                              const int* __restrict__ flag) {
  __shared__ bf16 tile[32][33];
  const bool f32 = *flag != 0;
  int b = blockIdx.x;
  const void* in; bf16* out; int K, N, tt;
  if (b < 512)       { in = W11; out = Wt11; K = 512;  N = 1024; tt = b; }
  else if (b < 1024) { in = W12; out = Wt12; K = 512;  N = 1024; tt = b - 512; }
  else if (b < 1536) { in = W21; out = Wt2cat; K = 1024; N = 512; tt = b - 1024; }
  else if (b < 2048) { in = W22; out = Wt2cat + (size_t)512 * 1024; K = 1024; N = 512; tt = b - 1536; }
  else if (b < 2112) { in = W31; out = Wt3cat; K = 512; N = 128; tt = b - 2048; }
  else               { in = W32; out = Wt3cat + (size_t)128 * 512; K = 512; N = 128; tt = b - 2112; }
  int tilesx = N / 32;
  int bx = (tt % tilesx) * 32;
  int by = (tt / tilesx) * 32;
  int tx = threadIdx.x, ty = threadIdx.y;
#pragma unroll
  for (int i = 0; i < 32; i += 8) {
    size_t idx = (size_t)(by + ty + i) * N + (bx + tx);
    tile[ty + i][tx] = f32 ? __float2bfloat16(((const float*)in)[idx])
                           : ((const bf16*)in)[idx];
  }
  __syncthreads();
#pragma unroll
  for (int i = 0; i < 32; i += 8)
    out[(size_t)(bx + ty + i) * K + (by + tx)] = tile[tx][ty + i];
}

// ---------------------------------------------------------------- input-side agg (layer 1)
__global__ __launch_bounds__(256) void aggx_kernel(
    const bf16* __restrict__ X,
    const int* __restrict__ off1, const int* __restrict__ cs1, const float* __restrict__ cw1,
    const int* __restrict__ off2, const int* __restrict__ cs2, const float* __restrict__ cw2,
    const float* __restrict__ dinv1, const float* __restrict__ dinv2,
    bf16* __restrict__ outA, bf16* __restrict__ outB, int n) {
  int v = blockIdx.x * 4 + (threadIdx.x >> 6);
  if (v >= n) return;
  v = __builtin_amdgcn_readfirstlane(v);
  const int c = (threadIdx.x & 63) * 8;
  const bf16* __restrict__ base = X + c;

  float a[8], b[8];
#pragma unroll
  for (int k = 0; k < 8; k++) { a[k] = 0.f; b[k] = 0.f; }

  int s1 = __builtin_amdgcn_readfirstlane(off1[v]);
  int e1 = __builtin_amdgcn_readfirstlane(off1[v + 1]);
  int i = s1;
  for (; i + 4 <= e1; i += 4) {
    int u0 = cs1[i], u1 = cs1[i + 1], u2 = cs1[i + 2], u3 = cs1[i + 3];
    float w0 = cw1[i], w1 = cw1[i + 1], w2 = cw1[i + 2], w3 = cw1[i + 3];
    short8 r0 = *(const short8*)(base + (size_t)u0 * 512);
    short8 r1 = *(const short8*)(base + (size_t)u1 * 512);
    short8 r2 = *(const short8*)(base + (size_t)u2 * 512);
    short8 r3 = *(const short8*)(base + (size_t)u3 * 512);
    bf16x8_fma(r0, w0, a); bf16x8_fma(r1, w1, a);
    bf16x8_fma(r2, w2, a); bf16x8_fma(r3, w3, a);
  }
  for (; i + 2 <= e1; i += 2) {
    int u0 = cs1[i], u1 = cs1[i + 1];
    float w0 = cw1[i], w1 = cw1[i + 1];
    short8 r0 = *(const short8*)(base + (size_t)u0 * 512);
    short8 r1 = *(const short8*)(base + (size_t)u1 * 512);
    bf16x8_fma(r0, w0, a); bf16x8_fma(r1, w1, a);
  }
  if (i < e1) {
    short8 r0 = *(const short8*)(base + (size_t)cs1[i] * 512);
    bf16x8_fma(r0, cw1[i], a);
  }
  int s2 = __builtin_amdgcn_readfirstlane(off2[v]);
  int e2 = __builtin_amdgcn_readfirstlane(off2[v + 1]);
  i = s2;
  for (; i + 4 <= e2; i += 4) {
    int u0 = cs2[i], u1 = cs2[i + 1], u2 = cs2[i + 2], u3 = cs2[i + 3];
    float w0 = cw2[i], w1 = cw2[i + 1], w2 = cw2[i + 2], w3 = cw2[i + 3];
    short8 r0 = *(const short8*)(base + (size_t)u0 * 512);
    short8 r1 = *(const short8*)(base + (size_t)u1 * 512);
    short8 r2 = *(const short8*)(base + (size_t)u2 * 512);
    short8 r3 = *(const short8*)(base + (size_t)u3 * 512);
    bf16x8_fma(r0, w0, b); bf16x8_fma(r1, w1, b);
    bf16x8_fma(r2, w2, b); bf16x8_fma(r3, w3, b);
  }
  for (; i + 2 <= e2; i += 2) {
    int u0 = cs2[i], u1 = cs2[i + 1];
    float w0 = cw2[i], w1 = cw2[i + 1];
    short8 r0 = *(const short8*)(base + (size_t)u0 * 512);
    short8 r1 = *(const short8*)(base + (size_t)u1 * 512);
    bf16x8_fma(r0, w0, b); bf16x8_fma(r1, w1, b);
  }
  if (i < e2) {
    short8 r0 = *(const short8*)(base + (size_t)cs2[i] * 512);
    bf16x8_fma(r0, cw2[i], b);
  }

  short8 self = *(const short8*)(base + (size_t)v * 512);
  const float dv1 = dinv1[v], dv2 = dinv2[v];
  short8 ra, rb;
#pragma unroll
  for (int k = 0; k < 8; k++) {
    float xs = bf2f((unsigned short)self[k]);
    ra[k] = (short)__bfloat16_as_ushort(__float2bfloat16(dv1 * a[k] + dv1 * dv1 * xs));
    rb[k] = (short)__bfloat16_as_ushort(__float2bfloat16(dv2 * b[k] + dv2 * dv2 * xs));
  }
  *(short8*)(outA + (size_t)v * 512 + c) = ra;
  *(short8*)(outB + (size_t)v * 512 + c) = rb;
}

// ---------------------------------------------------------------- GEMM (m97-style)
__device__ inline void gemm_body(const bf16* __restrict__ A, const bf16* __restrict__ Bt,
                                 bf16* __restrict__ C, int M, int K, int N,
                                 int m0, int n0) {
  __shared__ bf16 As[128 * 32];
  __shared__ bf16 Bs[128 * 32];
  const int tid = threadIdx.x;
  const int wave = tid >> 6;
  const int lane = tid & 63;
  const int quad = lane >> 4;
  const int l16 = lane & 15;
  const int wr = (wave >> 1) * 64;
  const int wc = (wave & 1) * 64;
  const int r_sub = lane >> 2;
  const int cb = (lane & 3) * 16;

  floatx4 acc[4][4];
#pragma unroll
  for (int i = 0; i < 4; i++)
#pragma unroll
    for (int j = 0; j < 4; j++) acc[i][j] = (floatx4){0.f, 0.f, 0.f, 0.f};

  for (int k0 = 0; k0 < K; k0 += 32) {
    __syncthreads();
#pragma unroll
    for (int j = 0; j < 2; ++j) {
      int p = wave * 2 + j;
      int ra = p * 16 + r_sub;
      int grow = m0 + ra; if (grow >= M) grow = M - 1;
      gl_lds16((const char*)(A + (size_t)grow * K + k0) + cb, (char*)As + p * 1024);
      int rb = n0 + p * 16 + r_sub;
      gl_lds16((const char*)(Bt + (size_t)rb * K + k0) + cb, (char*)Bs + p * 1024);
    }
    __syncthreads();

    short8 af[4], bfr[4];
#pragma unroll
    for (int i = 0; i < 4; i++)
      af[i] = *(const short8*)(As + (wr + i * 16 + l16) * 32 + quad * 8);
#pragma unroll
    for (int j = 0; j < 4; j++)
      bfr[j] = *(const short8*)(Bs + (wc + j * 16 + l16) * 32 + quad * 8);
#pragma unroll
    for (int i = 0; i < 4; i++)
#pragma unroll
      for (int j = 0; j < 4; j++)
        acc[i][j] = __builtin_amdgcn_mfma_f32_16x16x32_bf16(af[i], bfr[j], acc[i][j], 0, 0, 0);
  }

#pragma unroll
  for (int i = 0; i < 4; i++) {
#pragma unroll
    for (int r = 0; r < 4; r++) {
      int row = m0 + wr + i * 16 + quad * 4 + r;
      if (row < M) {
#pragma unroll
        for (int j = 0; j < 4; j++) {
          int col = n0 + wc + j * 16 + l16;
          C[(size_t)row * N + col] = __float2bfloat16(acc[i][j][r]);
        }
      }
    }
  }
}

// XCD-swizzled (dual-capable) GEMM: 1D grid; xcd = lin&7 gets m-tiles {xcd, xcd+8,...},
// the ntiles n-tiles of one m-tile in consecutive per-XCD slots -> A-tile fetched
// once per XCD L2 instead of 8x across XCDs.
__global__ __launch_bounds__(256) void gemm128_sw(
    const bf16* __restrict__ A0, const bf16* __restrict__ Bt0, bf16* __restrict__ C0,
    const bf16* __restrict__ A1, const bf16* __restrict__ Bt1, bf16* __restrict__ C1,
    int M, int K, int N, int mtilesPerHalf, int mtTotal, int ntLog2) {
  int lin = blockIdx.x;
  int g = lin & 7;
  int s = lin >> 3;
  int n_t = s & ((1 << ntLog2) - 1);
  int m_t = g + 8 * (s >> ntLog2);
  if (m_t >= mtTotal) return;
  int half = (m_t >= mtilesPerHalf) ? 1 : 0;
  int m_local = m_t - half * mtilesPerHalf;
  const bf16* A = half ? A1 : A0;
  const bf16* Bt = half ? Bt1 : Bt0;
  bf16* C = half ? C1 : C0;
  gemm_body(A, Bt, C, M, K, N, m_local * 128, n_t * 128);
}

// ---------------------------------------------------------------- layer-1 epilogue
__global__ __launch_bounds__(256) void combine1_kernel(
    const bf16* __restrict__ Ha, const bf16* __restrict__ Hb,
    const float* __restrict__ ba, const float* __restrict__ bb,
    const float* __restrict__ w01, bf16* __restrict__ out, int total) {
  int e = (blockIdx.x * 256 + threadIdx.x) * 8;
  if (e >= total) return;
  int c = e & 1023;
  short8 ha = *(const short8*)(Ha + e);
  short8 hb = *(const short8*)(Hb + e);
  short8 r;
#pragma unroll
  for (int k = 0; k < 8; k++) {
    float x = eluf(bf2f((unsigned short)ha[k]) + ba[c + k]);
    float y = eluf(bf2f((unsigned short)hb[k]) + bb[c + k]);
    r[k] = (short)__bfloat16_as_ushort(
        __float2bfloat16(x * w01[2 * (c + k)] + y * w01[2 * (c + k) + 1]));
  }
  *(short8*)(out + e) = r;
}

// ---------------------------------------------------------------- output-side agg (layers 2,3)
template <int C, bool WU>
__global__ __launch_bounds__(256) void agg_out_kernel(
    const bf16* __restrict__ Ha, const bf16* __restrict__ Hb, int ldH,
    const int* __restrict__ off1, const int* __restrict__ cs1, const float* __restrict__ cw1,
    const int* __restrict__ off2, const int* __restrict__ cs2, const float* __restrict__ cw2,
    const float* __restrict__ dinv1, const float* __restrict__ dinv2,
    const float* __restrict__ ba, const float* __restrict__ bb,
    const float* __restrict__ w01, void* __restrict__ out, int n,
    const int* __restrict__ outflag) {
  constexpr int TPV = C / 8;
  constexpr int G = 256 / TPV;
  const int t = threadIdx.x;
  int v = blockIdx.x * G + t / TPV;
  if (v >= n) return;
  if (WU) v = __builtin_amdgcn_readfirstlane(v);
  const int c = (t % TPV) * 8;
  const bf16* __restrict__ baseA = Ha + c;
  const bf16* __restrict__ baseB = Hb + c;

  float a[8], b[8];
#pragma unroll
  for (int k = 0; k < 8; k++) { a[k] = 0.f; b[k] = 0.f; }

  int s1 = off1[v], e1 = off1[v + 1];
  if (WU) { s1 = __builtin_amdgcn_readfirstlane(s1); e1 = __builtin_amdgcn_readfirstlane(e1); }
  int i = s1;
  for (; i + 4 <= e1; i += 4) {
    int u0 = cs1[i], u1 = cs1[i + 1], u2 = cs1[i + 2], u3 = cs1[i + 3];
    float w0 = cw1[i], w1 = cw1[i + 1], w2 = cw1[i + 2], w3 = cw1[i + 3];
    short8 r0 = *(const short8*)(baseA + (size_t)u0 * ldH);
    short8 r1 = *(const short8*)(baseA + (size_t)u1 * ldH);
    short8 r2 = *(const short8*)(baseA + (size_t)u2 * ldH);
    short8 r3 = *(const short8*)(baseA + (size_t)u3 * ldH);
    bf16x8_fma(r0, w0, a); bf16x8_fma(r1, w1, a);
    bf16x8_fma(r2, w2, a); bf16x8_fma(r3, w3, a);
  }
  for (; i + 2 <= e1; i += 2) {
    int u0 = cs1[i], u1 = cs1[i + 1];
    float w0 = cw1[i], w1 = cw1[i + 1];
    short8 r0 = *(const short8*)(baseA + (size_t)u0 * ldH);
    short8 r1 = *(const short8*)(baseA + (size_t)u1 * ldH);
    bf16x8_fma(r0, w0, a); bf16x8_fma(r1, w1, a);
  }
  if (i < e1) {
    short8 r0 = *(const short8*)(baseA + (size_t)cs1[i] * ldH);
    bf16x8_fma(r0, cw1[i], a);
  }
  int s2 = off2[v], e2 = off2[v + 1];
  if (WU) { s2 = __builtin_amdgcn_readfirstlane(s2); e2 = __builtin_amdgcn_readfirstlane(e2); }
  i = s2;
  for (; i + 4 <= e2; i += 4) {
    int u0 = cs2[i], u1 = cs2[i + 1], u2 = cs2[i + 2], u3 = cs2[i + 3];
    float w0 = cw2[i], w1 = cw2[i + 1], w2 = cw2[i + 2], w3 = cw2[i + 3];
    short8 r0 = *(const short8*)(baseB + (size_t)u0 * ldH);
    short8 r1 = *(const short8*)(baseB + (size_t)u1 * ldH);
    short8 r2 = *(const short8*)(baseB + (size_t)u2 * ldH);
    short8 r3 = *(const short8*)(baseB + (size_t)u3 * ldH);
    bf16x8_fma(r0, w0, b); bf16x8_fma(r1, w1, b);
    bf16x8_fma(r2, w2, b); bf16x8_fma(r3, w3, b);
  }
  for (; i + 2 <= e2; i += 2) {
    int u0 = cs2[i], u1 = cs2[i + 1];
    float w0 = cw2[i], w1 = cw2[i + 1];
    short8 r0 = *(const short8*)(baseB + (size_t)u0 * ldH);
    short8 r1 = *(const short8*)(baseB + (size_t)u1 * ldH);
    bf16x8_fma(r0, w0, b); bf16x8_fma(r1, w1, b);
  }
  if (i < e2) {
    short8 r0 = *(const short8*)(baseB + (size_t)cs2[i] * ldH);
    bf16x8_fma(r0, cw2[i], b);
  }

  short8 sa = *(const short8*)(baseA + (size_t)v * ldH);
  short8 sb = *(const short8*)(baseB + (size_t)v * ldH);
  const float dv1 = dinv1[v], dv2 = dinv2[v];

  float r[8];
#pragma unroll
  for (int k = 0; k < 8; k++) {
    float x = eluf(dv1 * a[k] + dv1 * dv1 * bf2f((unsigned short)sa[k]) + ba[c + k]);
    float y = eluf(dv2 * b[k] + dv2 * dv2 * bf2f((unsigned short)sb[k]) + bb[c + k]);
    r[k] = x * w01[2 * (c + k)] + y * w01[2 * (c + k) + 1];
  }

  const bool out_f32 = (outflag != nullptr) && (*outflag != 0);
  size_t oi = (size_t)v * C + c;
  if (out_f32) {
    floatx4 lo = {r[0], r[1], r[2], r[3]};
    floatx4 hi = {r[4], r[5], r[6], r[7]};
    *(floatx4*)((float*)out + oi) = lo;
    *(floatx4*)((float*)out + oi + 4) = hi;
  } else {
    short8 rb;
#pragma unroll
    for (int k = 0; k < 8; k++)
      rb[k] = (short)__bfloat16_as_ushort(__float2bfloat16(r[k]));
    *(short8*)((bf16*)out + oi) = rb;
  }
}

// ---------------------------------------------------------------- host pipeline
extern "C" void kernel_launch(void* const* d_in, const int* in_sizes, int n_in,
                              void* d_out, int out_size, void* d_ws, size_t ws_size,
                              hipStream_t stream) {
  const void* X = d_in[0];
  const int* ei1 = (const int*)d_in[1];
  const int* ei2 = (const int*)d_in[2];
  const int n = in_sizes[0] / 512;
  const int E1 = in_sizes[1] / 2;
  const int E2 = in_sizes[2] / 2;
  const int* src1 = ei1;           const int* dst1 = ei1 + E1;
  const int* src2 = ei2;           const int* dst2 = ei2 + E2;

  auto rnd = [](size_t b) { return (b + 255) & ~(size_t)255; };
  char* p = (char*)d_ws;
  auto alloc = [&](size_t bytes) { char* r = p; p += rnd(bytes); return r; };

  int* flag = (int*)alloc(256);
  int* deg1 = (int*)alloc((size_t)n * 4);
  int* deg2 = (int*)alloc((size_t)n * 4);
  int* cur1 = (int*)alloc((size_t)n * 4);
  int* cur2 = (int*)alloc((size_t)n * 4);
  int* off1 = (int*)alloc((size_t)(n + 1) * 4);
  int* off2 = (int*)alloc((size_t)(n + 1) * 4);
  float* dinv1 = (float*)alloc((size_t)n * 4);
  float* dinv2 = (float*)alloc((size_t)n * 4);
  int* cs1 = (int*)alloc((size_t)E1 * 4);
  float* cw1 = (float*)alloc((size_t)E1 * 4);
  int* cs2 = (int*)alloc((size_t)E2 * 4);
  float* cw2 = (float*)alloc((size_t)E2 * 4);
  bf16* Wt11 = (bf16*)alloc((size_t)512 * 1024 * 2);
  bf16* Wt12 = (bf16*)alloc((size_t)512 * 1024 * 2);
  bf16* Wt2cat = (bf16*)alloc((size_t)1024 * 1024 * 2);
  bf16* Wt3cat = (bf16*)alloc((size_t)256 * 512 * 2);
  float* bf_[6]; int bsz[6] = {1024, 1024, 512, 512, 128, 128};
  for (int i = 0; i < 6; i++) bf_[i] = (float*)alloc((size_t)bsz[i] * 4);
  float* w01_[3]; int asz[3] = {2048, 1024, 256};
  for (int i = 0; i < 3; i++) w01_[i] = (float*)alloc((size_t)asz[i] * 4);
  bf16* Xb = (bf16*)alloc((size_t)n * 512 * 2);
  bf16* aggXa = (bf16*)alloc((size_t)n * 512 * 2);
  bf16* aggXb = (bf16*)alloc((size_t)n * 512 * 2);
  bf16* H1a = (bf16*)alloc((size_t)n * 1024 * 2);
  bf16* H1b = (bf16*)alloc((size_t)n * 1024 * 2);
  bf16* act1 = (bf16*)alloc((size_t)n * 1024 * 2);
  bf16* H2cat = H1a;   // dead after combine1
  bf16* act2 = aggXa;  // dead after gemm_dual
  bf16* H3cat = H1b;   // dead after combine1

  probe_dtype<<<1, 256, 0, stream>>>((const unsigned short*)X, flag);
  hipMemsetAsync(deg1, 0, rnd((size_t)n * 4) * 4, stream);  // deg1,deg2,cur1,cur2

  to_bf16_kernel<<<(n * 512 + 255) / 256, 256, 0, stream>>>(X, Xb, n * 512, flag);
  small_prep<<<20, 256, 0, stream>>>(d_in[4], d_in[6], d_in[8], d_in[10], d_in[12], d_in[14],
                                     d_in[15], d_in[16], d_in[17],
                                     bf_[0], bf_[1], bf_[2], bf_[3], bf_[4], bf_[5],
                                     w01_[0], w01_[1], w01_[2], flag);

  int Etot = E1 + E2;
  deg_fused<<<(Etot + 255) / 256, 256, 0, stream>>>(dst1, E1, dst2, E2, deg1, deg2);
  scan2_kernel<<<2, 1024, 0, stream>>>(deg1, off1, dinv1, deg2, off2, dinv2, n);
  csr_fused<<<(Etot + 255) / 256, 256, 0, stream>>>(src1, dst1, E1, src2, dst2, E2,
                                                    off1, cur1, dinv1, cs1, cw1,
                                                    off2, cur2, dinv2, cs2, cw2);

  transpose_all<<<2176, dim3(32, 8), 0, stream>>>(d_in[3], d_in[5], d_in[7], d_in[9],
                                                  d_in[11], d_in[13],
                                                  Wt11, Wt12, Wt2cat, Wt3cat, flag);

  const int mtiles = (n + 127) / 128;
  auto swgrid = [](int mtTotal, int ntiles) {
    return 8 * ntiles * ((mtTotal + 7) / 8);
  };
  // ---- layer 1: input-side aggregation, swizzled dual GEMM, fast combine
  aggx_kernel<<<(n + 3) / 4, 256, 0, stream>>>(Xb, off1, cs1, cw1, off2, cs2, cw2,
                                               dinv1, dinv2, aggXa, aggXb, n);
  gemm128_sw<<<swgrid(2 * mtiles, 8), 256, 0, stream>>>(
      aggXa, Wt11, H1a, aggXb, Wt12, H1b, n, 512, 1024, mtiles, 2 * mtiles, 3);
  combine1_kernel<<<(n * 1024 / 8 + 255) / 256, 256, 0, stream>>>(
      H1a, H1b, bf_[0], bf_[1], w01_[0], act1, n * 1024);
  // ---- layer 2: swizzled concat GEMM + output-side agg
  gemm128_sw<<<swgrid(mtiles, 8), 256, 0, stream>>>(
      act1, Wt2cat, H2cat, act1, Wt2cat, H2cat, n, 1024, 1024, mtiles, mtiles, 3);
  agg_out_kernel<512, true><<<(n + 3) / 4, 256, 0, stream>>>(
      H2cat, H2cat + 512, 1024, off1, cs1, cw1, off2, cs2, cw2,
      dinv1, dinv2, bf_[2], bf_[3], w01_[1], act2, n, (const int*)nullptr);
  // ---- layer 3: swizzled concat GEMM + output-side agg -> d_out
  gemm128_sw<<<swgrid(mtiles, 2), 256, 0, stream>>>(
      act2, Wt3cat, H3cat, act2, Wt3cat, H3cat, n, 512, 256, mtiles, mtiles, 1);
  agg_out_kernel<128, false><<<(n + 15) / 16, 256, 0, stream>>>(
      H3cat, H3cat + 128, 256, off1, cs1, cw1, off2, cs2, cw2,
      dinv1, dinv2, bf_[4], bf_[5], w01_[2], d_out, n, flag);
}

// Round 9
// 328.904 us; speedup vs baseline: 1.8666x; 1.0499x over previous
//
#include <hip/hip_runtime.h>
#include <hip/hip_bf16.h>
#include <math.h>

using bf16 = __hip_bfloat16;
typedef __attribute__((ext_vector_type(8))) short short8;
typedef __attribute__((ext_vector_type(4))) float floatx4;

// ---------------------------------------------------------------- helpers
__device__ inline void gl_lds16(const void* g, void* l) {
  __builtin_amdgcn_global_load_lds(
      (const __attribute__((address_space(1))) unsigned int*)g,
      (__attribute__((address_space(3))) unsigned int*)l,
      16, 0, 0);
}
// fast ELU: branch-free select + v_exp_f32 (error ~1e-7, invisible at bf16)
__device__ inline float eluf(float x) { return x > 0.f ? x : __expf(x) - 1.f; }
__device__ inline float bf2f(unsigned short h) {
  return __uint_as_float(((unsigned)h) << 16);
}
__device__ inline void bf16x8_fma(short8 r, float w, float* acc) {
#pragma unroll
  for (int k = 0; k < 8; k++) acc[k] += w * bf2f((unsigned short)r[k]);
}

// ---------------------------------------------------------------- probe + zero counters
// block 0: dtype probe (f32 data viewed as bf16 -> even halves decode huge).
// blocks 1..: zero the deg/cur counter region (replaces hipMemsetAsync dispatch).
__global__ void probe_zero(const unsigned short* __restrict__ x, int* __restrict__ flag,
                           int* __restrict__ zbase, int zwords) {
  if (blockIdx.x == 0) {
    __shared__ int s;
    int t = threadIdx.x;
    if (t == 0) s = 0;
    __syncthreads();
    int bad = 0;
    for (int i = t; i < 1024; i += 256) {
      unsigned short h = x[2 * i];
      unsigned e = (h >> 7) & 0xFF;
      if (e >= 0xE5) bad = 1;
    }
    if (bad) atomicOr(&s, 1);
    __syncthreads();
    if (t == 0) flag[0] = s;
  } else {
    int i = (blockIdx.x - 1) * 1024 + threadIdx.x * 4;
    if (i < zwords) {
      zbase[i] = 0; zbase[i + 1] = 0; zbase[i + 2] = 0; zbase[i + 3] = 0;
    }
  }
}

// ---------------------------------------------------------------- fused prep
// one dispatch: [0,2176) weight transposes; [2176, 2176+xb) X->bf16 (8 elem/thr);
// next 20 blocks small_prep (bias->f32, aw->softmax); remaining: degree counting.
__global__ void prep_all(
    const void* X, bf16* __restrict__ Xb, int nx,           // nx = n*512 (mult of 2048)
    const void* W11, const void* W12, const void* W21, const void* W22,
    const void* W31, const void* W32,
    bf16* Wt11, bf16* Wt12, bf16* Wt2cat, bf16* Wt3cat,
    const void* b11, const void* b12, const void* b21, const void* b22,
    const void* b31, const void* b32, const void* aw1, const void* aw2, const void* aw3,
    float* ob11, float* ob12, float* ob21, float* ob22, float* ob31, float* ob32,
    float* ow1, float* ow2, float* ow3,
    const int* __restrict__ dst1, int E1, const int* __restrict__ dst2, int E2,
    int* __restrict__ deg1, int* __restrict__ deg2,
    const int* __restrict__ flag) {
  const bool f32 = *flag != 0;
  int b = blockIdx.x;
  const int xbBlocks = nx / 2048;
  if (b < 2176) {
    // ---- transposes: W[K][N] -> Wt[N][K]
    __shared__ bf16 tile[32][33];
    const void* in; bf16* out; int K, N, tt;
    if (b < 512)       { in = W11; out = Wt11; K = 512;  N = 1024; tt = b; }
    else if (b < 1024) { in = W12; out = Wt12; K = 512;  N = 1024; tt = b - 512; }
    else if (b < 1536) { in = W21; out = Wt2cat; K = 1024; N = 512; tt = b - 1024; }
    else if (b < 2048) { in = W22; out = Wt2cat + (size_t)512 * 1024; K = 1024; N = 512; tt = b - 1536; }
    else if (b < 2112) { in = W31; out = Wt3cat; K = 512; N = 128; tt = b - 2048; }
    else               { in = W32; out = Wt3cat + (size_t)128 * 512; K = 512; N = 128; tt = b - 2112; }
    int tilesx = N / 32;
    int bx = (tt % tilesx) * 32;
    int by = (tt / tilesx) * 32;
    int tx = threadIdx.x & 31, ty = threadIdx.x >> 5;
#pragma unroll
    for (int i = 0; i < 32; i += 8) {
      size_t idx = (size_t)(by + ty + i) * N + (bx + tx);
      tile[ty + i][tx] = f32 ? __float2bfloat16(((const float*)X == nullptr ? 0.f : ((const float*)in)[idx]))
                             : ((const bf16*)in)[idx];
    }
    __syncthreads();
#pragma unroll
    for (int i = 0; i < 32; i += 8)
      out[(size_t)(bx + ty + i) * K + (by + tx)] = tile[tx][ty + i];
    return;
  }
  b -= 2176;
  if (b < xbBlocks) {
    // ---- X -> bf16, 8 elems per thread
    int e = (b * 256 + threadIdx.x) * 8;
    if (f32) {
      const float* src = (const float*)X + e;
      short8 r;
#pragma unroll
      for (int k = 0; k < 8; k++)
        r[k] = (short)__bfloat16_as_ushort(__float2bfloat16(src[k]));
      *(short8*)(Xb + e) = r;
    } else {
      *(short8*)(Xb + e) = *(const short8*)((const bf16*)X + e);
    }
    return;
  }
  b -= xbBlocks;
  if (b < 20) {
    // ---- small prep
    auto cv = [&](const void* p, int i) -> float {
      return f32 ? ((const float*)p)[i] : __bfloat162float(((const bf16*)p)[i]);
    };
    int t = b * 256 + threadIdx.x;
    if (t < 1024) ob11[t] = cv(b11, t);
    else if (t < 2048) ob12[t - 1024] = cv(b12, t - 1024);
    else if (t < 2560) ob21[t - 2048] = cv(b21, t - 2048);
    else if (t < 3072) ob22[t - 2560] = cv(b22, t - 2560);
    else if (t < 3200) ob31[t - 3072] = cv(b31, t - 3072);
    else if (t < 3328) ob32[t - 3200] = cv(b32, t - 3200);
    else if (t < 4992) {
      int j = t - 3328;
      const void* src; float* dst; int jj;
      if (j < 1024)      { src = aw1; dst = ow1; jj = j; }
      else if (j < 1536) { src = aw2; dst = ow2; jj = j - 1024; }
      else               { src = aw3; dst = ow3; jj = j - 1536; }
      float e0 = cv(src, 2 * jj), e1 = cv(src, 2 * jj + 1);
      float mx = fmaxf(e0, e1);
      float w0 = expf(e0 - mx), w1 = expf(e1 - mx);
      float inv = 1.f / (w0 + w1);
      dst[2 * jj] = w0 * inv;
      dst[2 * jj + 1] = w1 * inv;
    }
    return;
  }
  b -= 20;
  {
    // ---- degrees
    int e = b * 256 + threadIdx.x;
    if (e < E1) atomicAdd(&deg1[dst1[e]], 1);
    else if (e < E1 + E2) atomicAdd(&deg2[dst2[e - E1]], 1);
  }
}

// ---------------------------------------------------------------- scan (serial 2-graph)
__global__ void scan2_kernel(const int* __restrict__ deg1, int* __restrict__ off1,
                             float* __restrict__ dinv1,
                             const int* __restrict__ deg2, int* __restrict__ off2,
                             float* __restrict__ dinv2, int n) {
  const int* deg = blockIdx.x ? deg2 : deg1;
  int* off = blockIdx.x ? off2 : off1;
  float* dinv = blockIdx.x ? dinv2 : dinv1;
  __shared__ int s[1024];
  __shared__ int carry_s;
  int t = threadIdx.x;
  if (t == 0) carry_s = 0;
  __syncthreads();
  for (int base = 0; base < n; base += 1024) {
    int i = base + t;
    int orig = (i < n) ? deg[i] : 0;
    s[t] = orig;
    __syncthreads();
    for (int d = 1; d < 1024; d <<= 1) {
      int add = (t >= d) ? s[t - d] : 0;
      __syncthreads();
      s[t] += add;
      __syncthreads();
    }
    int incl = s[t];
    int carry = carry_s;
    if (i < n) {
      off[i]  = carry + incl - orig;
      dinv[i] = rsqrtf((float)(orig + 1));
    }
    __syncthreads();
    if (t == 1023) carry_s = carry + incl;
    __syncthreads();
  }
  if (t == 0) off[n] = carry_s;
}

__global__ void csr_fused(const int* __restrict__ src1, const int* __restrict__ dst1, int E1,
                          const int* __restrict__ src2, const int* __restrict__ dst2, int E2,
                          const int* __restrict__ off1, int* __restrict__ cur1,
                          const float* __restrict__ dinv1,
                          int* __restrict__ cs1, float* __restrict__ cw1,
                          const int* __restrict__ off2, int* __restrict__ cur2,
                          const float* __restrict__ dinv2,
                          int* __restrict__ cs2, float* __restrict__ cw2) {
  int e = blockIdx.x * 256 + threadIdx.x;
  if (e < E1) {
    int d = dst1[e], s = src1[e];
    int slot = off1[d] + atomicAdd(&cur1[d], 1);
    cs1[slot] = s;
    cw1[slot] = dinv1[s];
  } else if (e < E1 + E2) {
    int ee = e - E1;
    int d = dst2[ee], s = src2[ee];
    int slot = off2[d] + atomicAdd(&cur2[d], 1);
    cs2[slot] = s;
    cw2[slot] = dinv2[s];
  }
}

// ---------------------------------------------------------------- input-side agg (layer 1)
__global__ __launch_bounds__(256) void aggx_kernel(
    const bf16* __restrict__ X,
    const int* __restrict__ off1, const int* __restrict__ cs1, const float* __restrict__ cw1,
    const int* __restrict__ off2, const int* __restrict__ cs2, const float* __restrict__ cw2,
    const float* __restrict__ dinv1, const float* __restrict__ dinv2,
    bf16* __restrict__ outA, bf16* __restrict__ outB, int n) {
  int v = blockIdx.x * 4 + (threadIdx.x >> 6);
  if (v >= n) return;
  v = __builtin_amdgcn_readfirstlane(v);
  const int c = (threadIdx.x & 63) * 8;
  const bf16* __restrict__ base = X + c;

  float a[8], b[8];
#pragma unroll
  for (int k = 0; k < 8; k++) { a[k] = 0.f; b[k] = 0.f; }

  int s1 = __builtin_amdgcn_readfirstlane(off1[v]);
  int e1 = __builtin_amdgcn_readfirstlane(off1[v + 1]);
  int i = s1;
  for (; i + 4 <= e1; i += 4) {
    int u0 = cs1[i], u1 = cs1[i + 1], u2 = cs1[i + 2], u3 = cs1[i + 3];
    float w0 = cw1[i], w1 = cw1[i + 1], w2 = cw1[i + 2], w3 = cw1[i + 3];
    short8 r0 = *(const short8*)(base + (size_t)u0 * 512);
    short8 r1 = *(const short8*)(base + (size_t)u1 * 512);
    short8 r2 = *(const short8*)(base + (size_t)u2 * 512);
    short8 r3 = *(const short8*)(base + (size_t)u3 * 512);
    bf16x8_fma(r0, w0, a); bf16x8_fma(r1, w1, a);
    bf16x8_fma(r2, w2, a); bf16x8_fma(r3, w3, a);
  }
  for (; i + 2 <= e1; i += 2) {
    int u0 = cs1[i], u1 = cs1[i + 1];
    float w0 = cw1[i], w1 = cw1[i + 1];
    short8 r0 = *(const short8*)(base + (size_t)u0 * 512);
    short8 r1 = *(const short8*)(base + (size_t)u1 * 512);
    bf16x8_fma(r0, w0, a); bf16x8_fma(r1, w1, a);
  }
  if (i < e1) {
    short8 r0 = *(const short8*)(base + (size_t)cs1[i] * 512);
    bf16x8_fma(r0, cw1[i], a);
  }
  int s2 = __builtin_amdgcn_readfirstlane(off2[v]);
  int e2 = __builtin_amdgcn_readfirstlane(off2[v + 1]);
  i = s2;
  for (; i + 4 <= e2; i += 4) {
    int u0 = cs2[i], u1 = cs2[i + 1], u2 = cs2[i + 2], u3 = cs2[i + 3];
    float w0 = cw2[i], w1 = cw2[i + 1], w2 = cw2[i + 2], w3 = cw2[i + 3];
    short8 r0 = *(const short8*)(base + (size_t)u0 * 512);
    short8 r1 = *(const short8*)(base + (size_t)u1 * 512);
    short8 r2 = *(const short8*)(base + (size_t)u2 * 512);
    short8 r3 = *(const short8*)(base + (size_t)u3 * 512);
    bf16x8_fma(r0, w0, b); bf16x8_fma(r1, w1, b);
    bf16x8_fma(r2, w2, b); bf16x8_fma(r3, w3, b);
  }
  for (; i + 2 <= e2; i += 2) {
    int u0 = cs2[i], u1 = cs2[i + 1];
    float w0 = cw2[i], w1 = cw2[i + 1];
    short8 r0 = *(const short8*)(base + (size_t)u0 * 512);
    short8 r1 = *(const short8*)(base + (size_t)u1 * 512);
    bf16x8_fma(r0, w0, b); bf16x8_fma(r1, w1, b);
  }
  if (i < e2) {
    short8 r0 = *(const short8*)(base + (size_t)cs2[i] * 512);
    bf16x8_fma(r0, cw2[i], b);
  }

  short8 self = *(const short8*)(base + (size_t)v * 512);
  const float dv1 = dinv1[v], dv2 = dinv2[v];
  short8 ra, rb;
#pragma unroll
  for (int k = 0; k < 8; k++) {
    float xs = bf2f((unsigned short)self[k]);
    ra[k] = (short)__bfloat16_as_ushort(__float2bfloat16(dv1 * a[k] + dv1 * dv1 * xs));
    rb[k] = (short)__bfloat16_as_ushort(__float2bfloat16(dv2 * b[k] + dv2 * dv2 * xs));
  }
  *(short8*)(outA + (size_t)v * 512 + c) = ra;
  *(short8*)(outB + (size_t)v * 512 + c) = rb;
}

// ---------------------------------------------------------------- GEMM (m97-style, XOR-swizzled LDS)
// LDS row r holds its four 16B chunks rotated by s(r) = (r>>1)&3: position q = chunk q^s.
// Staging: lane loads global chunk (lane&3)^((lane>>3)&3) -> DMA layout unchanged.
// Read: chunk quad of row R sits at position quad^((l16>>1)&3).
// Result: 16-lane b128 reads spread over 8 (bank,phase) slots -> 2-way (free, m136).
__device__ inline void gemm_body(const bf16* __restrict__ A, const bf16* __restrict__ Bt,
                                 bf16* __restrict__ C, int M, int K, int N,
                                 int m0, int n0) {
  __shared__ bf16 As[128 * 32];
  __shared__ bf16 Bs[128 * 32];
  const int tid = threadIdx.x;
  const int wave = tid >> 6;
  const int lane = tid & 63;
  const int quad = lane >> 4;
  const int l16 = lane & 15;
  const int wr = (wave >> 1) * 64;
  const int wc = (wave & 1) * 64;
  const int r_sub = lane >> 2;
  const int cb = (((lane & 3) ^ ((lane >> 3) & 3)) * 16);  // swizzled source chunk
  const int rsw = (l16 >> 1) & 3;                          // read-side swizzle

  floatx4 acc[4][4];
#pragma unroll
  for (int i = 0; i < 4; i++)
#pragma unroll
    for (int j = 0; j < 4; j++) acc[i][j] = (floatx4){0.f, 0.f, 0.f, 0.f};

  for (int k0 = 0; k0 < K; k0 += 32) {
    __syncthreads();
#pragma unroll
    for (int j = 0; j < 2; ++j) {
      int p = wave * 2 + j;
      int ra = p * 16 + r_sub;
      int grow = m0 + ra; if (grow >= M) grow = M - 1;
      gl_lds16((const char*)(A + (size_t)grow * K + k0) + cb, (char*)As + p * 1024);
      int rb = n0 + p * 16 + r_sub;
      gl_lds16((const char*)(Bt + (size_t)rb * K + k0) + cb, (char*)Bs + p * 1024);
    }
    __syncthreads();

    short8 af[4], bfr[4];
#pragma unroll
    for (int i = 0; i < 4; i++)
      af[i] = *(const short8*)(As + (wr + i * 16 + l16) * 32 + (quad ^ rsw) * 8);
#pragma unroll
    for (int j = 0; j < 4; j++)
      bfr[j] = *(const short8*)(Bs + (wc + j * 16 + l16) * 32 + (quad ^ rsw) * 8);
#pragma unroll
    for (int i = 0; i < 4; i++)
#pragma unroll
      for (int j = 0; j < 4; j++)
        acc[i][j] = __builtin_amdgcn_mfma_f32_16x16x32_bf16(af[i], bfr[j], acc[i][j], 0, 0, 0);
  }

#pragma unroll
  for (int i = 0; i < 4; i++) {
#pragma unroll
    for (int r = 0; r < 4; r++) {
      int row = m0 + wr + i * 16 + quad * 4 + r;
      if (row < M) {
#pragma unroll
        for (int j = 0; j < 4; j++) {
          int col = n0 + wc + j * 16 + l16;
          C[(size_t)row * N + col] = __float2bfloat16(acc[i][j][r]);
        }
      }
    }
  }
}

// XCD-swizzled (dual-capable) GEMM
__global__ __launch_bounds__(256) void gemm128_sw(
    const bf16* __restrict__ A0, const bf16* __restrict__ Bt0, bf16* __restrict__ C0,
    const bf16* __restrict__ A1, const bf16* __restrict__ Bt1, bf16* __restrict__ C1,
    int M, int K, int N, int mtilesPerHalf, int mtTotal, int ntLog2) {
  int lin = blockIdx.x;
  int g = lin & 7;
  int s = lin >> 3;
  int n_t = s & ((1 << ntLog2) - 1);
  int m_t = g + 8 * (s >> ntLog2);
  if (m_t >= mtTotal) return;
  int half = (m_t >= mtilesPerHalf) ? 1 : 0;
  int m_local = m_t - half * mtilesPerHalf;
  const bf16* A = half ? A1 : A0;
  const bf16* Bt = half ? Bt1 : Bt0;
  bf16* C = half ? C1 : C0;
  gemm_body(A, Bt, C, M, K, N, m_local * 128, n_t * 128);
}

// ---------------------------------------------------------------- layer-1 epilogue
__global__ __launch_bounds__(256) void combine1_kernel(
    const bf16* __restrict__ Ha, const bf16* __restrict__ Hb,
    const float* __restrict__ ba, const float* __restrict__ bb,
    const float* __restrict__ w01, bf16* __restrict__ out, int total) {
  int e = (blockIdx.x * 256 + threadIdx.x) * 8;
  if (e >= total) return;
  int c = e & 1023;
  short8 ha = *(const short8*)(Ha + e);
  short8 hb = *(const short8*)(Hb + e);
  short8 r;
#pragma unroll
  for (int k = 0; k < 8; k++) {
    float x = eluf(bf2f((unsigned short)ha[k]) + ba[c + k]);
    float y = eluf(bf2f((unsigned short)hb[k]) + bb[c + k]);
    r[k] = (short)__bfloat16_as_ushort(
        __float2bfloat16(x * w01[2 * (c + k)] + y * w01[2 * (c + k) + 1]));
  }
  *(short8*)(out + e) = r;
}

// ---------------------------------------------------------------- output-side agg (layers 2,3)
template <int C, bool WU>
__global__ __launch_bounds__(256) void agg_out_kernel(
    const bf16* __restrict__ Ha, const bf16* __restrict__ Hb, int ldH,
    const int* __restrict__ off1, const int* __restrict__ cs1, const float* __restrict__ cw1,
    const int* __restrict__ off2, const int* __restrict__ cs2, const float* __restrict__ cw2,
    const float* __restrict__ dinv1, const float* __restrict__ dinv2,
    const float* __restrict__ ba, const float* __restrict__ bb,
    const float* __restrict__ w01, void* __restrict__ out, int n,
    const int* __restrict__ outflag) {
  constexpr int TPV = C / 8;
  constexpr int G = 256 / TPV;
  const int t = threadIdx.x;
  int v = blockIdx.x * G + t / TPV;
  if (v >= n) return;
  if (WU) v = __builtin_amdgcn_readfirstlane(v);
  const int c = (t % TPV) * 8;
  const bf16* __restrict__ baseA = Ha + c;
  const bf16* __restrict__ baseB = Hb + c;

  float a[8], b[8];
#pragma unroll
  for (int k = 0; k < 8; k++) { a[k] = 0.f; b[k] = 0.f; }

  int s1 = off1[v], e1 = off1[v + 1];
  if (WU) { s1 = __builtin_amdgcn_readfirstlane(s1); e1 = __builtin_amdgcn_readfirstlane(e1); }
  int i = s1;
  for (; i + 4 <= e1; i += 4) {
    int u0 = cs1[i], u1 = cs1[i + 1], u2 = cs1[i + 2], u3 = cs1[i + 3];
    float w0 = cw1[i], w1 = cw1[i + 1], w2 = cw1[i + 2], w3 = cw1[i + 3];
    short8 r0 = *(const short8*)(baseA + (size_t)u0 * ldH);
    short8 r1 = *(const short8*)(baseA + (size_t)u1 * ldH);
    short8 r2 = *(const short8*)(baseA + (size_t)u2 * ldH);
    short8 r3 = *(const short8*)(baseA + (size_t)u3 * ldH);
    bf16x8_fma(r0, w0, a); bf16x8_fma(r1, w1, a);
    bf16x8_fma(r2, w2, a); bf16x8_fma(r3, w3, a);
  }
  for (; i + 2 <= e1; i += 2) {
    int u0 = cs1[i], u1 = cs1[i + 1];
    float w0 = cw1[i], w1 = cw1[i + 1];
    short8 r0 = *(const short8*)(baseA + (size_t)u0 * ldH);
    short8 r1 = *(const short8*)(baseA + (size_t)u1 * ldH);
    bf16x8_fma(r0, w0, a); bf16x8_fma(r1, w1, a);
  }
  if (i < e1) {
    short8 r0 = *(const short8*)(baseA + (size_t)cs1[i] * ldH);
    bf16x8_fma(r0, cw1[i], a);
  }
  int s2 = off2[v], e2 = off2[v + 1];
  if (WU) { s2 = __builtin_amdgcn_readfirstlane(s2); e2 = __builtin_amdgcn_readfirstlane(e2); }
  i = s2;
  for (; i + 4 <= e2; i += 4) {
    int u0 = cs2[i], u1 = cs2[i + 1], u2 = cs2[i + 2], u3 = cs2[i + 3];
    float w0 = cw2[i], w1 = cw2[i + 1], w2 = cw2[i + 2], w3 = cw2[i + 3];
    short8 r0 = *(const short8*)(baseB + (size_t)u0 * ldH);
    short8 r1 = *(const short8*)(baseB + (size_t)u1 * ldH);
    short8 r2 = *(const short8*)(baseB + (size_t)u2 * ldH);
    short8 r3 = *(const short8*)(baseB + (size_t)u3 * ldH);
    bf16x8_fma(r0, w0, b); bf16x8_fma(r1, w1, b);
    bf16x8_fma(r2, w2, b); bf16x8_fma(r3, w3, b);
  }
  for (; i + 2 <= e2; i += 2) {
    int u0 = cs2[i], u1 = cs2[i + 1];
    float w0 = cw2[i], w1 = cw2[i + 1];
    short8 r0 = *(const short8*)(baseB + (size_t)u0 * ldH);
    short8 r1 = *(const short8*)(baseB + (size_t)u1 * ldH);
    bf16x8_fma(r0, w0, b); bf16x8_fma(r1, w1, b);
  }
  if (i < e2) {
    short8 r0 = *(const short8*)(baseB + (size_t)cs2[i] * ldH);
    bf16x8_fma(r0, cw2[i], b);
  }

  short8 sa = *(const short8*)(baseA + (size_t)v * ldH);
  short8 sb = *(const short8*)(baseB + (size_t)v * ldH);
  const float dv1 = dinv1[v], dv2 = dinv2[v];

  float r[8];
#pragma unroll
  for (int k = 0; k < 8; k++) {
    float x = eluf(dv1 * a[k] + dv1 * dv1 * bf2f((unsigned short)sa[k]) + ba[c + k]);
    float y = eluf(dv2 * b[k] + dv2 * dv2 * bf2f((unsigned short)sb[k]) + bb[c + k]);
    r[k] = x * w01[2 * (c + k)] + y * w01[2 * (c + k) + 1];
  }

  const bool out_f32 = (outflag != nullptr) && (*outflag != 0);
  size_t oi = (size_t)v * C + c;
  if (out_f32) {
    floatx4 lo = {r[0], r[1], r[2], r[3]};
    floatx4 hi = {r[4], r[5], r[6], r[7]};
    *(floatx4*)((float*)out + oi) = lo;
    *(floatx4*)((float*)out + oi + 4) = hi;
  } else {
    short8 rb;
#pragma unroll
    for (int k = 0; k < 8; k++)
      rb[k] = (short)__bfloat16_as_ushort(__float2bfloat16(r[k]));
    *(short8*)((bf16*)out + oi) = rb;
  }
}

// ---------------------------------------------------------------- host pipeline
extern "C" void kernel_launch(void* const* d_in, const int* in_sizes, int n_in,
                              void* d_out, int out_size, void* d_ws, size_t ws_size,
                              hipStream_t stream) {
  const void* X = d_in[0];
  const int* ei1 = (const int*)d_in[1];
  const int* ei2 = (const int*)d_in[2];
  const int n = in_sizes[0] / 512;
  const int E1 = in_sizes[1] / 2;
  const int E2 = in_sizes[2] / 2;
  const int* src1 = ei1;           const int* dst1 = ei1 + E1;
  const int* src2 = ei2;           const int* dst2 = ei2 + E2;

  auto rnd = [](size_t b) { return (b + 255) & ~(size_t)255; };
  char* p = (char*)d_ws;
  auto alloc = [&](size_t bytes) { char* r = p; p += rnd(bytes); return r; };

  int* flag = (int*)alloc(256);
  int* deg1 = (int*)alloc((size_t)n * 4);
  int* deg2 = (int*)alloc((size_t)n * 4);
  int* cur1 = (int*)alloc((size_t)n * 4);
  int* cur2 = (int*)alloc((size_t)n * 4);
  int* off1 = (int*)alloc((size_t)(n + 1) * 4);
  int* off2 = (int*)alloc((size_t)(n + 1) * 4);
  float* dinv1 = (float*)alloc((size_t)n * 4);
  float* dinv2 = (float*)alloc((size_t)n * 4);
  int* cs1 = (int*)alloc((size_t)E1 * 4);
  float* cw1 = (float*)alloc((size_t)E1 * 4);
  int* cs2 = (int*)alloc((size_t)E2 * 4);
  float* cw2 = (float*)alloc((size_t)E2 * 4);
  bf16* Wt11 = (bf16*)alloc((size_t)512 * 1024 * 2);
  bf16* Wt12 = (bf16*)alloc((size_t)512 * 1024 * 2);
  bf16* Wt2cat = (bf16*)alloc((size_t)1024 * 1024 * 2);
  bf16* Wt3cat = (bf16*)alloc((size_t)256 * 512 * 2);
  float* bf_[6]; int bsz[6] = {1024, 1024, 512, 512, 128, 128};
  for (int i = 0; i < 6; i++) bf_[i] = (float*)alloc((size_t)bsz[i] * 4);
  float* w01_[3]; int asz[3] = {2048, 1024, 256};
  for (int i = 0; i < 3; i++) w01_[i] = (float*)alloc((size_t)asz[i] * 4);
  bf16* Xb = (bf16*)alloc((size_t)n * 512 * 2);
  bf16* aggXa = (bf16*)alloc((size_t)n * 512 * 2);
  bf16* aggXb = (bf16*)alloc((size_t)n * 512 * 2);
  bf16* H1a = (bf16*)alloc((size_t)n * 1024 * 2);
  bf16* H1b = (bf16*)alloc((size_t)n * 1024 * 2);
  bf16* act1 = (bf16*)alloc((size_t)n * 1024 * 2);
  bf16* H2cat = H1a;   // dead after combine1
  bf16* act2 = aggXa;  // dead after gemm L1
  bf16* H3cat = H1b;   // dead after combine1

  // ---- prep: probe + zero counters (deg1..cur2 contiguous 256B-rounded blocks)
  int zwords = (int)(rnd((size_t)n * 4) * 4 / 4);
  probe_zero<<<1 + (zwords + 1023) / 1024, 256, 0, stream>>>(
      (const unsigned short*)X, flag, deg1, zwords);

  // ---- fused prep: transposes + X conversion + small consts + degrees
  int xbBlocks = (n * 512) / 2048;
  int degBlocks = (E1 + E2 + 255) / 256;
  prep_all<<<2176 + xbBlocks + 20 + degBlocks, 256, 0, stream>>>(
      X, Xb, n * 512,
      d_in[3], d_in[5], d_in[7], d_in[9], d_in[11], d_in[13],
      Wt11, Wt12, Wt2cat, Wt3cat,
      d_in[4], d_in[6], d_in[8], d_in[10], d_in[12], d_in[14],
      d_in[15], d_in[16], d_in[17],
      bf_[0], bf_[1], bf_[2], bf_[3], bf_[4], bf_[5],
      w01_[0], w01_[1], w01_[2],
      dst1, E1, dst2, E2, deg1, deg2, flag);

  scan2_kernel<<<2, 1024, 0, stream>>>(deg1, off1, dinv1, deg2, off2, dinv2, n);
  csr_fused<<<(E1 + E2 + 255) / 256, 256, 0, stream>>>(src1, dst1, E1, src2, dst2, E2,
                                                       off1, cur1, dinv1, cs1, cw1,
                                                       off2, cur2, dinv2, cs2, cw2);

  const int mtiles = (n + 127) / 128;
  auto swgrid = [](int mtTotal, int ntiles) {
    return 8 * ntiles * ((mtTotal + 7) / 8);
  };
  // ---- layer 1
  aggx_kernel<<<(n + 3) / 4, 256, 0, stream>>>(Xb, off1, cs1, cw1, off2, cs2, cw2,
                                               dinv1, dinv2, aggXa, aggXb, n);
  gemm128_sw<<<swgrid(2 * mtiles, 8), 256, 0, stream>>>(
      aggXa, Wt11, H1a, aggXb, Wt12, H1b, n, 512, 1024, mtiles, 2 * mtiles, 3);
  combine1_kernel<<<(n * 1024 / 8 + 255) / 256, 256, 0, stream>>>(
      H1a, H1b, bf_[0], bf_[1], w01_[0], act1, n * 1024);
  // ---- layer 2
  gemm128_sw<<<swgrid(mtiles, 8), 256, 0, stream>>>(
      act1, Wt2cat, H2cat, act1, Wt2cat, H2cat, n, 1024, 1024, mtiles, mtiles, 3);
  agg_out_kernel<512, true><<<(n + 3) / 4, 256, 0, stream>>>(
      H2cat, H2cat + 512, 1024, off1, cs1, cw1, off2, cs2, cw2,
      dinv1, dinv2, bf_[2], bf_[3], w01_[1], act2, n, (const int*)nullptr);
  // ---- layer 3
  gemm128_sw<<<swgrid(mtiles, 2), 256, 0, stream>>>(
      act2, Wt3cat, H3cat, act2, Wt3cat, H3cat, n, 512, 256, mtiles, mtiles, 1);
  agg_out_kernel<128, false><<<(n + 15) / 16, 256, 0, stream>>>(
      H3cat, H3cat + 128, 256, off1, cs1, cw1, off2, cs2, cw2,
      dinv1, dinv2, bf_[4], bf_[5], w01_[2], d_out, n, flag);
}

// Round 10
// 316.657 us; speedup vs baseline: 1.9388x; 1.0387x over previous
//
#include <hip/hip_runtime.h>
#include <hip/hip_bf16.h>
#include <math.h>

using bf16 = __hip_bfloat16;
typedef __attribute__((ext_vector_type(8))) short short8;
typedef __attribute__((ext_vector_type(4))) float floatx4;

// ---------------------------------------------------------------- helpers
__device__ inline void gl_lds16(const void* g, void* l) {
  __builtin_amdgcn_global_load_lds(
      (const __attribute__((address_space(1))) unsigned int*)g,
      (__attribute__((address_space(3))) unsigned int*)l,
      16, 0, 0);
}
// fast ELU: branch-free select + v_exp_f32 (error ~1e-7, invisible at bf16)
__device__ inline float eluf(float x) { return x > 0.f ? x : __expf(x) - 1.f; }
__device__ inline float bf2f(unsigned short h) {
  return __uint_as_float(((unsigned)h) << 16);
}
__device__ inline void bf16x8_fma(short8 r, float w, float* acc) {
#pragma unroll
  for (int k = 0; k < 8; k++) acc[k] += w * bf2f((unsigned short)r[k]);
}

// ---------------------------------------------------------------- probe + zero counters
__global__ void probe_zero(const unsigned short* __restrict__ x, int* __restrict__ flag,
                           int* __restrict__ zbase, int zwords) {
  if (blockIdx.x == 0) {
    __shared__ int s;
    int t = threadIdx.x;
    if (t == 0) s = 0;
    __syncthreads();
    int bad = 0;
    for (int i = t; i < 1024; i += 256) {
      unsigned short h = x[2 * i];
      unsigned e = (h >> 7) & 0xFF;
      if (e >= 0xE5) bad = 1;
    }
    if (bad) atomicOr(&s, 1);
    __syncthreads();
    if (t == 0) flag[0] = s;
  } else {
    int i = (blockIdx.x - 1) * 1024 + threadIdx.x * 4;
    if (i < zwords) {
      zbase[i] = 0; zbase[i + 1] = 0; zbase[i + 2] = 0; zbase[i + 3] = 0;
    }
  }
}

// ---------------------------------------------------------------- fused prep
__global__ void prep_all(
    const void* X, bf16* __restrict__ Xb, int nx,
    const void* W11, const void* W12, const void* W21, const void* W22,
    const void* W31, const void* W32,
    bf16* Wt11, bf16* Wt12, bf16* Wt2cat, bf16* Wt3cat,
    const void* b11, const void* b12, const void* b21, const void* b22,
    const void* b31, const void* b32, const void* aw1, const void* aw2, const void* aw3,
    float* ob11, float* ob12, float* ob21, float* ob22, float* ob31, float* ob32,
    float* ow1, float* ow2, float* ow3,
    const int* __restrict__ dst1, int E1, const int* __restrict__ dst2, int E2,
    int* __restrict__ deg1, int* __restrict__ deg2,
    const int* __restrict__ flag) {
  const bool f32 = *flag != 0;
  int b = blockIdx.x;
  const int xbBlocks = nx / 2048;
  if (b < 2176) {
    __shared__ bf16 tile[32][33];
    const void* in; bf16* out; int K, N, tt;
    if (b < 512)       { in = W11; out = Wt11; K = 512;  N = 1024; tt = b; }
    else if (b < 1024) { in = W12; out = Wt12; K = 512;  N = 1024; tt = b - 512; }
    else if (b < 1536) { in = W21; out = Wt2cat; K = 1024; N = 512; tt = b - 1024; }
    else if (b < 2048) { in = W22; out = Wt2cat + (size_t)512 * 1024; K = 1024; N = 512; tt = b - 1536; }
    else if (b < 2112) { in = W31; out = Wt3cat; K = 512; N = 128; tt = b - 2048; }
    else               { in = W32; out = Wt3cat + (size_t)128 * 512; K = 512; N = 128; tt = b - 2112; }
    int tilesx = N / 32;
    int bx = (tt % tilesx) * 32;
    int by = (tt / tilesx) * 32;
    int tx = threadIdx.x & 31, ty = threadIdx.x >> 5;
#pragma unroll
    for (int i = 0; i < 32; i += 8) {
      size_t idx = (size_t)(by + ty + i) * N + (bx + tx);
      tile[ty + i][tx] = f32 ? __float2bfloat16(((const float*)in)[idx])
                             : ((const bf16*)in)[idx];
    }
    __syncthreads();
#pragma unroll
    for (int i = 0; i < 32; i += 8)
      out[(size_t)(bx + ty + i) * K + (by + tx)] = tile[tx][ty + i];
    return;
  }
  b -= 2176;
  if (b < xbBlocks) {
    int e = (b * 256 + threadIdx.x) * 8;
    if (f32) {
      const float* src = (const float*)X + e;
      short8 r;
#pragma unroll
      for (int k = 0; k < 8; k++)
        r[k] = (short)__bfloat16_as_ushort(__float2bfloat16(src[k]));
      *(short8*)(Xb + e) = r;
    } else {
      *(short8*)(Xb + e) = *(const short8*)((const bf16*)X + e);
    }
    return;
  }
  b -= xbBlocks;
  if (b < 20) {
    auto cv = [&](const void* p, int i) -> float {
      return f32 ? ((const float*)p)[i] : __bfloat162float(((const bf16*)p)[i]);
    };
    int t = b * 256 + threadIdx.x;
    if (t < 1024) ob11[t] = cv(b11, t);
    else if (t < 2048) ob12[t - 1024] = cv(b12, t - 1024);
    else if (t < 2560) ob21[t - 2048] = cv(b21, t - 2048);
    else if (t < 3072) ob22[t - 2560] = cv(b22, t - 2560);
    else if (t < 3200) ob31[t - 3072] = cv(b31, t - 3072);
    else if (t < 3328) ob32[t - 3200] = cv(b32, t - 3200);
    else if (t < 4992) {
      int j = t - 3328;
      const void* src; float* dst; int jj;
      if (j < 1024)      { src = aw1; dst = ow1; jj = j; }
      else if (j < 1536) { src = aw2; dst = ow2; jj = j - 1024; }
      else               { src = aw3; dst = ow3; jj = j - 1536; }
      float e0 = cv(src, 2 * jj), e1 = cv(src, 2 * jj + 1);
      float mx = fmaxf(e0, e1);
      float w0 = expf(e0 - mx), w1 = expf(e1 - mx);
      float inv = 1.f / (w0 + w1);
      dst[2 * jj] = w0 * inv;
      dst[2 * jj + 1] = w1 * inv;
    }
    return;
  }
  b -= 20;
  {
    int e = b * 256 + threadIdx.x;
    if (e < E1) atomicAdd(&deg1[dst1[e]], 1);
    else if (e < E1 + E2) atomicAdd(&deg2[dst2[e - E1]], 1);
  }
}

// ---------------------------------------------------------------- scan (wave-shuffle, 4 barriers/chunk)
__global__ void scan2_kernel(const int* __restrict__ deg1, int* __restrict__ off1,
                             float* __restrict__ dinv1,
                             const int* __restrict__ deg2, int* __restrict__ off2,
                             float* __restrict__ dinv2, int n) {
  const int* deg = blockIdx.x ? deg2 : deg1;
  int* off = blockIdx.x ? off2 : off1;
  float* dinv = blockIdx.x ? dinv2 : dinv1;
  __shared__ int wsum[16];
  __shared__ int carry_s;
  const int t = threadIdx.x;
  const int waveid = t >> 6;
  const int lane = t & 63;
  if (t == 0) carry_s = 0;
  __syncthreads();
  for (int base = 0; base < n; base += 1024) {
    int i = base + t;
    int orig = (i < n) ? deg[i] : 0;
    // wave-level inclusive scan (no barriers)
    int v = orig;
#pragma unroll
    for (int d = 1; d < 64; d <<= 1) {
      int u = __shfl_up(v, d, 64);
      if (lane >= d) v += u;
    }
    if (lane == 63) wsum[waveid] = v;
    __syncthreads();
    if (waveid == 0 && lane < 16) {
      int s = wsum[lane];
#pragma unroll
      for (int d = 1; d < 16; d <<= 1) {
        int u = __shfl_up(s, d, 64);
        if (lane >= d) s += u;
      }
      wsum[lane] = s;  // inclusive wave sums
    }
    __syncthreads();
    int woff = waveid ? wsum[waveid - 1] : 0;
    int incl = v + woff;
    int carry = carry_s;
    if (i < n) {
      off[i]  = carry + incl - orig;
      dinv[i] = rsqrtf((float)(orig + 1));
    }
    __syncthreads();
    if (t == 1023) carry_s = carry + wsum[15];
    __syncthreads();
  }
  if (t == 0) off[n] = carry_s;
}

__global__ void csr_fused(const int* __restrict__ src1, const int* __restrict__ dst1, int E1,
                          const int* __restrict__ src2, const int* __restrict__ dst2, int E2,
                          const int* __restrict__ off1, int* __restrict__ cur1,
                          const float* __restrict__ dinv1,
                          int* __restrict__ cs1, float* __restrict__ cw1,
                          const int* __restrict__ off2, int* __restrict__ cur2,
                          const float* __restrict__ dinv2,
                          int* __restrict__ cs2, float* __restrict__ cw2) {
  int e = blockIdx.x * 256 + threadIdx.x;
  if (e < E1) {
    int d = dst1[e], s = src1[e];
    int slot = off1[d] + atomicAdd(&cur1[d], 1);
    cs1[slot] = s;
    cw1[slot] = dinv1[s];
  } else if (e < E1 + E2) {
    int ee = e - E1;
    int d = dst2[ee], s = src2[ee];
    int slot = off2[d] + atomicAdd(&cur2[d], 1);
    cs2[slot] = s;
    cw2[slot] = dinv2[s];
  }
}

// ---------------------------------------------------------------- gather loop (8/4/2/1 unroll)
template <int LD>
__device__ inline void gather_accum(const bf16* __restrict__ base,
                                    const int* __restrict__ cs, const float* __restrict__ cw,
                                    int s, int e, float* acc) {
  int i = s;
  for (; i + 8 <= e; i += 8) {
    short8 r[8]; float w[8];
#pragma unroll
    for (int k = 0; k < 8; k++) {
      r[k] = *(const short8*)(base + (size_t)cs[i + k] * LD);
      w[k] = cw[i + k];
    }
#pragma unroll
    for (int k = 0; k < 8; k++) bf16x8_fma(r[k], w[k], acc);
  }
  for (; i + 4 <= e; i += 4) {
    short8 r[4]; float w[4];
#pragma unroll
    for (int k = 0; k < 4; k++) {
      r[k] = *(const short8*)(base + (size_t)cs[i + k] * LD);
      w[k] = cw[i + k];
    }
#pragma unroll
    for (int k = 0; k < 4; k++) bf16x8_fma(r[k], w[k], acc);
  }
  for (; i + 2 <= e; i += 2) {
    short8 r0 = *(const short8*)(base + (size_t)cs[i] * LD);
    short8 r1 = *(const short8*)(base + (size_t)cs[i + 1] * LD);
    bf16x8_fma(r0, cw[i], acc);
    bf16x8_fma(r1, cw[i + 1], acc);
  }
  if (i < e) {
    short8 r0 = *(const short8*)(base + (size_t)cs[i] * LD);
    bf16x8_fma(r0, cw[i], acc);
  }
}

// ---------------------------------------------------------------- input-side agg (layer 1)
__global__ __launch_bounds__(256) void aggx_kernel(
    const bf16* __restrict__ X,
    const int* __restrict__ off1, const int* __restrict__ cs1, const float* __restrict__ cw1,
    const int* __restrict__ off2, const int* __restrict__ cs2, const float* __restrict__ cw2,
    const float* __restrict__ dinv1, const float* __restrict__ dinv2,
    bf16* __restrict__ outA, bf16* __restrict__ outB, int n) {
  int v = blockIdx.x * 4 + (threadIdx.x >> 6);
  if (v >= n) return;
  v = __builtin_amdgcn_readfirstlane(v);
  const int c = (threadIdx.x & 63) * 8;
  const bf16* __restrict__ base = X + c;

  float a[8], b[8];
#pragma unroll
  for (int k = 0; k < 8; k++) { a[k] = 0.f; b[k] = 0.f; }

  int s1 = __builtin_amdgcn_readfirstlane(off1[v]);
  int e1 = __builtin_amdgcn_readfirstlane(off1[v + 1]);
  gather_accum<512>(base, cs1, cw1, s1, e1, a);
  int s2 = __builtin_amdgcn_readfirstlane(off2[v]);
  int e2 = __builtin_amdgcn_readfirstlane(off2[v + 1]);
  gather_accum<512>(base, cs2, cw2, s2, e2, b);

  short8 self = *(const short8*)(base + (size_t)v * 512);
  const float dv1 = dinv1[v], dv2 = dinv2[v];
  short8 ra, rb;
#pragma unroll
  for (int k = 0; k < 8; k++) {
    float xs = bf2f((unsigned short)self[k]);
    ra[k] = (short)__bfloat16_as_ushort(__float2bfloat16(dv1 * a[k] + dv1 * dv1 * xs));
    rb[k] = (short)__bfloat16_as_ushort(__float2bfloat16(dv2 * b[k] + dv2 * dv2 * xs));
  }
  *(short8*)(outA + (size_t)v * 512 + c) = ra;
  *(short8*)(outB + (size_t)v * 512 + c) = rb;
}

// ---------------------------------------------------------------- GEMM (m97-style, XOR-swizzled LDS)
__device__ inline void gemm_body(const bf16* __restrict__ A, const bf16* __restrict__ Bt,
                                 bf16* __restrict__ C, int M, int K, int N,
                                 int m0, int n0) {
  __shared__ bf16 As[128 * 32];
  __shared__ bf16 Bs[128 * 32];
  const int tid = threadIdx.x;
  const int wave = tid >> 6;
  const int lane = tid & 63;
  const int quad = lane >> 4;
  const int l16 = lane & 15;
  const int wr = (wave >> 1) * 64;
  const int wc = (wave & 1) * 64;
  const int r_sub = lane >> 2;
  const int cb = (((lane & 3) ^ ((lane >> 3) & 3)) * 16);  // swizzled source chunk
  const int rsw = (l16 >> 1) & 3;                          // read-side swizzle

  floatx4 acc[4][4];
#pragma unroll
  for (int i = 0; i < 4; i++)
#pragma unroll
    for (int j = 0; j < 4; j++) acc[i][j] = (floatx4){0.f, 0.f, 0.f, 0.f};

  for (int k0 = 0; k0 < K; k0 += 32) {
    __syncthreads();
#pragma unroll
    for (int j = 0; j < 2; ++j) {
      int p = wave * 2 + j;
      int ra = p * 16 + r_sub;
      int grow = m0 + ra; if (grow >= M) grow = M - 1;
      gl_lds16((const char*)(A + (size_t)grow * K + k0) + cb, (char*)As + p * 1024);
      int rb = n0 + p * 16 + r_sub;
      gl_lds16((const char*)(Bt + (size_t)rb * K + k0) + cb, (char*)Bs + p * 1024);
    }
    __syncthreads();

    short8 af[4], bfr[4];
#pragma unroll
    for (int i = 0; i < 4; i++)
      af[i] = *(const short8*)(As + (wr + i * 16 + l16) * 32 + (quad ^ rsw) * 8);
#pragma unroll
    for (int j = 0; j < 4; j++)
      bfr[j] = *(const short8*)(Bs + (wc + j * 16 + l16) * 32 + (quad ^ rsw) * 8);
#pragma unroll
    for (int i = 0; i < 4; i++)
#pragma unroll
      for (int j = 0; j < 4; j++)
        acc[i][j] = __builtin_amdgcn_mfma_f32_16x16x32_bf16(af[i], bfr[j], acc[i][j], 0, 0, 0);
  }

#pragma unroll
  for (int i = 0; i < 4; i++) {
#pragma unroll
    for (int r = 0; r < 4; r++) {
      int row = m0 + wr + i * 16 + quad * 4 + r;
      if (row < M) {
#pragma unroll
        for (int j = 0; j < 4; j++) {
          int col = n0 + wc + j * 16 + l16;
          C[(size_t)row * N + col] = __float2bfloat16(acc[i][j][r]);
        }
      }
    }
  }
}

// XCD-swizzled (dual-capable) GEMM
__global__ __launch_bounds__(256) void gemm128_sw(
    const bf16* __restrict__ A0, const bf16* __restrict__ Bt0, bf16* __restrict__ C0,
    const bf16* __restrict__ A1, const bf16* __restrict__ Bt1, bf16* __restrict__ C1,
    int M, int K, int N, int mtilesPerHalf, int mtTotal, int ntLog2) {
  int lin = blockIdx.x;
  int g = lin & 7;
  int s = lin >> 3;
  int n_t = s & ((1 << ntLog2) - 1);
  int m_t = g + 8 * (s >> ntLog2);
  if (m_t >= mtTotal) return;
  int half = (m_t >= mtilesPerHalf) ? 1 : 0;
  int m_local = m_t - half * mtilesPerHalf;
  const bf16* A = half ? A1 : A0;
  const bf16* Bt = half ? Bt1 : Bt0;
  bf16* C = half ? C1 : C0;
  gemm_body(A, Bt, C, M, K, N, m_local * 128, n_t * 128);
}

// ---------------------------------------------------------------- layer-1 epilogue
__global__ __launch_bounds__(256) void combine1_kernel(
    const bf16* __restrict__ Ha, const bf16* __restrict__ Hb,
    const float* __restrict__ ba, const float* __restrict__ bb,
    const float* __restrict__ w01, bf16* __restrict__ out, int total) {
  int e = (blockIdx.x * 256 + threadIdx.x) * 8;
  if (e >= total) return;
  int c = e & 1023;
  short8 ha = *(const short8*)(Ha + e);
  short8 hb = *(const short8*)(Hb + e);
  short8 r;
#pragma unroll
  for (int k = 0; k < 8; k++) {
    float x = eluf(bf2f((unsigned short)ha[k]) + ba[c + k]);
    float y = eluf(bf2f((unsigned short)hb[k]) + bb[c + k]);
    r[k] = (short)__bfloat16_as_ushort(
        __float2bfloat16(x * w01[2 * (c + k)] + y * w01[2 * (c + k) + 1]));
  }
  *(short8*)(out + e) = r;
}

// ---------------------------------------------------------------- output-side agg (layers 2,3)
template <int C, int LD, bool WU>
__global__ __launch_bounds__(256) void agg_out_kernel(
    const bf16* __restrict__ Ha, const bf16* __restrict__ Hb,
    const int* __restrict__ off1, const int* __restrict__ cs1, const float* __restrict__ cw1,
    const int* __restrict__ off2, const int* __restrict__ cs2, const float* __restrict__ cw2,
    const float* __restrict__ dinv1, const float* __restrict__ dinv2,
    const float* __restrict__ ba, const float* __restrict__ bb,
    const float* __restrict__ w01, void* __restrict__ out, int n,
    const int* __restrict__ outflag) {
  constexpr int TPV = C / 8;
  constexpr int G = 256 / TPV;
  const int t = threadIdx.x;
  int v = blockIdx.x * G + t / TPV;
  if (v >= n) return;
  if (WU) v = __builtin_amdgcn_readfirstlane(v);
  const int c = (t % TPV) * 8;
  const bf16* __restrict__ baseA = Ha + c;
  const bf16* __restrict__ baseB = Hb + c;

  float a[8], b[8];
#pragma unroll
  for (int k = 0; k < 8; k++) { a[k] = 0.f; b[k] = 0.f; }

  int s1 = off1[v], e1 = off1[v + 1];
  if (WU) { s1 = __builtin_amdgcn_readfirstlane(s1); e1 = __builtin_amdgcn_readfirstlane(e1); }
  gather_accum<LD>(baseA, cs1, cw1, s1, e1, a);
  int s2 = off2[v], e2 = off2[v + 1];
  if (WU) { s2 = __builtin_amdgcn_readfirstlane(s2); e2 = __builtin_amdgcn_readfirstlane(e2); }
  gather_accum<LD>(baseB, cs2, cw2, s2, e2, b);

  short8 sa = *(const short8*)(baseA + (size_t)v * LD);
  short8 sb = *(const short8*)(baseB + (size_t)v * LD);
  const float dv1 = dinv1[v], dv2 = dinv2[v];

  float r[8];
#pragma unroll
  for (int k = 0; k < 8; k++) {
    float x = eluf(dv1 * a[k] + dv1 * dv1 * bf2f((unsigned short)sa[k]) + ba[c + k]);
    float y = eluf(dv2 * b[k] + dv2 * dv2 * bf2f((unsigned short)sb[k]) + bb[c + k]);
    r[k] = x * w01[2 * (c + k)] + y * w01[2 * (c + k) + 1];
  }

  const bool out_f32 = (outflag != nullptr) && (*outflag != 0);
  size_t oi = (size_t)v * C + c;
  if (out_f32) {
    floatx4 lo = {r[0], r[1], r[2], r[3]};
    floatx4 hi = {r[4], r[5], r[6], r[7]};
    *(floatx4*)((float*)out + oi) = lo;
    *(floatx4*)((float*)out + oi + 4) = hi;
  } else {
    short8 rb;
#pragma unroll
    for (int k = 0; k < 8; k++)
      rb[k] = (short)__bfloat16_as_ushort(__float2bfloat16(r[k]));
    *(short8*)((bf16*)out + oi) = rb;
  }
}

// ---------------------------------------------------------------- host pipeline
extern "C" void kernel_launch(void* const* d_in, const int* in_sizes, int n_in,
                              void* d_out, int out_size, void* d_ws, size_t ws_size,
                              hipStream_t stream) {
  const void* X = d_in[0];
  const int* ei1 = (const int*)d_in[1];
  const int* ei2 = (const int*)d_in[2];
  const int n = in_sizes[0] / 512;
  const int E1 = in_sizes[1] / 2;
  const int E2 = in_sizes[2] / 2;
  const int* src1 = ei1;           const int* dst1 = ei1 + E1;
  const int* src2 = ei2;           const int* dst2 = ei2 + E2;

  auto rnd = [](size_t b) { return (b + 255) & ~(size_t)255; };
  char* p = (char*)d_ws;
  auto alloc = [&](size_t bytes) { char* r = p; p += rnd(bytes); return r; };

  int* flag = (int*)alloc(256);
  int* deg1 = (int*)alloc((size_t)n * 4);
  int* deg2 = (int*)alloc((size_t)n * 4);
  int* cur1 = (int*)alloc((size_t)n * 4);
  int* cur2 = (int*)alloc((size_t)n * 4);
  int* off1 = (int*)alloc((size_t)(n + 1) * 4);
  int* off2 = (int*)alloc((size_t)(n + 1) * 4);
  float* dinv1 = (float*)alloc((size_t)n * 4);
  float* dinv2 = (float*)alloc((size_t)n * 4);
  int* cs1 = (int*)alloc((size_t)E1 * 4);
  float* cw1 = (float*)alloc((size_t)E1 * 4);
  int* cs2 = (int*)alloc((size_t)E2 * 4);
  float* cw2 = (float*)alloc((size_t)E2 * 4);
  bf16* Wt11 = (bf16*)alloc((size_t)512 * 1024 * 2);
  bf16* Wt12 = (bf16*)alloc((size_t)512 * 1024 * 2);
  bf16* Wt2cat = (bf16*)alloc((size_t)1024 * 1024 * 2);
  bf16* Wt3cat = (bf16*)alloc((size_t)256 * 512 * 2);
  float* bf_[6]; int bsz[6] = {1024, 1024, 512, 512, 128, 128};
  for (int i = 0; i < 6; i++) bf_[i] = (float*)alloc((size_t)bsz[i] * 4);
  float* w01_[3]; int asz[3] = {2048, 1024, 256};
  for (int i = 0; i < 3; i++) w01_[i] = (float*)alloc((size_t)asz[i] * 4);
  bf16* Xb = (bf16*)alloc((size_t)n * 512 * 2);
  bf16* aggXa = (bf16*)alloc((size_t)n * 512 * 2);
  bf16* aggXb = (bf16*)alloc((size_t)n * 512 * 2);
  bf16* H1a = (bf16*)alloc((size_t)n * 1024 * 2);
  bf16* H1b = (bf16*)alloc((size_t)n * 1024 * 2);
  bf16* act1 = (bf16*)alloc((size_t)n * 1024 * 2);
  bf16* H2cat = H1a;   // dead after combine1
  bf16* act2 = aggXa;  // dead after gemm L1
  bf16* H3cat = H1b;   // dead after combine1

  // ---- prep: probe + zero counters
  int zwords = (int)(rnd((size_t)n * 4) * 4 / 4);
  probe_zero<<<1 + (zwords + 1023) / 1024, 256, 0, stream>>>(
      (const unsigned short*)X, flag, deg1, zwords);

  // ---- fused prep
  int xbBlocks = (n * 512) / 2048;
  int degBlocks = (E1 + E2 + 255) / 256;
  prep_all<<<2176 + xbBlocks + 20 + degBlocks, 256, 0, stream>>>(
      X, Xb, n * 512,
      d_in[3], d_in[5], d_in[7], d_in[9], d_in[11], d_in[13],
      Wt11, Wt12, Wt2cat, Wt3cat,
      d_in[4], d_in[6], d_in[8], d_in[10], d_in[12], d_in[14],
      d_in[15], d_in[16], d_in[17],
      bf_[0], bf_[1], bf_[2], bf_[3], bf_[4], bf_[5],
      w01_[0], w01_[1], w01_[2],
      dst1, E1, dst2, E2, deg1, deg2, flag);

  scan2_kernel<<<2, 1024, 0, stream>>>(deg1, off1, dinv1, deg2, off2, dinv2, n);
  csr_fused<<<(E1 + E2 + 255) / 256, 256, 0, stream>>>(src1, dst1, E1, src2, dst2, E2,
                                                       off1, cur1, dinv1, cs1, cw1,
                                                       off2, cur2, dinv2, cs2, cw2);

  const int mtiles = (n + 127) / 128;
  auto swgrid = [](int mtTotal, int ntiles) {
    return 8 * ntiles * ((mtTotal + 7) / 8);
  };
  // ---- layer 1
  aggx_kernel<<<(n + 3) / 4, 256, 0, stream>>>(Xb, off1, cs1, cw1, off2, cs2, cw2,
                                               dinv1, dinv2, aggXa, aggXb, n);
  gemm128_sw<<<swgrid(2 * mtiles, 8), 256, 0, stream>>>(
      aggXa, Wt11, H1a, aggXb, Wt12, H1b, n, 512, 1024, mtiles, 2 * mtiles, 3);
  combine1_kernel<<<(n * 1024 / 8 + 255) / 256, 256, 0, stream>>>(
      H1a, H1b, bf_[0], bf_[1], w01_[0], act1, n * 1024);
  // ---- layer 2
  gemm128_sw<<<swgrid(mtiles, 8), 256, 0, stream>>>(
      act1, Wt2cat, H2cat, act1, Wt2cat, H2cat, n, 1024, 1024, mtiles, mtiles, 3);
  agg_out_kernel<512, 1024, true><<<(n + 3) / 4, 256, 0, stream>>>(
      H2cat, H2cat + 512, off1, cs1, cw1, off2, cs2, cw2,
      dinv1, dinv2, bf_[2], bf_[3], w01_[1], act2, n, (const int*)nullptr);
  // ---- layer 3
  gemm128_sw<<<swgrid(mtiles, 2), 256, 0, stream>>>(
      act2, Wt3cat, H3cat, act2, Wt3cat, H3cat, n, 512, 256, mtiles, mtiles, 1);
  agg_out_kernel<128, 256, false><<<(n + 15) / 16, 256, 0, stream>>>(
      H3cat, H3cat + 128, off1, cs1, cw1, off2, cs2, cw2,
      dinv1, dinv2, bf_[4], bf_[5], w01_[2], d_out, n, flag);
}

// Round 11
// 313.885 us; speedup vs baseline: 1.9560x; 1.0088x over previous
//
#include <hip/hip_runtime.h>
#include <hip/hip_bf16.h>
#include <math.h>

using bf16 = __hip_bfloat16;
typedef __attribute__((ext_vector_type(8))) short short8;
typedef __attribute__((ext_vector_type(4))) float floatx4;

// ---------------------------------------------------------------- helpers
__device__ inline void gl_lds16(const void* g, void* l) {
  __builtin_amdgcn_global_load_lds(
      (const __attribute__((address_space(1))) unsigned int*)g,
      (__attribute__((address_space(3))) unsigned int*)l,
      16, 0, 0);
}
__device__ inline float eluf(float x) { return x > 0.f ? x : __expf(x) - 1.f; }
__device__ inline float bf2f(unsigned short h) {
  return __uint_as_float(((unsigned)h) << 16);
}
__device__ inline void bf16x8_fma(short8 r, float w, float* acc) {
#pragma unroll
  for (int k = 0; k < 8; k++) acc[k] += w * bf2f((unsigned short)r[k]);
}

// ---------------------------------------------------------------- probe + zero counters
__global__ void probe_zero(const unsigned short* __restrict__ x, int* __restrict__ flag,
                           int* __restrict__ zbase, int zwords) {
  if (blockIdx.x == 0) {
    __shared__ int s;
    int t = threadIdx.x;
    if (t == 0) s = 0;
    __syncthreads();
    int bad = 0;
    for (int i = t; i < 1024; i += 256) {
      unsigned short h = x[2 * i];
      unsigned e = (h >> 7) & 0xFF;
      if (e >= 0xE5) bad = 1;
    }
    if (bad) atomicOr(&s, 1);
    __syncthreads();
    if (t == 0) flag[0] = s;
  } else {
    int i = (blockIdx.x - 1) * 1024 + threadIdx.x * 4;
    if (i < zwords) {
      zbase[i] = 0; zbase[i + 1] = 0; zbase[i + 2] = 0; zbase[i + 3] = 0;
    }
  }
}

// ---------------------------------------------------------------- fused prep
__global__ void prep_all(
    const void* X, bf16* __restrict__ Xb, int nx,
    const void* W11, const void* W12, const void* W21, const void* W22,
    const void* W31, const void* W32,
    bf16* Wt11, bf16* Wt12, bf16* Wt2cat, bf16* Wt3cat,
    const void* b11, const void* b12, const void* b21, const void* b22,
    const void* b31, const void* b32, const void* aw1, const void* aw2, const void* aw3,
    float* ob11, float* ob12, float* ob21, float* ob22, float* ob31, float* ob32,
    float* ow1, float* ow2, float* ow3,
    const int* __restrict__ dst1, int E1, const int* __restrict__ dst2, int E2,
    int* __restrict__ deg1, int* __restrict__ deg2,
    const int* __restrict__ flag) {
  const bool f32 = *flag != 0;
  int b = blockIdx.x;
  const int xbBlocks = nx / 2048;
  if (b < 2176) {
    __shared__ bf16 tile[32][33];
    const void* in; bf16* out; int K, N, tt;
    if (b < 512)       { in = W11; out = Wt11; K = 512;  N = 1024; tt = b; }
    else if (b < 1024) { in = W12; out = Wt12; K = 512;  N = 1024; tt = b - 512; }
    else if (b < 1536) { in = W21; out = Wt2cat; K = 1024; N = 512; tt = b - 1024; }
    else if (b < 2048) { in = W22; out = Wt2cat + (size_t)512 * 1024; K = 1024; N = 512; tt = b - 1536; }
    else if (b < 2112) { in = W31; out = Wt3cat; K = 512; N = 128; tt = b - 2048; }
    else               { in = W32; out = Wt3cat + (size_t)128 * 512; K = 512; N = 128; tt = b - 2112; }
    int tilesx = N / 32;
    int bx = (tt % tilesx) * 32;
    int by = (tt / tilesx) * 32;
    int tx = threadIdx.x & 31, ty = threadIdx.x >> 5;
#pragma unroll
    for (int i = 0; i < 32; i += 8) {
      size_t idx = (size_t)(by + ty + i) * N + (bx + tx);
      tile[ty + i][tx] = f32 ? __float2bfloat16(((const float*)in)[idx])
                             : ((const bf16*)in)[idx];
    }
    __syncthreads();
#pragma unroll
    for (int i = 0; i < 32; i += 8)
      out[(size_t)(bx + ty + i) * K + (by + tx)] = tile[tx][ty + i];
    return;
  }
  b -= 2176;
  if (b < xbBlocks) {
    int e = (b * 256 + threadIdx.x) * 8;
    if (f32) {
      const float* src = (const float*)X + e;
      short8 r;
#pragma unroll
      for (int k = 0; k < 8; k++)
        r[k] = (short)__bfloat16_as_ushort(__float2bfloat16(src[k]));
      *(short8*)(Xb + e) = r;
    } else {
      *(short8*)(Xb + e) = *(const short8*)((const bf16*)X + e);
    }
    return;
  }
  b -= xbBlocks;
  if (b < 20) {
    auto cv = [&](const void* p, int i) -> float {
      return f32 ? ((const float*)p)[i] : __bfloat162float(((const bf16*)p)[i]);
    };
    int t = b * 256 + threadIdx.x;
    if (t < 1024) ob11[t] = cv(b11, t);
    else if (t < 2048) ob12[t - 1024] = cv(b12, t - 1024);
    else if (t < 2560) ob21[t - 2048] = cv(b21, t - 2048);
    else if (t < 3072) ob22[t - 2560] = cv(b22, t - 2560);
    else if (t < 3200) ob31[t - 3072] = cv(b31, t - 3072);
    else if (t < 3328) ob32[t - 3200] = cv(b32, t - 3200);
    else if (t < 4992) {
      int j = t - 3328;
      const void* src; float* dst; int jj;
      if (j < 1024)      { src = aw1; dst = ow1; jj = j; }
      else if (j < 1536) { src = aw2; dst = ow2; jj = j - 1024; }
      else               { src = aw3; dst = ow3; jj = j - 1536; }
      float e0 = cv(src, 2 * jj), e1 = cv(src, 2 * jj + 1);
      float mx = fmaxf(e0, e1);
      float w0 = expf(e0 - mx), w1 = expf(e1 - mx);
      float inv = 1.f / (w0 + w1);
      dst[2 * jj] = w0 * inv;
      dst[2 * jj + 1] = w1 * inv;
    }
    return;
  }
  b -= 20;
  {
    int e = b * 256 + threadIdx.x;
    if (e < E1) atomicAdd(&deg1[dst1[e]], 1);
    else if (e < E1 + E2) atomicAdd(&deg2[dst2[e - E1]], 1);
  }
}

// ---------------------------------------------------------------- scan (wave-shuffle)
__global__ void scan2_kernel(const int* __restrict__ deg1, int* __restrict__ off1,
                             float* __restrict__ dinv1,
                             const int* __restrict__ deg2, int* __restrict__ off2,
                             float* __restrict__ dinv2, int n) {
  const int* deg = blockIdx.x ? deg2 : deg1;
  int* off = blockIdx.x ? off2 : off1;
  float* dinv = blockIdx.x ? dinv2 : dinv1;
  __shared__ int wsum[16];
  __shared__ int carry_s;
  const int t = threadIdx.x;
  const int waveid = t >> 6;
  const int lane = t & 63;
  if (t == 0) carry_s = 0;
  __syncthreads();
  for (int base = 0; base < n; base += 1024) {
    int i = base + t;
    int orig = (i < n) ? deg[i] : 0;
    int v = orig;
#pragma unroll
    for (int d = 1; d < 64; d <<= 1) {
      int u = __shfl_up(v, d, 64);
      if (lane >= d) v += u;
    }
    if (lane == 63) wsum[waveid] = v;
    __syncthreads();
    if (waveid == 0 && lane < 16) {
      int s = wsum[lane];
#pragma unroll
      for (int d = 1; d < 16; d <<= 1) {
        int u = __shfl_up(s, d, 64);
        if (lane >= d) s += u;
      }
      wsum[lane] = s;
    }
    __syncthreads();
    int woff = waveid ? wsum[waveid - 1] : 0;
    int incl = v + woff;
    int carry = carry_s;
    if (i < n) {
      off[i]  = carry + incl - orig;
      dinv[i] = rsqrtf((float)(orig + 1));
    }
    __syncthreads();
    if (t == 1023) carry_s = carry + wsum[15];
    __syncthreads();
  }
  if (t == 0) off[n] = carry_s;
}

__global__ void csr_fused(const int* __restrict__ src1, const int* __restrict__ dst1, int E1,
                          const int* __restrict__ src2, const int* __restrict__ dst2, int E2,
                          const int* __restrict__ off1, int* __restrict__ cur1,
                          const float* __restrict__ dinv1,
                          int* __restrict__ cs1, float* __restrict__ cw1,
                          const int* __restrict__ off2, int* __restrict__ cur2,
                          const float* __restrict__ dinv2,
                          int* __restrict__ cs2, float* __restrict__ cw2) {
  int e = blockIdx.x * 256 + threadIdx.x;
  if (e < E1) {
    int d = dst1[e], s = src1[e];
    int slot = off1[d] + atomicAdd(&cur1[d], 1);
    cs1[slot] = s;
    cw1[slot] = dinv1[s];
  } else if (e < E1 + E2) {
    int ee = e - E1;
    int d = dst2[ee], s = src2[ee];
    int slot = off2[d] + atomicAdd(&cur2[d], 1);
    cs2[slot] = s;
    cw2[slot] = dinv2[s];
  }
}

// ---------------------------------------------------------------- gather loop (8/4/2/1 unroll)
template <int LD>
__device__ inline void gather_accum(const bf16* __restrict__ base,
                                    const int* __restrict__ cs, const float* __restrict__ cw,
                                    int s, int e, float* acc) {
  int i = s;
  for (; i + 8 <= e; i += 8) {
    short8 r[8]; float w[8];
#pragma unroll
    for (int k = 0; k < 8; k++) {
      r[k] = *(const short8*)(base + (size_t)cs[i + k] * LD);
      w[k] = cw[i + k];
    }
#pragma unroll
    for (int k = 0; k < 8; k++) bf16x8_fma(r[k], w[k], acc);
  }
  for (; i + 4 <= e; i += 4) {
    short8 r[4]; float w[4];
#pragma unroll
    for (int k = 0; k < 4; k++) {
      r[k] = *(const short8*)(base + (size_t)cs[i + k] * LD);
      w[k] = cw[i + k];
    }
#pragma unroll
    for (int k = 0; k < 4; k++) bf16x8_fma(r[k], w[k], acc);
  }
  for (; i + 2 <= e; i += 2) {
    short8 r0 = *(const short8*)(base + (size_t)cs[i] * LD);
    short8 r1 = *(const short8*)(base + (size_t)cs[i + 1] * LD);
    bf16x8_fma(r0, cw[i], acc);
    bf16x8_fma(r1, cw[i + 1], acc);
  }
  if (i < e) {
    short8 r0 = *(const short8*)(base + (size_t)cs[i] * LD);
    bf16x8_fma(r0, cw[i], acc);
  }
}

// ---------------------------------------------------------------- input-side agg (layer 1)
__global__ __launch_bounds__(256) void aggx_kernel(
    const bf16* __restrict__ X,
    const int* __restrict__ off1, const int* __restrict__ cs1, const float* __restrict__ cw1,
    const int* __restrict__ off2, const int* __restrict__ cs2, const float* __restrict__ cw2,
    const float* __restrict__ dinv1, const float* __restrict__ dinv2,
    bf16* __restrict__ outA, bf16* __restrict__ outB, int n) {
  int v = blockIdx.x * 4 + (threadIdx.x >> 6);
  if (v >= n) return;
  v = __builtin_amdgcn_readfirstlane(v);
  const int c = (threadIdx.x & 63) * 8;
  const bf16* __restrict__ base = X + c;

  float a[8], b[8];
#pragma unroll
  for (int k = 0; k < 8; k++) { a[k] = 0.f; b[k] = 0.f; }

  int s1 = __builtin_amdgcn_readfirstlane(off1[v]);
  int e1 = __builtin_amdgcn_readfirstlane(off1[v + 1]);
  gather_accum<512>(base, cs1, cw1, s1, e1, a);
  int s2 = __builtin_amdgcn_readfirstlane(off2[v]);
  int e2 = __builtin_amdgcn_readfirstlane(off2[v + 1]);
  gather_accum<512>(base, cs2, cw2, s2, e2, b);

  short8 self = *(const short8*)(base + (size_t)v * 512);
  const float dv1 = dinv1[v], dv2 = dinv2[v];
  short8 ra, rb;
#pragma unroll
  for (int k = 0; k < 8; k++) {
    float xs = bf2f((unsigned short)self[k]);
    ra[k] = (short)__bfloat16_as_ushort(__float2bfloat16(dv1 * a[k] + dv1 * dv1 * xs));
    rb[k] = (short)__bfloat16_as_ushort(__float2bfloat16(dv2 * b[k] + dv2 * dv2 * xs));
  }
  *(short8*)(outA + (size_t)v * 512 + c) = ra;
  *(short8*)(outB + (size_t)v * 512 + c) = rb;
}

// ---------------------------------------------------------------- GEMM (m97-style, XOR-swizzled LDS)
__device__ inline void gemm_body(const bf16* __restrict__ A, const bf16* __restrict__ Bt,
                                 bf16* __restrict__ C, int M, int K, int N,
                                 int m0, int n0) {
  __shared__ bf16 As[128 * 32];
  __shared__ bf16 Bs[128 * 32];
  const int tid = threadIdx.x;
  const int wave = tid >> 6;
  const int lane = tid & 63;
  const int quad = lane >> 4;
  const int l16 = lane & 15;
  const int wr = (wave >> 1) * 64;
  const int wc = (wave & 1) * 64;
  const int r_sub = lane >> 2;
  const int cb = (((lane & 3) ^ ((lane >> 3) & 3)) * 16);
  const int rsw = (l16 >> 1) & 3;

  floatx4 acc[4][4];
#pragma unroll
  for (int i = 0; i < 4; i++)
#pragma unroll
    for (int j = 0; j < 4; j++) acc[i][j] = (floatx4){0.f, 0.f, 0.f, 0.f};

  for (int k0 = 0; k0 < K; k0 += 32) {
    __syncthreads();
#pragma unroll
    for (int j = 0; j < 2; ++j) {
      int p = wave * 2 + j;
      int ra = p * 16 + r_sub;
      int grow = m0 + ra; if (grow >= M) grow = M - 1;
      gl_lds16((const char*)(A + (size_t)grow * K + k0) + cb, (char*)As + p * 1024);
      int rb = n0 + p * 16 + r_sub;
      gl_lds16((const char*)(Bt + (size_t)rb * K + k0) + cb, (char*)Bs + p * 1024);
    }
    __syncthreads();

    short8 af[4], bfr[4];
#pragma unroll
    for (int i = 0; i < 4; i++)
      af[i] = *(const short8*)(As + (wr + i * 16 + l16) * 32 + (quad ^ rsw) * 8);
#pragma unroll
    for (int j = 0; j < 4; j++)
      bfr[j] = *(const short8*)(Bs + (wc + j * 16 + l16) * 32 + (quad ^ rsw) * 8);
#pragma unroll
    for (int i = 0; i < 4; i++)
#pragma unroll
      for (int j = 0; j < 4; j++)
        acc[i][j] = __builtin_amdgcn_mfma_f32_16x16x32_bf16(af[i], bfr[j], acc[i][j], 0, 0, 0);
  }

#pragma unroll
  for (int i = 0; i < 4; i++) {
#pragma unroll
    for (int r = 0; r < 4; r++) {
      int row = m0 + wr + i * 16 + quad * 4 + r;
      if (row < M) {
#pragma unroll
        for (int j = 0; j < 4; j++) {
          int col = n0 + wc + j * 16 + l16;
          C[(size_t)row * N + col] = __float2bfloat16(acc[i][j][r]);
        }
      }
    }
  }
}

__global__ __launch_bounds__(256) void gemm128_sw(
    const bf16* __restrict__ A0, const bf16* __restrict__ Bt0, bf16* __restrict__ C0,
    const bf16* __restrict__ A1, const bf16* __restrict__ Bt1, bf16* __restrict__ C1,
    int M, int K, int N, int mtilesPerHalf, int mtTotal, int ntLog2) {
  int lin = blockIdx.x;
  int g = lin & 7;
  int s = lin >> 3;
  int n_t = s & ((1 << ntLog2) - 1);
  int m_t = g + 8 * (s >> ntLog2);
  if (m_t >= mtTotal) return;
  int half = (m_t >= mtilesPerHalf) ? 1 : 0;
  int m_local = m_t - half * mtilesPerHalf;
  const bf16* A = half ? A1 : A0;
  const bf16* Bt = half ? Bt1 : Bt0;
  bf16* C = half ? C1 : C0;
  gemm_body(A, Bt, C, M, K, N, m_local * 128, n_t * 128);
}

// ---------------------------------------------------------------- layer-1 fused GEMM
// act1 = w0*elu(aggXa@W11 + ba) + w1*elu(aggXb@W12 + bb)
// 128x64 tiles, acc 2x(4x2) = 64 VGPRs (occupancy-safe, unlike R6's 2x(4x4)).
// Separate LDS buffers per operand pair -> both phases staged under 2 barriers/k0.
__global__ __launch_bounds__(256) void gemm_l1f(
    const bf16* __restrict__ Aa, const bf16* __restrict__ Bta,
    const bf16* __restrict__ Ab, const bf16* __restrict__ Btb,
    const float* __restrict__ ba, const float* __restrict__ bb,
    const float* __restrict__ w01, bf16* __restrict__ out,
    int M, int K, int N, int mtiles) {
  int lin = blockIdx.x;
  int g = lin & 7;
  int s = lin >> 3;
  int n_t = s & 15;                 // 16 n-tiles of 64
  int m_t = g + 8 * (s >> 4);
  if (m_t >= mtiles) return;
  const int m0 = m_t * 128, n0 = n_t * 64;

  __shared__ bf16 Asa[128 * 32];
  __shared__ bf16 Asb[128 * 32];
  __shared__ bf16 Bsa[64 * 32];
  __shared__ bf16 Bsb[64 * 32];
  const int tid = threadIdx.x;
  const int wave = tid >> 6;
  const int lane = tid & 63;
  const int quad = lane >> 4;
  const int l16 = lane & 15;
  const int wr = (wave >> 1) * 64;
  const int wc = (wave & 1) * 32;
  const int r_sub = lane >> 2;
  const int cb = (((lane & 3) ^ ((lane >> 3) & 3)) * 16);
  const int rsw = (l16 >> 1) & 3;

  floatx4 acca[4][2], accb[4][2];
#pragma unroll
  for (int i = 0; i < 4; i++)
#pragma unroll
    for (int j = 0; j < 2; j++) {
      acca[i][j] = (floatx4){0.f, 0.f, 0.f, 0.f};
      accb[i][j] = (floatx4){0.f, 0.f, 0.f, 0.f};
    }

  for (int k0 = 0; k0 < K; k0 += 32) {
    __syncthreads();
#pragma unroll
    for (int j = 0; j < 2; ++j) {
      int p = wave * 2 + j;
      int ra = p * 16 + r_sub;
      int grow = m0 + ra; if (grow >= M) grow = M - 1;
      gl_lds16((const char*)(Aa + (size_t)grow * K + k0) + cb, (char*)Asa + p * 1024);
      gl_lds16((const char*)(Ab + (size_t)grow * K + k0) + cb, (char*)Asb + p * 1024);
    }
    {
      int rb = n0 + wave * 16 + r_sub;   // N=1024 mult of 64, no guard
      gl_lds16((const char*)(Bta + (size_t)rb * K + k0) + cb, (char*)Bsa + wave * 1024);
      gl_lds16((const char*)(Btb + (size_t)rb * K + k0) + cb, (char*)Bsb + wave * 1024);
    }
    __syncthreads();

    short8 afa[4], afb[4], bfa[2], bfb[2];
#pragma unroll
    for (int i = 0; i < 4; i++) {
      afa[i] = *(const short8*)(Asa + (wr + i * 16 + l16) * 32 + (quad ^ rsw) * 8);
      afb[i] = *(const short8*)(Asb + (wr + i * 16 + l16) * 32 + (quad ^ rsw) * 8);
    }
#pragma unroll
    for (int j = 0; j < 2; j++) {
      bfa[j] = *(const short8*)(Bsa + (wc + j * 16 + l16) * 32 + (quad ^ rsw) * 8);
      bfb[j] = *(const short8*)(Bsb + (wc + j * 16 + l16) * 32 + (quad ^ rsw) * 8);
    }
#pragma unroll
    for (int i = 0; i < 4; i++)
#pragma unroll
      for (int j = 0; j < 2; j++) {
        acca[i][j] = __builtin_amdgcn_mfma_f32_16x16x32_bf16(afa[i], bfa[j], acca[i][j], 0, 0, 0);
        accb[i][j] = __builtin_amdgcn_mfma_f32_16x16x32_bf16(afb[i], bfb[j], accb[i][j], 0, 0, 0);
      }
  }

#pragma unroll
  for (int j = 0; j < 2; j++) {
    int col = n0 + wc + j * 16 + l16;
    float baj = ba[col], bbj = bb[col];
    float w0 = w01[2 * col], w1 = w01[2 * col + 1];
#pragma unroll
    for (int i = 0; i < 4; i++) {
#pragma unroll
      for (int r = 0; r < 4; r++) {
        int row = m0 + wr + i * 16 + quad * 4 + r;
        if (row < M) {
          float x = eluf(acca[i][j][r] + baj);
          float y = eluf(accb[i][j][r] + bbj);
          out[(size_t)row * N + col] = __float2bfloat16(x * w0 + y * w1);
        }
      }
    }
  }
}

// ---------------------------------------------------------------- output-side agg (layers 2,3)
template <int C, int LD, bool WU>
__global__ __launch_bounds__(256) void agg_out_kernel(
    const bf16* __restrict__ Ha, const bf16* __restrict__ Hb,
    const int* __restrict__ off1, const int* __restrict__ cs1, const float* __restrict__ cw1,
    const int* __restrict__ off2, const int* __restrict__ cs2, const float* __restrict__ cw2,
    const float* __restrict__ dinv1, const float* __restrict__ dinv2,
    const float* __restrict__ ba, const float* __restrict__ bb,
    const float* __restrict__ w01, void* __restrict__ out, int n,
    const int* __restrict__ outflag) {
  constexpr int TPV = C / 8;
  constexpr int G = 256 / TPV;
  const int t = threadIdx.x;
  int v = blockIdx.x * G + t / TPV;
  if (v >= n) return;
  if (WU) v = __builtin_amdgcn_readfirstlane(v);
  const int c = (t % TPV) * 8;
  const bf16* __restrict__ baseA = Ha + c;
  const bf16* __restrict__ baseB = Hb + c;

  float a[8], b[8];
#pragma unroll
  for (int k = 0; k < 8; k++) { a[k] = 0.f; b[k] = 0.f; }

  int s1 = off1[v], e1 = off1[v + 1];
  if (WU) { s1 = __builtin_amdgcn_readfirstlane(s1); e1 = __builtin_amdgcn_readfirstlane(e1); }
  gather_accum<LD>(baseA, cs1, cw1, s1, e1, a);
  int s2 = off2[v], e2 = off2[v + 1];
  if (WU) { s2 = __builtin_amdgcn_readfirstlane(s2); e2 = __builtin_amdgcn_readfirstlane(e2); }
  gather_accum<LD>(baseB, cs2, cw2, s2, e2, b);

  short8 sa = *(const short8*)(baseA + (size_t)v * LD);
  short8 sb = *(const short8*)(baseB + (size_t)v * LD);
  const float dv1 = dinv1[v], dv2 = dinv2[v];

  float r[8];
#pragma unroll
  for (int k = 0; k < 8; k++) {
    float x = eluf(dv1 * a[k] + dv1 * dv1 * bf2f((unsigned short)sa[k]) + ba[c + k]);
    float y = eluf(dv2 * b[k] + dv2 * dv2 * bf2f((unsigned short)sb[k]) + bb[c + k]);
    r[k] = x * w01[2 * (c + k)] + y * w01[2 * (c + k) + 1];
  }

  const bool out_f32 = (outflag != nullptr) && (*outflag != 0);
  size_t oi = (size_t)v * C + c;
  if (out_f32) {
    floatx4 lo = {r[0], r[1], r[2], r[3]};
    floatx4 hi = {r[4], r[5], r[6], r[7]};
    *(floatx4*)((float*)out + oi) = lo;
    *(floatx4*)((float*)out + oi + 4) = hi;
  } else {
    short8 rb;
#pragma unroll
    for (int k = 0; k < 8; k++)
      rb[k] = (short)__bfloat16_as_ushort(__float2bfloat16(r[k]));
    *(short8*)((bf16*)out + oi) = rb;
  }
}

// ---------------------------------------------------------------- host pipeline
extern "C" void kernel_launch(void* const* d_in, const int* in_sizes, int n_in,
                              void* d_out, int out_size, void* d_ws, size_t ws_size,
                              hipStream_t stream) {
  const void* X = d_in[0];
  const int* ei1 = (const int*)d_in[1];
  const int* ei2 = (const int*)d_in[2];
  const int n = in_sizes[0] / 512;
  const int E1 = in_sizes[1] / 2;
  const int E2 = in_sizes[2] / 2;
  const int* src1 = ei1;           const int* dst1 = ei1 + E1;
  const int* src2 = ei2;           const int* dst2 = ei2 + E2;

  auto rnd = [](size_t b) { return (b + 255) & ~(size_t)255; };
  char* p = (char*)d_ws;
  auto alloc = [&](size_t bytes) { char* r = p; p += rnd(bytes); return r; };

  int* flag = (int*)alloc(256);
  int* deg1 = (int*)alloc((size_t)n * 4);
  int* deg2 = (int*)alloc((size_t)n * 4);
  int* cur1 = (int*)alloc((size_t)n * 4);
  int* cur2 = (int*)alloc((size_t)n * 4);
  int* off1 = (int*)alloc((size_t)(n + 1) * 4);
  int* off2 = (int*)alloc((size_t)(n + 1) * 4);
  float* dinv1 = (float*)alloc((size_t)n * 4);
  float* dinv2 = (float*)alloc((size_t)n * 4);
  int* cs1 = (int*)alloc((size_t)E1 * 4);
  float* cw1 = (float*)alloc((size_t)E1 * 4);
  int* cs2 = (int*)alloc((size_t)E2 * 4);
  float* cw2 = (float*)alloc((size_t)E2 * 4);
  bf16* Wt11 = (bf16*)alloc((size_t)512 * 1024 * 2);
  bf16* Wt12 = (bf16*)alloc((size_t)512 * 1024 * 2);
  bf16* Wt2cat = (bf16*)alloc((size_t)1024 * 1024 * 2);
  bf16* Wt3cat = (bf16*)alloc((size_t)256 * 512 * 2);
  float* bf_[6]; int bsz[6] = {1024, 1024, 512, 512, 128, 128};
  for (int i = 0; i < 6; i++) bf_[i] = (float*)alloc((size_t)bsz[i] * 4);
  float* w01_[3]; int asz[3] = {2048, 1024, 256};
  for (int i = 0; i < 3; i++) w01_[i] = (float*)alloc((size_t)asz[i] * 4);
  bf16* Xb = (bf16*)alloc((size_t)n * 512 * 2);
  bf16* aggXa = (bf16*)alloc((size_t)n * 512 * 2);
  bf16* aggXb = (bf16*)alloc((size_t)n * 512 * 2);
  bf16* H1a = (bf16*)alloc((size_t)n * 1024 * 2);
  bf16* act1 = (bf16*)alloc((size_t)n * 1024 * 2);
  bf16* H2cat = H1a;
  bf16* act2 = aggXa;  // dead after gemm_l1f
  bf16* H3cat = aggXb; // dead after gemm_l1f

  // ---- prep: probe + zero counters
  int zwords = (int)(rnd((size_t)n * 4) * 4 / 4);
  probe_zero<<<1 + (zwords + 1023) / 1024, 256, 0, stream>>>(
      (const unsigned short*)X, flag, deg1, zwords);

  // ---- fused prep
  int xbBlocks = (n * 512) / 2048;
  int degBlocks = (E1 + E2 + 255) / 256;
  prep_all<<<2176 + xbBlocks + 20 + degBlocks, 256, 0, stream>>>(
      X, Xb, n * 512,
      d_in[3], d_in[5], d_in[7], d_in[9], d_in[11], d_in[13],
      Wt11, Wt12, Wt2cat, Wt3cat,
      d_in[4], d_in[6], d_in[8], d_in[10], d_in[12], d_in[14],
      d_in[15], d_in[16], d_in[17],
      bf_[0], bf_[1], bf_[2], bf_[3], bf_[4], bf_[5],
      w01_[0], w01_[1], w01_[2],
      dst1, E1, dst2, E2, deg1, deg2, flag);

  scan2_kernel<<<2, 1024, 0, stream>>>(deg1, off1, dinv1, deg2, off2, dinv2, n);
  csr_fused<<<(E1 + E2 + 255) / 256, 256, 0, stream>>>(src1, dst1, E1, src2, dst2, E2,
                                                       off1, cur1, dinv1, cs1, cw1,
                                                       off2, cur2, dinv2, cs2, cw2);

  const int mtiles = (n + 127) / 128;
  auto swgrid = [](int mtTotal, int ntiles) {
    return 8 * ntiles * ((mtTotal + 7) / 8);
  };
  // ---- layer 1: input-side agg + fused dual-GEMM/bias/ELU/combine (128x64 tiles)
  aggx_kernel<<<(n + 3) / 4, 256, 0, stream>>>(Xb, off1, cs1, cw1, off2, cs2, cw2,
                                               dinv1, dinv2, aggXa, aggXb, n);
  gemm_l1f<<<swgrid(mtiles, 16), 256, 0, stream>>>(
      aggXa, Wt11, aggXb, Wt12, bf_[0], bf_[1], w01_[0], act1, n, 512, 1024, mtiles);
  // ---- layer 2
  gemm128_sw<<<swgrid(mtiles, 8), 256, 0, stream>>>(
      act1, Wt2cat, H2cat, act1, Wt2cat, H2cat, n, 1024, 1024, mtiles, mtiles, 3);
  agg_out_kernel<512, 1024, true><<<(n + 3) / 4, 256, 0, stream>>>(
      H2cat, H2cat + 512, off1, cs1, cw1, off2, cs2, cw2,
      dinv1, dinv2, bf_[2], bf_[3], w01_[1], act2, n, (const int*)nullptr);
  // ---- layer 3
  gemm128_sw<<<swgrid(mtiles, 2), 256, 0, stream>>>(
      act2, Wt3cat, H3cat, act2, Wt3cat, H3cat, n, 512, 256, mtiles, mtiles, 1);
  agg_out_kernel<128, 256, false><<<(n + 15) / 16, 256, 0, stream>>>(
      H3cat, H3cat + 128, off1, cs1, cw1, off2, cs2, cw2,
      dinv1, dinv2, bf_[4], bf_[5], w01_[2], d_out, n, flag);
}

// Round 12
// 311.206 us; speedup vs baseline: 1.9728x; 1.0086x over previous
//
#include <hip/hip_runtime.h>
#include <hip/hip_bf16.h>
#include <math.h>

using bf16 = __hip_bfloat16;
typedef __attribute__((ext_vector_type(8))) short short8;
typedef __attribute__((ext_vector_type(4))) float floatx4;

// ---------------------------------------------------------------- helpers
__device__ inline void gl_lds16(const void* g, void* l) {
  __builtin_amdgcn_global_load_lds(
      (const __attribute__((address_space(1))) unsigned int*)g,
      (__attribute__((address_space(3))) unsigned int*)l,
      16, 0, 0);
}
__device__ inline float eluf(float x) { return x > 0.f ? x : __expf(x) - 1.f; }
__device__ inline float bf2f(unsigned short h) {
  return __uint_as_float(((unsigned)h) << 16);
}
__device__ inline void bf16x8_fma(short8 r, float w, float* acc) {
#pragma unroll
  for (int k = 0; k < 8; k++) acc[k] += w * bf2f((unsigned short)r[k]);
}

// ---------------------------------------------------------------- probe + zero counters
__global__ void probe_zero(const unsigned short* __restrict__ x, int* __restrict__ flag,
                           int* __restrict__ zbase, int zwords) {
  if (blockIdx.x == 0) {
    __shared__ int s;
    int t = threadIdx.x;
    if (t == 0) s = 0;
    __syncthreads();
    int bad = 0;
    for (int i = t; i < 1024; i += 256) {
      unsigned short h = x[2 * i];
      unsigned e = (h >> 7) & 0xFF;
      if (e >= 0xE5) bad = 1;
    }
    if (bad) atomicOr(&s, 1);
    __syncthreads();
    if (t == 0) flag[0] = s;
  } else {
    int i = (blockIdx.x - 1) * 1024 + threadIdx.x * 4;
    if (i < zwords) {
      zbase[i] = 0; zbase[i + 1] = 0; zbase[i + 2] = 0; zbase[i + 3] = 0;
    }
  }
}

// ---------------------------------------------------------------- fused prep
__global__ void prep_all(
    const void* X, bf16* __restrict__ Xb, int nx,
    const void* W11, const void* W12, const void* W21, const void* W22,
    const void* W31, const void* W32,
    bf16* Wt11, bf16* Wt12, bf16* Wt2cat, bf16* Wt3cat,
    const void* b11, const void* b12, const void* b21, const void* b22,
    const void* b31, const void* b32, const void* aw1, const void* aw2, const void* aw3,
    float* ob11, float* ob12, float* ob21, float* ob22, float* ob31, float* ob32,
    float* ow1, float* ow2, float* ow3,
    const int* __restrict__ dst1, int E1, const int* __restrict__ dst2, int E2,
    int* __restrict__ deg1, int* __restrict__ deg2,
    const int* __restrict__ flag) {
  const bool f32 = *flag != 0;
  int b = blockIdx.x;
  const int xbBlocks = nx / 2048;
  if (b < 2176) {
    __shared__ bf16 tile[32][33];
    const void* in; bf16* out; int K, N, tt;
    if (b < 512)       { in = W11; out = Wt11; K = 512;  N = 1024; tt = b; }
    else if (b < 1024) { in = W12; out = Wt12; K = 512;  N = 1024; tt = b - 512; }
    else if (b < 1536) { in = W21; out = Wt2cat; K = 1024; N = 512; tt = b - 1024; }
    else if (b < 2048) { in = W22; out = Wt2cat + (size_t)512 * 1024; K = 1024; N = 512; tt = b - 1536; }
    else if (b < 2112) { in = W31; out = Wt3cat; K = 512; N = 128; tt = b - 2048; }
    else               { in = W32; out = Wt3cat + (size_t)128 * 512; K = 512; N = 128; tt = b - 2112; }
    int tilesx = N / 32;
    int bx = (tt % tilesx) * 32;
    int by = (tt / tilesx) * 32;
    int tx = threadIdx.x & 31, ty = threadIdx.x >> 5;
#pragma unroll
    for (int i = 0; i < 32; i += 8) {
      size_t idx = (size_t)(by + ty + i) * N + (bx + tx);
      tile[ty + i][tx] = f32 ? __float2bfloat16(((const float*)in)[idx])
                             : ((const bf16*)in)[idx];
    }
    __syncthreads();
#pragma unroll
    for (int i = 0; i < 32; i += 8)
      out[(size_t)(bx + ty + i) * K + (by + tx)] = tile[tx][ty + i];
    return;
  }
  b -= 2176;
  if (b < xbBlocks) {
    int e = (b * 256 + threadIdx.x) * 8;
    if (f32) {
      const float* src = (const float*)X + e;
      short8 r;
#pragma unroll
      for (int k = 0; k < 8; k++)
        r[k] = (short)__bfloat16_as_ushort(__float2bfloat16(src[k]));
      *(short8*)(Xb + e) = r;
    } else {
      *(short8*)(Xb + e) = *(const short8*)((const bf16*)X + e);
    }
    return;
  }
  b -= xbBlocks;
  if (b < 20) {
    auto cv = [&](const void* p, int i) -> float {
      return f32 ? ((const float*)p)[i] : __bfloat162float(((const bf16*)p)[i]);
    };
    int t = b * 256 + threadIdx.x;
    if (t < 1024) ob11[t] = cv(b11, t);
    else if (t < 2048) ob12[t - 1024] = cv(b12, t - 1024);
    else if (t < 2560) ob21[t - 2048] = cv(b21, t - 2048);
    else if (t < 3072) ob22[t - 2560] = cv(b22, t - 2560);
    else if (t < 3200) ob31[t - 3072] = cv(b31, t - 3072);
    else if (t < 3328) ob32[t - 3200] = cv(b32, t - 3200);
    else if (t < 4992) {
      int j = t - 3328;
      const void* src; float* dst; int jj;
      if (j < 1024)      { src = aw1; dst = ow1; jj = j; }
      else if (j < 1536) { src = aw2; dst = ow2; jj = j - 1024; }
      else               { src = aw3; dst = ow3; jj = j - 1536; }
      float e0 = cv(src, 2 * jj), e1 = cv(src, 2 * jj + 1);
      float mx = fmaxf(e0, e1);
      float w0 = expf(e0 - mx), w1 = expf(e1 - mx);
      float inv = 1.f / (w0 + w1);
      dst[2 * jj] = w0 * inv;
      dst[2 * jj + 1] = w1 * inv;
    }
    return;
  }
  b -= 20;
  {
    int e = b * 256 + threadIdx.x;
    if (e < E1) atomicAdd(&deg1[dst1[e]], 1);
    else if (e < E1 + E2) atomicAdd(&deg2[dst2[e - E1]], 1);
  }
}

// ---------------------------------------------------------------- scan (wave-shuffle)
__global__ void scan2_kernel(const int* __restrict__ deg1, int* __restrict__ off1,
                             float* __restrict__ dinv1,
                             const int* __restrict__ deg2, int* __restrict__ off2,
                             float* __restrict__ dinv2, int n) {
  const int* deg = blockIdx.x ? deg2 : deg1;
  int* off = blockIdx.x ? off2 : off1;
  float* dinv = blockIdx.x ? dinv2 : dinv1;
  __shared__ int wsum[16];
  __shared__ int carry_s;
  const int t = threadIdx.x;
  const int waveid = t >> 6;
  const int lane = t & 63;
  if (t == 0) carry_s = 0;
  __syncthreads();
  for (int base = 0; base < n; base += 1024) {
    int i = base + t;
    int orig = (i < n) ? deg[i] : 0;
    int v = orig;
#pragma unroll
    for (int d = 1; d < 64; d <<= 1) {
      int u = __shfl_up(v, d, 64);
      if (lane >= d) v += u;
    }
    if (lane == 63) wsum[waveid] = v;
    __syncthreads();
    if (waveid == 0 && lane < 16) {
      int s = wsum[lane];
#pragma unroll
      for (int d = 1; d < 16; d <<= 1) {
        int u = __shfl_up(s, d, 64);
        if (lane >= d) s += u;
      }
      wsum[lane] = s;
    }
    __syncthreads();
    int woff = waveid ? wsum[waveid - 1] : 0;
    int incl = v + woff;
    int carry = carry_s;
    if (i < n) {
      off[i]  = carry + incl - orig;
      dinv[i] = rsqrtf((float)(orig + 1));
    }
    __syncthreads();
    if (t == 1023) carry_s = carry + wsum[15];
    __syncthreads();
  }
  if (t == 0) off[n] = carry_s;
}

__global__ void csr_fused(const int* __restrict__ src1, const int* __restrict__ dst1, int E1,
                          const int* __restrict__ src2, const int* __restrict__ dst2, int E2,
                          const int* __restrict__ off1, int* __restrict__ cur1,
                          const float* __restrict__ dinv1,
                          int* __restrict__ cs1, float* __restrict__ cw1,
                          const int* __restrict__ off2, int* __restrict__ cur2,
                          const float* __restrict__ dinv2,
                          int* __restrict__ cs2, float* __restrict__ cw2) {
  int e = blockIdx.x * 256 + threadIdx.x;
  if (e < E1) {
    int d = dst1[e], s = src1[e];
    int slot = off1[d] + atomicAdd(&cur1[d], 1);
    cs1[slot] = s;
    cw1[slot] = dinv1[s];
  } else if (e < E1 + E2) {
    int ee = e - E1;
    int d = dst2[ee], s = src2[ee];
    int slot = off2[d] + atomicAdd(&cur2[d], 1);
    cs2[slot] = s;
    cw2[slot] = dinv2[s];
  }
}

// ---------------------------------------------------------------- gather loop (8/4/2/1 unroll)
template <int LD>
__device__ inline void gather_accum(const bf16* __restrict__ base,
                                    const int* __restrict__ cs, const float* __restrict__ cw,
                                    int s, int e, float* acc) {
  int i = s;
  for (; i + 8 <= e; i += 8) {
    short8 r[8]; float w[8];
#pragma unroll
    for (int k = 0; k < 8; k++) {
      r[k] = *(const short8*)(base + (size_t)cs[i + k] * LD);
      w[k] = cw[i + k];
    }
#pragma unroll
    for (int k = 0; k < 8; k++) bf16x8_fma(r[k], w[k], acc);
  }
  for (; i + 4 <= e; i += 4) {
    short8 r[4]; float w[4];
#pragma unroll
    for (int k = 0; k < 4; k++) {
      r[k] = *(const short8*)(base + (size_t)cs[i + k] * LD);
      w[k] = cw[i + k];
    }
#pragma unroll
    for (int k = 0; k < 4; k++) bf16x8_fma(r[k], w[k], acc);
  }
  for (; i + 2 <= e; i += 2) {
    short8 r0 = *(const short8*)(base + (size_t)cs[i] * LD);
    short8 r1 = *(const short8*)(base + (size_t)cs[i + 1] * LD);
    bf16x8_fma(r0, cw[i], acc);
    bf16x8_fma(r1, cw[i + 1], acc);
  }
  if (i < e) {
    short8 r0 = *(const short8*)(base + (size_t)cs[i] * LD);
    bf16x8_fma(r0, cw[i], acc);
  }
}

// ---------------------------------------------------------------- input-side agg (layer 1)
// XCD channel-sliced: blockIdx&7 = 64-channel slice -> per-XCD X stripe 1.25 MB (L2-resident).
// Block = 32 vertices x 8 lanes.
__global__ __launch_bounds__(256) void aggx_kernel(
    const bf16* __restrict__ X,
    const int* __restrict__ off1, const int* __restrict__ cs1, const float* __restrict__ cw1,
    const int* __restrict__ off2, const int* __restrict__ cs2, const float* __restrict__ cw2,
    const float* __restrict__ dinv1, const float* __restrict__ dinv2,
    bf16* __restrict__ outA, bf16* __restrict__ outB, int n) {
  const int lin = blockIdx.x;
  const int slice = lin & 7;
  const int vg = lin >> 3;
  const int t = threadIdx.x;
  const int v = vg * 32 + t / 8;
  if (v >= n) return;
  const int c = slice * 64 + (t & 7) * 8;
  const bf16* __restrict__ base = X + c;

  float a[8], b[8];
#pragma unroll
  for (int k = 0; k < 8; k++) { a[k] = 0.f; b[k] = 0.f; }

  gather_accum<512>(base, cs1, cw1, off1[v], off1[v + 1], a);
  gather_accum<512>(base, cs2, cw2, off2[v], off2[v + 1], b);

  short8 self = *(const short8*)(base + (size_t)v * 512);
  const float dv1 = dinv1[v], dv2 = dinv2[v];
  short8 ra, rb;
#pragma unroll
  for (int k = 0; k < 8; k++) {
    float xs = bf2f((unsigned short)self[k]);
    ra[k] = (short)__bfloat16_as_ushort(__float2bfloat16(dv1 * a[k] + dv1 * dv1 * xs));
    rb[k] = (short)__bfloat16_as_ushort(__float2bfloat16(dv2 * b[k] + dv2 * dv2 * xs));
  }
  *(short8*)(outA + (size_t)v * 512 + c) = ra;
  *(short8*)(outB + (size_t)v * 512 + c) = rb;
}

// ---------------------------------------------------------------- GEMM (m97-style, XOR-swizzled LDS)
__device__ inline void gemm_body(const bf16* __restrict__ A, const bf16* __restrict__ Bt,
                                 bf16* __restrict__ C, int M, int K, int N,
                                 int m0, int n0) {
  __shared__ bf16 As[128 * 32];
  __shared__ bf16 Bs[128 * 32];
  const int tid = threadIdx.x;
  const int wave = tid >> 6;
  const int lane = tid & 63;
  const int quad = lane >> 4;
  const int l16 = lane & 15;
  const int wr = (wave >> 1) * 64;
  const int wc = (wave & 1) * 64;
  const int r_sub = lane >> 2;
  const int cb = (((lane & 3) ^ ((lane >> 3) & 3)) * 16);
  const int rsw = (l16 >> 1) & 3;

  floatx4 acc[4][4];
#pragma unroll
  for (int i = 0; i < 4; i++)
#pragma unroll
    for (int j = 0; j < 4; j++) acc[i][j] = (floatx4){0.f, 0.f, 0.f, 0.f};

  for (int k0 = 0; k0 < K; k0 += 32) {
    __syncthreads();
#pragma unroll
    for (int j = 0; j < 2; ++j) {
      int p = wave * 2 + j;
      int ra = p * 16 + r_sub;
      int grow = m0 + ra; if (grow >= M) grow = M - 1;
      gl_lds16((const char*)(A + (size_t)grow * K + k0) + cb, (char*)As + p * 1024);
      int rb = n0 + p * 16 + r_sub;
      gl_lds16((const char*)(Bt + (size_t)rb * K + k0) + cb, (char*)Bs + p * 1024);
    }
    __syncthreads();

    short8 af[4], bfr[4];
#pragma unroll
    for (int i = 0; i < 4; i++)
      af[i] = *(const short8*)(As + (wr + i * 16 + l16) * 32 + (quad ^ rsw) * 8);
#pragma unroll
    for (int j = 0; j < 4; j++)
      bfr[j] = *(const short8*)(Bs + (wc + j * 16 + l16) * 32 + (quad ^ rsw) * 8);
#pragma unroll
    for (int i = 0; i < 4; i++)
#pragma unroll
      for (int j = 0; j < 4; j++)
        acc[i][j] = __builtin_amdgcn_mfma_f32_16x16x32_bf16(af[i], bfr[j], acc[i][j], 0, 0, 0);
  }

#pragma unroll
  for (int i = 0; i < 4; i++) {
#pragma unroll
    for (int r = 0; r < 4; r++) {
      int row = m0 + wr + i * 16 + quad * 4 + r;
      if (row < M) {
#pragma unroll
        for (int j = 0; j < 4; j++) {
          int col = n0 + wc + j * 16 + l16;
          C[(size_t)row * N + col] = __float2bfloat16(acc[i][j][r]);
        }
      }
    }
  }
}

__global__ __launch_bounds__(256) void gemm128_sw(
    const bf16* __restrict__ A0, const bf16* __restrict__ Bt0, bf16* __restrict__ C0,
    const bf16* __restrict__ A1, const bf16* __restrict__ Bt1, bf16* __restrict__ C1,
    int M, int K, int N, int mtilesPerHalf, int mtTotal, int ntLog2) {
  int lin = blockIdx.x;
  int g = lin & 7;
  int s = lin >> 3;
  int n_t = s & ((1 << ntLog2) - 1);
  int m_t = g + 8 * (s >> ntLog2);
  if (m_t >= mtTotal) return;
  int half = (m_t >= mtilesPerHalf) ? 1 : 0;
  int m_local = m_t - half * mtilesPerHalf;
  const bf16* A = half ? A1 : A0;
  const bf16* Bt = half ? Bt1 : Bt0;
  bf16* C = half ? C1 : C0;
  gemm_body(A, Bt, C, M, K, N, m_local * 128, n_t * 128);
}

// ---------------------------------------------------------------- layer-1 fused GEMM (128x64)
__global__ __launch_bounds__(256) void gemm_l1f(
    const bf16* __restrict__ Aa, const bf16* __restrict__ Bta,
    const bf16* __restrict__ Ab, const bf16* __restrict__ Btb,
    const float* __restrict__ ba, const float* __restrict__ bb,
    const float* __restrict__ w01, bf16* __restrict__ out,
    int M, int K, int N, int mtiles) {
  int lin = blockIdx.x;
  int g = lin & 7;
  int s = lin >> 3;
  int n_t = s & 15;
  int m_t = g + 8 * (s >> 4);
  if (m_t >= mtiles) return;
  const int m0 = m_t * 128, n0 = n_t * 64;

  __shared__ bf16 Asa[128 * 32];
  __shared__ bf16 Asb[128 * 32];
  __shared__ bf16 Bsa[64 * 32];
  __shared__ bf16 Bsb[64 * 32];
  const int tid = threadIdx.x;
  const int wave = tid >> 6;
  const int lane = tid & 63;
  const int quad = lane >> 4;
  const int l16 = lane & 15;
  const int wr = (wave >> 1) * 64;
  const int wc = (wave & 1) * 32;
  const int r_sub = lane >> 2;
  const int cb = (((lane & 3) ^ ((lane >> 3) & 3)) * 16);
  const int rsw = (l16 >> 1) & 3;

  floatx4 acca[4][2], accb[4][2];
#pragma unroll
  for (int i = 0; i < 4; i++)
#pragma unroll
    for (int j = 0; j < 2; j++) {
      acca[i][j] = (floatx4){0.f, 0.f, 0.f, 0.f};
      accb[i][j] = (floatx4){0.f, 0.f, 0.f, 0.f};
    }

  for (int k0 = 0; k0 < K; k0 += 32) {
    __syncthreads();
#pragma unroll
    for (int j = 0; j < 2; ++j) {
      int p = wave * 2 + j;
      int ra = p * 16 + r_sub;
      int grow = m0 + ra; if (grow >= M) grow = M - 1;
      gl_lds16((const char*)(Aa + (size_t)grow * K + k0) + cb, (char*)Asa + p * 1024);
      gl_lds16((const char*)(Ab + (size_t)grow * K + k0) + cb, (char*)Asb + p * 1024);
    }
    {
      int rb = n0 + wave * 16 + r_sub;
      gl_lds16((const char*)(Bta + (size_t)rb * K + k0) + cb, (char*)Bsa + wave * 1024);
      gl_lds16((const char*)(Btb + (size_t)rb * K + k0) + cb, (char*)Bsb + wave * 1024);
    }
    __syncthreads();

    short8 afa[4], afb[4], bfa[2], bfb[2];
#pragma unroll
    for (int i = 0; i < 4; i++) {
      afa[i] = *(const short8*)(Asa + (wr + i * 16 + l16) * 32 + (quad ^ rsw) * 8);
      afb[i] = *(const short8*)(Asb + (wr + i * 16 + l16) * 32 + (quad ^ rsw) * 8);
    }
#pragma unroll
    for (int j = 0; j < 2; j++) {
      bfa[j] = *(const short8*)(Bsa + (wc + j * 16 + l16) * 32 + (quad ^ rsw) * 8);
      bfb[j] = *(const short8*)(Bsb + (wc + j * 16 + l16) * 32 + (quad ^ rsw) * 8);
    }
#pragma unroll
    for (int i = 0; i < 4; i++)
#pragma unroll
      for (int j = 0; j < 2; j++) {
        acca[i][j] = __builtin_amdgcn_mfma_f32_16x16x32_bf16(afa[i], bfa[j], acca[i][j], 0, 0, 0);
        accb[i][j] = __builtin_amdgcn_mfma_f32_16x16x32_bf16(afb[i], bfb[j], accb[i][j], 0, 0, 0);
      }
  }

#pragma unroll
  for (int j = 0; j < 2; j++) {
    int col = n0 + wc + j * 16 + l16;
    float baj = ba[col], bbj = bb[col];
    float w0 = w01[2 * col], w1 = w01[2 * col + 1];
#pragma unroll
    for (int i = 0; i < 4; i++) {
#pragma unroll
      for (int r = 0; r < 4; r++) {
        int row = m0 + wr + i * 16 + quad * 4 + r;
        if (row < M) {
          float x = eluf(acca[i][j][r] + baj);
          float y = eluf(accb[i][j][r] + bbj);
          out[(size_t)row * N + col] = __float2bfloat16(x * w0 + y * w1);
        }
      }
    }
  }
}

// ---------------------------------------------------------------- layer-2 agg, XCD channel-sliced
// blockIdx&7 = slice (64 ch of the 512) -> per-XCD H stripe (both halves) 2.5 MB, L2-resident.
__global__ __launch_bounds__(256) void agg2_kernel(
    const bf16* __restrict__ Ha, const bf16* __restrict__ Hb,  // ldH = 1024
    const int* __restrict__ off1, const int* __restrict__ cs1, const float* __restrict__ cw1,
    const int* __restrict__ off2, const int* __restrict__ cs2, const float* __restrict__ cw2,
    const float* __restrict__ dinv1, const float* __restrict__ dinv2,
    const float* __restrict__ ba, const float* __restrict__ bb,
    const float* __restrict__ w01, bf16* __restrict__ out, int n) {
  const int lin = blockIdx.x;
  const int slice = lin & 7;
  const int vg = lin >> 3;
  const int t = threadIdx.x;
  const int v = vg * 32 + t / 8;
  if (v >= n) return;
  const int c = slice * 64 + (t & 7) * 8;
  const bf16* __restrict__ baseA = Ha + c;
  const bf16* __restrict__ baseB = Hb + c;

  float a[8], b[8];
#pragma unroll
  for (int k = 0; k < 8; k++) { a[k] = 0.f; b[k] = 0.f; }

  gather_accum<1024>(baseA, cs1, cw1, off1[v], off1[v + 1], a);
  gather_accum<1024>(baseB, cs2, cw2, off2[v], off2[v + 1], b);

  short8 sa = *(const short8*)(baseA + (size_t)v * 1024);
  short8 sb = *(const short8*)(baseB + (size_t)v * 1024);
  const float dv1 = dinv1[v], dv2 = dinv2[v];

  short8 r;
#pragma unroll
  for (int k = 0; k < 8; k++) {
    float x = eluf(dv1 * a[k] + dv1 * dv1 * bf2f((unsigned short)sa[k]) + ba[c + k]);
    float y = eluf(dv2 * b[k] + dv2 * dv2 * bf2f((unsigned short)sb[k]) + bb[c + k]);
    r[k] = (short)__bfloat16_as_ushort(
        __float2bfloat16(x * w01[2 * (c + k)] + y * w01[2 * (c + k) + 1]));
  }
  *(short8*)(out + (size_t)v * 512 + c) = r;
}

// ---------------------------------------------------------------- layer-3 agg (unchanged structure)
template <int C, int LD, bool WU>
__global__ __launch_bounds__(256) void agg_out_kernel(
    const bf16* __restrict__ Ha, const bf16* __restrict__ Hb,
    const int* __restrict__ off1, const int* __restrict__ cs1, const float* __restrict__ cw1,
    const int* __restrict__ off2, const int* __restrict__ cs2, const float* __restrict__ cw2,
    const float* __restrict__ dinv1, const float* __restrict__ dinv2,
    const float* __restrict__ ba, const float* __restrict__ bb,
    const float* __restrict__ w01, void* __restrict__ out, int n,
    const int* __restrict__ outflag) {
  constexpr int TPV = C / 8;
  constexpr int G = 256 / TPV;
  const int t = threadIdx.x;
  int v = blockIdx.x * G + t / TPV;
  if (v >= n) return;
  if (WU) v = __builtin_amdgcn_readfirstlane(v);
  const int c = (t % TPV) * 8;
  const bf16* __restrict__ baseA = Ha + c;
  const bf16* __restrict__ baseB = Hb + c;

  float a[8], b[8];
#pragma unroll
  for (int k = 0; k < 8; k++) { a[k] = 0.f; b[k] = 0.f; }

  int s1 = off1[v], e1 = off1[v + 1];
  if (WU) { s1 = __builtin_amdgcn_readfirstlane(s1); e1 = __builtin_amdgcn_readfirstlane(e1); }
  gather_accum<LD>(baseA, cs1, cw1, s1, e1, a);
  int s2 = off2[v], e2 = off2[v + 1];
  if (WU) { s2 = __builtin_amdgcn_readfirstlane(s2); e2 = __builtin_amdgcn_readfirstlane(e2); }
  gather_accum<LD>(baseB, cs2, cw2, s2, e2, b);

  short8 sa = *(const short8*)(baseA + (size_t)v * LD);
  short8 sb = *(const short8*)(baseB + (size_t)v * LD);
  const float dv1 = dinv1[v], dv2 = dinv2[v];

  float r[8];
#pragma unroll
  for (int k = 0; k < 8; k++) {
    float x = eluf(dv1 * a[k] + dv1 * dv1 * bf2f((unsigned short)sa[k]) + ba[c + k]);
    float y = eluf(dv2 * b[k] + dv2 * dv2 * bf2f((unsigned short)sb[k]) + bb[c + k]);
    r[k] = x * w01[2 * (c + k)] + y * w01[2 * (c + k) + 1];
  }

  const bool out_f32 = (outflag != nullptr) && (*outflag != 0);
  size_t oi = (size_t)v * C + c;
  if (out_f32) {
    floatx4 lo = {r[0], r[1], r[2], r[3]};
    floatx4 hi = {r[4], r[5], r[6], r[7]};
    *(floatx4*)((float*)out + oi) = lo;
    *(floatx4*)((float*)out + oi + 4) = hi;
  } else {
    short8 rb;
#pragma unroll
    for (int k = 0; k < 8; k++)
      rb[k] = (short)__bfloat16_as_ushort(__float2bfloat16(r[k]));
    *(short8*)((bf16*)out + oi) = rb;
  }
}

// ---------------------------------------------------------------- host pipeline
extern "C" void kernel_launch(void* const* d_in, const int* in_sizes, int n_in,
                              void* d_out, int out_size, void* d_ws, size_t ws_size,
                              hipStream_t stream) {
  const void* X = d_in[0];
  const int* ei1 = (const int*)d_in[1];
  const int* ei2 = (const int*)d_in[2];
  const int n = in_sizes[0] / 512;
  const int E1 = in_sizes[1] / 2;
  const int E2 = in_sizes[2] / 2;
  const int* src1 = ei1;           const int* dst1 = ei1 + E1;
  const int* src2 = ei2;           const int* dst2 = ei2 + E2;

  auto rnd = [](size_t b) { return (b + 255) & ~(size_t)255; };
  char* p = (char*)d_ws;
  auto alloc = [&](size_t bytes) { char* r = p; p += rnd(bytes); return r; };

  int* flag = (int*)alloc(256);
  int* deg1 = (int*)alloc((size_t)n * 4);
  int* deg2 = (int*)alloc((size_t)n * 4);
  int* cur1 = (int*)alloc((size_t)n * 4);
  int* cur2 = (int*)alloc((size_t)n * 4);
  int* off1 = (int*)alloc((size_t)(n + 1) * 4);
  int* off2 = (int*)alloc((size_t)(n + 1) * 4);
  float* dinv1 = (float*)alloc((size_t)n * 4);
  float* dinv2 = (float*)alloc((size_t)n * 4);
  int* cs1 = (int*)alloc((size_t)E1 * 4);
  float* cw1 = (float*)alloc((size_t)E1 * 4);
  int* cs2 = (int*)alloc((size_t)E2 * 4);
  float* cw2 = (float*)alloc((size_t)E2 * 4);
  bf16* Wt11 = (bf16*)alloc((size_t)512 * 1024 * 2);
  bf16* Wt12 = (bf16*)alloc((size_t)512 * 1024 * 2);
  bf16* Wt2cat = (bf16*)alloc((size_t)1024 * 1024 * 2);
  bf16* Wt3cat = (bf16*)alloc((size_t)256 * 512 * 2);
  float* bf_[6]; int bsz[6] = {1024, 1024, 512, 512, 128, 128};
  for (int i = 0; i < 6; i++) bf_[i] = (float*)alloc((size_t)bsz[i] * 4);
  float* w01_[3]; int asz[3] = {2048, 1024, 256};
  for (int i = 0; i < 3; i++) w01_[i] = (float*)alloc((size_t)asz[i] * 4);
  bf16* Xb = (bf16*)alloc((size_t)n * 512 * 2);
  bf16* aggXa = (bf16*)alloc((size_t)n * 512 * 2);
  bf16* aggXb = (bf16*)alloc((size_t)n * 512 * 2);
  bf16* H1a = (bf16*)alloc((size_t)n * 1024 * 2);
  bf16* act1 = (bf16*)alloc((size_t)n * 1024 * 2);
  bf16* H2cat = H1a;
  bf16* act2 = aggXa;  // dead after gemm_l1f
  bf16* H3cat = aggXb; // dead after gemm_l1f

  // ---- prep: probe + zero counters
  int zwords = (int)(rnd((size_t)n * 4) * 4 / 4);
  probe_zero<<<1 + (zwords + 1023) / 1024, 256, 0, stream>>>(
      (const unsigned short*)X, flag, deg1, zwords);

  // ---- fused prep
  int xbBlocks = (n * 512) / 2048;
  int degBlocks = (E1 + E2 + 255) / 256;
  prep_all<<<2176 + xbBlocks + 20 + degBlocks, 256, 0, stream>>>(
      X, Xb, n * 512,
      d_in[3], d_in[5], d_in[7], d_in[9], d_in[11], d_in[13],
      Wt11, Wt12, Wt2cat, Wt3cat,
      d_in[4], d_in[6], d_in[8], d_in[10], d_in[12], d_in[14],
      d_in[15], d_in[16], d_in[17],
      bf_[0], bf_[1], bf_[2], bf_[3], bf_[4], bf_[5],
      w01_[0], w01_[1], w01_[2],
      dst1, E1, dst2, E2, deg1, deg2, flag);

  scan2_kernel<<<2, 1024, 0, stream>>>(deg1, off1, dinv1, deg2, off2, dinv2, n);
  csr_fused<<<(E1 + E2 + 255) / 256, 256, 0, stream>>>(src1, dst1, E1, src2, dst2, E2,
                                                       off1, cur1, dinv1, cs1, cw1,
                                                       off2, cur2, dinv2, cs2, cw2);

  const int mtiles = (n + 127) / 128;
  auto swgrid = [](int mtTotal, int ntiles) {
    return 8 * ntiles * ((mtTotal + 7) / 8);
  };
  const int vg32 = 8 * ((n + 31) / 32);
  // ---- layer 1: XCD-sliced input agg + fused dual-GEMM/bias/ELU/combine
  aggx_kernel<<<vg32, 256, 0, stream>>>(Xb, off1, cs1, cw1, off2, cs2, cw2,
                                        dinv1, dinv2, aggXa, aggXb, n);
  gemm_l1f<<<swgrid(mtiles, 16), 256, 0, stream>>>(
      aggXa, Wt11, aggXb, Wt12, bf_[0], bf_[1], w01_[0], act1, n, 512, 1024, mtiles);
  // ---- layer 2: GEMM + XCD-sliced agg
  gemm128_sw<<<swgrid(mtiles, 8), 256, 0, stream>>>(
      act1, Wt2cat, H2cat, act1, Wt2cat, H2cat, n, 1024, 1024, mtiles, mtiles, 3);
  agg2_kernel<<<vg32, 256, 0, stream>>>(H2cat, H2cat + 512,
                                        off1, cs1, cw1, off2, cs2, cw2,
                                        dinv1, dinv2, bf_[2], bf_[3], w01_[1], act2, n);
  // ---- layer 3
  gemm128_sw<<<swgrid(mtiles, 2), 256, 0, stream>>>(
      act2, Wt3cat, H3cat, act2, Wt3cat, H3cat, n, 512, 256, mtiles, mtiles, 1);
  agg_out_kernel<128, 256, false><<<(n + 15) / 16, 256, 0, stream>>>(
      H3cat, H3cat + 128, off1, cs1, cw1, off2, cs2, cw2,
      dinv1, dinv2, bf_[4], bf_[5], w01_[2], d_out, n, flag);
}